// Round 5
// baseline (23620.401 us; speedup 1.0000x reference)
//
#include <hip/hip_runtime.h>
#include <hip/hip_fp16.h>
#include <cstdint>
#include <cstddef>

typedef unsigned short u16;
typedef unsigned int   u32;
typedef unsigned long long u64;

#define Bn 4
#define Tn 512
#define Hn 512
#define En 256
#define Vn 50257
#define NPAD 50304

#define G16  16
#define NBLK 32
#define RNT  256

// ---- dynamic LDS byte offsets ----
#define WC2L_B  0        // 64*512 halfs = 65536
#define WRL_B   65536    // up to 32*512 halfs = 32768
#define XB_B    98304    // [4][1536] f32 = 24576
#define C1L_B   122880   // cand1loc [64][4] f32 = 1024
#define BC2L_B  123904   // [512] f32
#define BRL_B   125952   // [512] f32
#define BC1L_B  128000   // [64] f32
#define BG1L_B  128256   // [32] f32
#define WG2L_B  128384   // [32] f32
#define GATEL_B 128512   // [4] f32
#define GPW_B   128528   // [4][4] f32
#define STW_B   128592   // [4][4][2] f32
#define IDS_B   128720   // [4] int
#define REC_LDS 128768

__device__ __forceinline__ u16 f2bf(float f) {
  u32 x; __builtin_memcpy(&x, &f, 4);
  u32 r = (x + 0x7fffu + ((x >> 16) & 1u)) >> 16;
  return (u16)r;
}
__device__ __forceinline__ float h2f(u16 h) {
  __half hh; __builtin_memcpy(&hh, &h, 2); return __half2float(hh);
}
__device__ __forceinline__ u16 f2h(float f) {
  __half hh = __float2half(f); u16 u; __builtin_memcpy(&u, &hh, 2); return u;
}
__device__ __forceinline__ u64 pack4h(float a, float b, float c, float d) {
  return (u64)f2h(a) | ((u64)f2h(b) << 16) | ((u64)f2h(c) << 32) | ((u64)f2h(d) << 48);
}
__device__ __forceinline__ void acc4h(u64 v, float* s) {
  s[0] += h2f((u16)v); s[1] += h2f((u16)(v >> 16));
  s[2] += h2f((u16)(v >> 32)); s[3] += h2f((u16)(v >> 48));
}

__device__ __forceinline__ float gld(const float* p) {
  return __hip_atomic_load(p, __ATOMIC_RELAXED, __HIP_MEMORY_SCOPE_AGENT);
}
__device__ __forceinline__ void gst(float* p, float v) {
  __hip_atomic_store(p, v, __ATOMIC_RELAXED, __HIP_MEMORY_SCOPE_AGENT);
}
__device__ __forceinline__ float2 gld2(const float* p) {
  u64 v = __hip_atomic_load((const u64*)p, __ATOMIC_RELAXED, __HIP_MEMORY_SCOPE_AGENT);
  float2 r; u32 lo = (u32)v, hi = (u32)(v >> 32);
  __builtin_memcpy(&r.x, &lo, 4); __builtin_memcpy(&r.y, &hi, 4);
  return r;
}
__device__ __forceinline__ void gst2(float* p, float a, float b) {
  u32 la, lb; __builtin_memcpy(&la, &a, 4); __builtin_memcpy(&lb, &b, 4);
  u64 v = ((u64)lb << 32) | la;
  __hip_atomic_store((u64*)p, v, __ATOMIC_RELAXED, __HIP_MEMORY_SCOPE_AGENT);
}
__device__ __forceinline__ u64 gldu64(const u16* p) {
  return __hip_atomic_load((const u64*)p, __ATOMIC_RELAXED, __HIP_MEMORY_SCOPE_AGENT);
}
__device__ __forceinline__ void gstu64(u16* p, u64 v) {
  __hip_atomic_store((u64*)p, v, __ATOMIC_RELAXED, __HIP_MEMORY_SCOPE_AGENT);
}

// ---------------- prep: transpose + fp32->fp16 (col-major) ----------------
__global__ __launch_bounds__(256) void transpose_h(
    const float* __restrict__ src, __half* __restrict__ dst, int K, int N)
{
  __shared__ float tile[32][33];
  const int tx = threadIdx.x & 31, ty = threadIdx.x >> 5;
  const int bn = blockIdx.x * 32, bk = blockIdx.y * 32;
  #pragma unroll
  for (int i = 0; i < 4; ++i)
    tile[ty + i * 8][tx] = src[(size_t)(bk + ty + i * 8) * N + bn + tx];
  __syncthreads();
  #pragma unroll
  for (int i = 0; i < 4; ++i)
    dst[(size_t)(bn + ty + i * 8) * K + bk + tx] = __float2half(tile[tx][ty + i * 8]);
}

// ---------------- prep: row-major fp32 -> fp16 ----------------
__global__ __launch_bounds__(256) void conv16_kernel(
    const float* __restrict__ src, __half* __restrict__ dst, int n)
{
  for (int i = blockIdx.x * 256 + threadIdx.x; i < n; i += gridDim.x * 256)
    dst[i] = __float2half(src[i]);
}

// ---------------- prep: Wh fp32 -> bf16 padded [512][NPAD] ----------------
__global__ __launch_bounds__(256) void convwh_kernel(
    const float* __restrict__ wh, u16* __restrict__ whb)
{
  const int k = blockIdx.y;
  const int v0 = (blockIdx.x * 256 + threadIdx.x) * 2;
  if (v0 >= NPAD) return;
  float a = (v0     < Vn) ? wh[(size_t)k * Vn + v0]     : 0.f;
  float b = (v0 + 1 < Vn) ? wh[(size_t)k * Vn + v0 + 1] : 0.f;
  u32 pack = (u32)f2bf(a) | ((u32)f2bf(b) << 16);
  *(u32*)&whb[(size_t)k * NPAD + v0] = pack;
}

// ---------------- persistent recurrence: single-barrier partial-sum scheme ----------------
// blocks 0..15: layer 0 (t = tick); blocks 16..31: layer 1 (t = tick-2)
__global__ __launch_bounds__(RNT, 1) void rec_kernel(
    const int* __restrict__ ids, const float* __restrict__ emb,
    const __half* __restrict__ wtC1_0h, const __half* __restrict__ wtG1_0h,
    const __half* __restrict__ wtC1_1h, const __half* __restrict__ wtG1_1h,
    const __half* __restrict__ wc2h_0, const __half* __restrict__ wc2h_1,
    const __half* __restrict__ wrh_0, const __half* __restrict__ wrh_1,
    const float* __restrict__ bc1_0, const float* __restrict__ bg1_0,
    const float* __restrict__ bc2_0, const float* __restrict__ br_0,
    const float* __restrict__ wg2_0, const float* __restrict__ bg2_0,
    const float* __restrict__ bc1_1, const float* __restrict__ bg1_1,
    const float* __restrict__ bc2_1, const float* __restrict__ br_1,
    const float* __restrict__ wg2_1, const float* __restrict__ bg2_1,
    float* __restrict__ n0buf, float* __restrict__ gatePb,
    u16* __restrict__ candPb, u16* __restrict__ rPb,
    u32* flags, float* __restrict__ histN, float* __restrict__ gates_out)
{
  extern __shared__ char smem[];
  __half* Wc2L = (__half*)(smem + WC2L_B);
  __half* WrL  = (__half*)(smem + WRL_B);
  float* xbl   = (float*)(smem + XB_B);
  float* cand1loc = (float*)(smem + C1L_B);
  float* bc2L  = (float*)(smem + BC2L_B);
  float* brL   = (float*)(smem + BRL_B);
  float* bc1L  = (float*)(smem + BC1L_B);
  float* bg1L  = (float*)(smem + BG1L_B);
  float* wg2L  = (float*)(smem + WG2L_B);
  float* gateL = (float*)(smem + GATEL_B);
  float* gpw   = (float*)(smem + GPW_B);
  float* stw   = (float*)(smem + STW_B);
  int*   ids4  = (int*)(smem + IDS_B);

  const int tid = threadIdx.x, g = blockIdx.x;
  const int l = g >> 4, gl = g & 15;
  const int w = tid >> 6, lane = tid & 63;
  const int C = l ? 1536 : 1280;
  const int e = l ? 512 : 256;
  const int er = e >> 4;            // Wr rows per block
  const int j0 = 2 * tid;

  const __half* wc2h = l ? wc2h_1 : wc2h_0;
  const __half* wrh  = l ? wrh_1  : wrh_0;
  const float* bc1 = l ? bc1_1 : bc1_0;
  const float* bg1 = l ? bg1_1 : bg1_0;
  const float* bc2 = l ? bc2_1 : bc2_0;
  const float* br  = l ? br_1  : br_0;
  const float* wg2 = l ? wg2_1 : wg2_0;
  const float bg2v = (l ? bg2_1 : bg2_0)[0];

  // ---- one-time staging ----
  {
    const u32* s = (const u32*)(wc2h + (size_t)gl * 64 * 512);
    u32* d = (u32*)Wc2L;
    for (int i = tid; i < 16384; i += RNT) d[i] = s[i];
    const u32* s2 = (const u32*)(wrh + (size_t)gl * er * 512);
    u32* d2 = (u32*)WrL;
    for (int i = tid; i < er * 256; i += RNT) d2[i] = s2[i];
  }
  for (int i = tid; i < 512; i += RNT) { bc2L[i] = bc2[i]; brL[i] = br[i]; }
  if (tid < 64) bc1L[tid] = bc1[gl * 64 + tid];
  else if (tid < 96)  bg1L[tid - 64] = bg1[gl * 32 + tid - 64];
  else if (tid < 128) wg2L[tid - 96] = wg2[gl * 32 + tid - 96];
  for (int i = tid; i < 6144; i += RNT) xbl[i] = 0.f;
  __syncthreads();

  for (int tick = 0; tick <= Tn + 2; ++tick) {
    const int t = tick - (l ? 2 : 0);
    const int tf = t - 1;
    const bool prod = (t >= 0) && (t < Tn);
    const bool fin  = (tf >= 0) && (tf < Tn);
    const int parw = tick & 1;
    const int parr = parw ^ 1;

    // ---- wait: own-layer flags >= tick; other-layer (l0 only) gets 1-tick slack ----
    if (tick > 0) {
      if (tid < 32) {
        u32 th = (l == 0 && tid >= 16) ? (u32)(tick - 1) : (u32)tick;
        bool wt;
        do {
          wt = __hip_atomic_load(&flags[tid * 16], __ATOMIC_RELAXED, __HIP_MEMORY_SCOPE_AGENT) < th;
        } while (__any(wt));
      }
    }
    __syncthreads();

    // ---- finalize loads (partials of step tf) + gate reduce + stage loads ----
    float cs[8] = {0.f,0.f,0.f,0.f,0.f,0.f,0.f,0.f};
    float rs[8] = {0.f,0.f,0.f,0.f,0.f,0.f,0.f,0.f};
    if (fin) {
      const u16* cb = candPb + (size_t)((l * 2 + parr) * G16) * 2048 + j0 * 4;
      const u16* rb = rPb    + (size_t)((l * 2 + parr) * G16) * 2048 + j0 * 4;
      #pragma unroll
      for (int gq = 0; gq < 16; ++gq) {
        u64 c0 = gldu64(cb + gq * 2048);
        u64 c1 = gldu64(cb + gq * 2048 + 4);
        u64 r0 = gldu64(rb + gq * 2048);
        u64 r1 = gldu64(rb + gq * 2048 + 4);
        acc4h(c0, cs); acc4h(c1, cs + 4);
        acc4h(r0, rs); acc4h(r1, rs + 4);
      }
      if (w == 0) {
        float gv = gld(gatePb + ((l * 2 + parr) * G16 + (lane >> 2)) * 4 + (lane & 3));
        gv += __shfl_xor(gv, 4); gv += __shfl_xor(gv, 8);
        gv += __shfl_xor(gv, 16); gv += __shfl_xor(gv, 32);
        if (lane < 4) gateL[lane] = 1.f / (1.f + expf(-(gv + bg2v)));
      }
    }
    if (l == 0 && prod && tid < 4) ids4[tid] = ids[tid * Tn + t];
    float n0v[8];
    if (l == 1 && prod) {
      #pragma unroll
      for (int b = 0; b < 4; ++b) {
        float2 v = gld2(n0buf + (t & 1) * 2048 + b * 512 + j0);
        n0v[b * 2] = v.x; n0v[b * 2 + 1] = v.y;
      }
    }
    __syncthreads();   // gateL + ids4 ready

    // ---- finalize compute: h(tf), LN, shift, outputs ----
    if (fin) {
      float g4[4] = {gateL[0], gateL[1], gateL[2], gateL[3]};
      float hp[2][4];
      #pragma unroll
      for (int jj = 0; jj < 2; ++jj) {
        int j = j0 + jj;
        float bcv = bc2L[j], brv = brL[j];
        #pragma unroll
        for (int b = 0; b < 4; ++b)
          hp[jj][b] = xbl[b * 1536 + j] + g4[b] * (cs[jj * 4 + b] + bcv)
                      + 0.1f * (rs[jj * 4 + b] + brv);
      }
      float s4[4], q4[4];
      #pragma unroll
      for (int b = 0; b < 4; ++b) {
        s4[b] = hp[0][b] + hp[1][b];
        q4[b] = hp[0][b] * hp[0][b] + hp[1][b] * hp[1][b];
      }
      #pragma unroll
      for (int off = 32; off; off >>= 1)
        #pragma unroll
        for (int b = 0; b < 4; ++b) {
          s4[b] += __shfl_xor(s4[b], off);
          q4[b] += __shfl_xor(q4[b], off);
        }
      if (lane == 0) {
        #pragma unroll
        for (int b = 0; b < 4; ++b) { stw[w * 8 + b * 2] = s4[b]; stw[w * 8 + b * 2 + 1] = q4[b]; }
      }
      __syncthreads();
      float m4[4], i4[4];
      #pragma unroll
      for (int b = 0; b < 4; ++b) {
        float s = stw[b * 2] + stw[8 + b * 2] + stw[16 + b * 2] + stw[24 + b * 2];
        float q = stw[b * 2 + 1] + stw[8 + b * 2 + 1] + stw[16 + b * 2 + 1] + stw[24 + b * 2 + 1];
        float m = s * (1.f / 512.f);
        float var = q * (1.f / 512.f) - m * m;
        m4[b] = m; i4[b] = rsqrtf(var + 1e-5f);
      }
      float nn[2][4];
      #pragma unroll
      for (int jj = 0; jj < 2; ++jj) {
        int j = j0 + jj;
        #pragma unroll
        for (int b = 0; b < 4; ++b) {
          float old = xbl[b * 1536 + j];
          xbl[b * 1536 + 512 + j] = old;
          float nv = (hp[jj][b] - m4[b]) * i4[b];
          xbl[b * 1536 + j] = nv;
          nn[jj][b] = nv;
        }
      }
      if (l == 0) {
        if ((tid >> 4) == gl) {
          #pragma unroll
          for (int b = 0; b < 4; ++b)
            gst2(n0buf + (tf & 1) * 2048 + b * 512 + j0, nn[0][b], nn[1][b]);
        }
      } else {
        if ((tid >> 4) == gl) {
          #pragma unroll
          for (int b = 0; b < 4; ++b) {
            histN[((size_t)(b * Tn + tf)) * Hn + j0]     = nn[0][b];
            histN[((size_t)(b * Tn + tf)) * Hn + j0 + 1] = nn[1][b];
          }
        }
        if (gl == 0 && tid < 4) gates_out[tid * Tn + tf] = gateL[tid];
      }
    }

    // ---- stage ctx section 2 (input) for step t ----
    if (prod) {
      if (l) {
        #pragma unroll
        for (int b = 0; b < 4; ++b) {
          xbl[b * 1536 + 1024 + j0]     = n0v[b * 2];
          xbl[b * 1536 + 1024 + j0 + 1] = n0v[b * 2 + 1];
        }
      } else if (tid < 128) {
        #pragma unroll
        for (int b = 0; b < 4; ++b) {
          float2 ev = *(const float2*)(emb + (size_t)ids4[b] * En + j0);
          xbl[b * 1536 + 1024 + j0]     = ev.x;
          xbl[b * 1536 + 1024 + j0 + 1] = ev.y;
        }
      }
    }
    __syncthreads();   // xbl complete

    // ---- produce: matvec1 (streamed Wc1/Wg1) ----
    if (prod) {
      const int Kp = C >> 1;
      const u32* W1 = (const u32*)(l ? wtC1_1h : wtC1_0h) + (size_t)(gl * 64 + w * 16) * Kp;
      const u32* Wg = (const u32*)(l ? wtG1_1h : wtG1_0h) + (size_t)(gl * 32 + w * 8) * Kp;
      float a1[16][4], a2[8][4];
      #pragma unroll
      for (int c = 0; c < 16; ++c)
        #pragma unroll
        for (int b = 0; b < 4; ++b) a1[c][b] = 0.f;
      #pragma unroll
      for (int c = 0; c < 8; ++c)
        #pragma unroll
        for (int b = 0; b < 4; ++b) a2[c][b] = 0.f;

      for (int p = lane; p < Kp; p += 64) {
        float2 x0 = *(const float2*)(xbl + 2 * p);
        float2 x1 = *(const float2*)(xbl + 1536 + 2 * p);
        float2 x2 = *(const float2*)(xbl + 3072 + 2 * p);
        float2 x3 = *(const float2*)(xbl + 4608 + 2 * p);
        #pragma unroll
        for (int c = 0; c < 16; ++c) {
          u32 wv = W1[(size_t)c * Kp + p];
          __half2 hw; __builtin_memcpy(&hw, &wv, 4);
          float2 wf = __half22float2(hw);
          a1[c][0] = fmaf(wf.x, x0.x, fmaf(wf.y, x0.y, a1[c][0]));
          a1[c][1] = fmaf(wf.x, x1.x, fmaf(wf.y, x1.y, a1[c][1]));
          a1[c][2] = fmaf(wf.x, x2.x, fmaf(wf.y, x2.y, a1[c][2]));
          a1[c][3] = fmaf(wf.x, x3.x, fmaf(wf.y, x3.y, a1[c][3]));
        }
        #pragma unroll
        for (int c = 0; c < 8; ++c) {
          u32 wv = Wg[(size_t)c * Kp + p];
          __half2 hw; __builtin_memcpy(&hw, &wv, 4);
          float2 wf = __half22float2(hw);
          a2[c][0] = fmaf(wf.x, x0.x, fmaf(wf.y, x0.y, a2[c][0]));
          a2[c][1] = fmaf(wf.x, x1.x, fmaf(wf.y, x1.y, a2[c][1]));
          a2[c][2] = fmaf(wf.x, x2.x, fmaf(wf.y, x2.y, a2[c][2]));
          a2[c][3] = fmaf(wf.x, x3.x, fmaf(wf.y, x3.y, a2[c][3]));
        }
      }
      #pragma unroll
      for (int off = 32; off; off >>= 1) {
        #pragma unroll
        for (int c = 0; c < 16; ++c)
          #pragma unroll
          for (int b = 0; b < 4; ++b) a1[c][b] += __shfl_xor(a1[c][b], off);
        #pragma unroll
        for (int c = 0; c < 8; ++c)
          #pragma unroll
          for (int b = 0; b < 4; ++b) a2[c][b] += __shfl_xor(a2[c][b], off);
      }
      float v1[4] = {0.f,0.f,0.f,0.f}, v2[4] = {0.f,0.f,0.f,0.f};
      #pragma unroll
      for (int c = 0; c < 16; ++c)
        if (lane == c) { v1[0]=a1[c][0]; v1[1]=a1[c][1]; v1[2]=a1[c][2]; v1[3]=a1[c][3]; }
      #pragma unroll
      for (int c = 0; c < 8; ++c)
        if (lane == c) { v2[0]=a2[c][0]; v2[1]=a2[c][1]; v2[2]=a2[c][2]; v2[3]=a2[c][3]; }
      if (lane < 16) {
        int cl = w * 16 + lane;
        float bb = bc1L[cl];
        #pragma unroll
        for (int b = 0; b < 4; ++b) cand1loc[cl * 4 + b] = fmaxf(v1[b] + bb, 0.f);
      }
      if (lane < 8) {
        int cl = w * 8 + lane;
        float bgv = bg1L[cl], wgv = wg2L[cl];
        float tb[4];
        #pragma unroll
        for (int b = 0; b < 4; ++b) tb[b] = tanhf(v2[b] + bgv) * wgv;
        #pragma unroll
        for (int off = 1; off < 8; off <<= 1)
          #pragma unroll
          for (int b = 0; b < 4; ++b) tb[b] += __shfl_xor(tb[b], off);
        if (lane == 0) {
          #pragma unroll
          for (int b = 0; b < 4; ++b) gpw[w * 4 + b] = tb[b];
        }
      }
    }
    __syncthreads();

    // ---- produce: matvec2 partials (Wc2 rows, Wr rows) + writes ----
    if (prod) {
      float cp0[4]={0.f,0.f,0.f,0.f}, cp1[4]={0.f,0.f,0.f,0.f};
      float rp0[4]={0.f,0.f,0.f,0.f}, rp1[4]={0.f,0.f,0.f,0.f};
      #pragma unroll 8
      for (int k = 0; k < 64; ++k) {
        float4 cf = *(const float4*)(cand1loc + k * 4);
        __half2 hw = *(const __half2*)(Wc2L + k * 512 + j0);
        float2 wf = __half22float2(hw);
        cp0[0] = fmaf(wf.x, cf.x, cp0[0]); cp0[1] = fmaf(wf.x, cf.y, cp0[1]);
        cp0[2] = fmaf(wf.x, cf.z, cp0[2]); cp0[3] = fmaf(wf.x, cf.w, cp0[3]);
        cp1[0] = fmaf(wf.y, cf.x, cp1[0]); cp1[1] = fmaf(wf.y, cf.y, cp1[1]);
        cp1[2] = fmaf(wf.y, cf.z, cp1[2]); cp1[3] = fmaf(wf.y, cf.w, cp1[3]);
      }
      for (int k = 0; k < er; ++k) {
        int ki = 1024 + gl * er + k;
        float i0 = xbl[ki], i1 = xbl[1536 + ki], i2 = xbl[3072 + ki], i3 = xbl[4608 + ki];
        __half2 hw = *(const __half2*)(WrL + k * 512 + j0);
        float2 wf = __half22float2(hw);
        rp0[0] = fmaf(wf.x, i0, rp0[0]); rp0[1] = fmaf(wf.x, i1, rp0[1]);
        rp0[2] = fmaf(wf.x, i2, rp0[2]); rp0[3] = fmaf(wf.x, i3, rp0[3]);
        rp1[0] = fmaf(wf.y, i0, rp1[0]); rp1[1] = fmaf(wf.y, i1, rp1[1]);
        rp1[2] = fmaf(wf.y, i2, rp1[2]); rp1[3] = fmaf(wf.y, i3, rp1[3]);
      }
      u16* cdst = candPb + (size_t)((l * 2 + parw) * G16 + gl) * 2048 + j0 * 4;
      u16* rdst = rPb    + (size_t)((l * 2 + parw) * G16 + gl) * 2048 + j0 * 4;
      gstu64(cdst,     pack4h(cp0[0], cp0[1], cp0[2], cp0[3]));
      gstu64(cdst + 4, pack4h(cp1[0], cp1[1], cp1[2], cp1[3]));
      gstu64(rdst,     pack4h(rp0[0], rp0[1], rp0[2], rp0[3]));
      gstu64(rdst + 4, pack4h(rp1[0], rp1[1], rp1[2], rp1[3]));
      if (tid < 4) {
        float gp = gpw[tid] + gpw[4 + tid] + gpw[8 + tid] + gpw[12 + tid];
        gst(gatePb + ((l * 2 + parw) * G16 + gl) * 4 + tid, gp);
      }
    }

    // ---- drain + flag ----
    asm volatile("s_waitcnt vmcnt(0)" ::: "memory");
    __syncthreads();
    if (tid == 0)
      __hip_atomic_store(&flags[g * 16], (u32)(tick + 1), __ATOMIC_RELAXED, __HIP_MEMORY_SCOPE_AGENT);
  }
}

// ---------------- attention scores (histN already normalized) ----------------
__global__ __launch_bounds__(256) void scores_kernel(
    const float* __restrict__ histN,
    const float* __restrict__ wa1, const float* __restrict__ ba1,
    const float* __restrict__ wa2, const float* __restrict__ ba2,
    float* __restrict__ scores)
{
  __shared__ float xs[8][512];
  __shared__ float wacc[4][8];
  const int tid = threadIdx.x, bid = blockIdx.x;

  for (int idx = tid; idx < 4096; idx += 256)
    xs[idx >> 9][idx & 511] = histN[(size_t)(bid * 8) * Hn + idx];
  __syncthreads();

  float pr[8] = {0.f,0.f,0.f,0.f,0.f,0.f,0.f,0.f};
  #pragma unroll
  for (int cc = 0; cc < 2; ++cc) {
    int c = tid + cc * 256;
    float a[8] = {0.f,0.f,0.f,0.f,0.f,0.f,0.f,0.f};
    for (int k = 0; k < 512; ++k) {
      float wv = wa1[(size_t)k * 512 + c];
      #pragma unroll
      for (int r = 0; r < 8; ++r) a[r] = fmaf(xs[r][k], wv, a[r]);
    }
    float b1 = ba1[c], w2 = wa2[c];
    #pragma unroll
    for (int r = 0; r < 8; ++r) pr[r] += tanhf(a[r] + b1) * w2;
  }
  int lane = tid & 63, wq = tid >> 6;
  #pragma unroll
  for (int off = 32; off; off >>= 1)
    #pragma unroll
    for (int r = 0; r < 8; ++r) pr[r] += __shfl_xor(pr[r], off);
  if (lane == 0) {
    #pragma unroll
    for (int r = 0; r < 8; ++r) wacc[wq][r] = pr[r];
  }
  __syncthreads();
  if (tid < 8)
    scores[bid * 8 + tid] = wacc[0][tid] + wacc[1][tid] + wacc[2][tid] + wacc[3][tid] + ba2[0];
}

// ---------------- prefix-softmax cumsum -> attended (bf16) ----------------
__global__ __launch_bounds__(256) void cumsum_kernel(
    const float* __restrict__ scores, const float* __restrict__ histN,
    u16* __restrict__ att)
{
  __shared__ float ee[512], den[512], sb[512], red[256];
  const int tid = threadIdx.x, b = blockIdx.x;
  float s0 = scores[b * Tn + tid], s1 = scores[b * Tn + tid + 256];
  red[tid] = fmaxf(s0, s1);
  __syncthreads();
  for (int s = 128; s; s >>= 1) { if (tid < s) red[tid] = fmaxf(red[tid], red[tid + s]); __syncthreads(); }
  float m = red[0];
  ee[tid] = expf(s0 - m); ee[tid + 256] = expf(s1 - m);
  den[tid] = ee[tid]; den[tid + 256] = ee[tid + 256];
  __syncthreads();
  float* A = den; float* D = sb;
  for (int off = 1; off < 512; off <<= 1) {
    for (int t2 = tid; t2 < 512; t2 += 256) { float v = A[t2]; if (t2 >= off) v += A[t2 - off]; D[t2] = v; }
    __syncthreads();
    float* tmp = A; A = D; D = tmp;
  }
  float* R = D;
  for (int t2 = tid; t2 < 512; t2 += 256) R[t2] = 1.f / A[t2];
  __syncthreads();

  const int h0 = tid * 2;
  float ax = 0.f, ay = 0.f;
  for (int t = 0; t < 512; ++t) {
    const float* hpp = histN + ((size_t)(b * Tn + t)) * Hn + h0;
    float x0 = hpp[0], x1 = hpp[1];
    float et = ee[t], rd = R[t];
    ax = fmaf(et, x0, ax); ay = fmaf(et, x1, ay);
    u32 pack = (u32)f2bf(x0 + ax * rd) | ((u32)f2bf(x1 + ay * rd) << 16);
    *(u32*)(att + ((size_t)(b * Tn + t)) * Hn + h0) = pack;
  }
}

// ---------------- final GEMM: att[2048x512]bf16 @ WhB[512xNPAD]bf16 + bh -> fp32 ----------------
typedef short bf16x8_t __attribute__((ext_vector_type(8)));
typedef float f32x4_t  __attribute__((ext_vector_type(4)));

__global__ __launch_bounds__(256) void gemm_kernel(
    const u16* __restrict__ Aw, const u16* __restrict__ Bw,
    const float* __restrict__ bh, float* __restrict__ out)
{
  __shared__ u16 Alds[128 * 64];
  __shared__ u16 Blds[64 * 128];
  const int tid = threadIdx.x;
  const int n0 = blockIdx.x * 128, m0 = blockIdx.y * 128;
  const int w = tid >> 6, lane = tid & 63;
  const int wm = (w & 1) * 64, wn = (w >> 1) * 64;

  f32x4_t acc[4][4];
  #pragma unroll
  for (int i = 0; i < 4; ++i)
    #pragma unroll
    for (int j = 0; j < 4; ++j) acc[i][j] = (f32x4_t){0.f, 0.f, 0.f, 0.f};

  for (int kt = 0; kt < 8; ++kt) {
    const int k0 = kt * 64;
    {
      int row = tid >> 1, kc = (tid & 1) * 32;
      #pragma unroll
      for (int jj = 0; jj < 4; ++jj) {
        uint4 v = *(const uint4*)(Aw + (size_t)(m0 + row) * 512 + k0 + kc + jj * 8);
        int byte = row * 128 + (kc + jj * 8) * 2;
        byte ^= (row & 7) << 4;
        *(uint4*)((char*)Alds + byte) = v;
      }
    }
    {
      #pragma unroll
      for (int q = 0; q < 4; ++q) {
        int r = (tid >> 4) + q * 16, c8 = (tid & 15) * 8;
        uint4 v = *(const uint4*)(Bw + (size_t)(k0 + r) * NPAD + n0 + c8);
        *(uint4*)&Blds[r * 128 + c8] = v;
      }
    }
    __syncthreads();
    #pragma unroll
    for (int kh = 0; kh < 2; ++kh) {
      bf16x8_t af[4];
      #pragma unroll
      for (int i = 0; i < 4; ++i) {
        int row = wm + i * 16 + (lane & 15);
        int byte = row * 128 + kh * 64 + (lane >> 4) * 16;
        byte ^= (row & 7) << 4;
        af[i] = *(const bf16x8_t*)((const char*)Alds + byte);
      }
      const int kb = kh * 32 + (lane >> 4) * 8;
      #pragma unroll
      for (int j = 0; j < 4; ++j) {
        int col = wn + j * 16 + (lane & 15);
        bf16x8_t bf;
        #pragma unroll
        for (int jj = 0; jj < 8; ++jj) bf[jj] = (short)Blds[(kb + jj) * 128 + col];
        #pragma unroll
        for (int i = 0; i < 4; ++i)
          acc[i][j] = __builtin_amdgcn_mfma_f32_16x16x32_bf16(af[i], bf, acc[i][j], 0, 0, 0);
      }
    }
    __syncthreads();
  }
  #pragma unroll
  for (int j = 0; j < 4; ++j) {
    int col = n0 + wn + j * 16 + (lane & 15);
    if (col < Vn) {
      float bias = bh[col];
      #pragma unroll
      for (int i = 0; i < 4; ++i) {
        int rbase = m0 + wm + i * 16 + (lane >> 4) * 4;
        #pragma unroll
        for (int r = 0; r < 4; ++r)
          out[(size_t)(rbase + r) * Vn + col] = acc[i][j][r] + bias;
      }
    }
  }
}

// ---------------- host ----------------
extern "C" void kernel_launch(void* const* d_in, const int* in_sizes, int n_in,
                              void* d_out, int out_size, void* d_ws, size_t ws_size,
                              hipStream_t stream) {
  const int*   ids  = (const int*)d_in[0];
  const float* emb  = (const float*)d_in[1];
  const float* Wc1_0 = (const float*)d_in[2];  const float* bc1_0 = (const float*)d_in[3];
  const float* Wc2_0 = (const float*)d_in[4];  const float* bc2_0 = (const float*)d_in[5];
  const float* Wg1_0 = (const float*)d_in[6];  const float* bg1_0 = (const float*)d_in[7];
  const float* Wg2_0 = (const float*)d_in[8];  const float* bg2_0 = (const float*)d_in[9];
  const float* Wr_0  = (const float*)d_in[10]; const float* br_0  = (const float*)d_in[11];
  const float* Wc1_1 = (const float*)d_in[12]; const float* bc1_1 = (const float*)d_in[13];
  const float* Wc2_1 = (const float*)d_in[14]; const float* bc2_1 = (const float*)d_in[15];
  const float* Wg1_1 = (const float*)d_in[16]; const float* bg1_1 = (const float*)d_in[17];
  const float* Wg2_1 = (const float*)d_in[18]; const float* bg2_1 = (const float*)d_in[19];
  const float* Wr_1  = (const float*)d_in[20]; const float* br_1  = (const float*)d_in[21];
  const float* Wa1 = (const float*)d_in[22]; const float* ba1 = (const float*)d_in[23];
  const float* Wa2 = (const float*)d_in[24]; const float* ba2 = (const float*)d_in[25];
  const float* Wh  = (const float*)d_in[26]; const float* bh  = (const float*)d_in[27];

  float* out = (float*)d_out;
  char*  ws  = (char*)d_ws;

  const size_t OFF_FLAGS = 0;                          // 2048
  const size_t OFF_N0    = 4096;                       // 16384
  const size_t OFF_GATEP = 20480;                      // 1024
  const size_t OFF_CANDP = 24576;                      // 262144
  const size_t OFF_RP    = 286720;                     // 262144
  const size_t OFF_WT    = 548864;                     // 11534336
  const size_t OFF_HISTN = OFF_WT + 11534336;          // 4 MB
  const size_t OFF_SCO   = OFF_HISTN + 4194304;        // 8 KB
  const size_t OFF_ATT   = OFF_SCO + 8192;             // 2 MB
  const size_t OFF_WHB   = OFF_ATT + 2097152;          // 51.5 MB

  u32*   flags  = (u32*)(ws + OFF_FLAGS);
  float* n0buf  = (float*)(ws + OFF_N0);
  float* gatePb = (float*)(ws + OFF_GATEP);
  u16*   candPb = (u16*)(ws + OFF_CANDP);
  u16*   rPb    = (u16*)(ws + OFF_RP);
  __half* wth   = (__half*)(ws + OFF_WT);
  float* histN  = (float*)(ws + OFF_HISTN);
  float* scores = (float*)(ws + OFF_SCO);
  u16*   att    = (u16*)(ws + OFF_ATT);
  u16*   whb    = (u16*)(ws + OFF_WHB);
  float* gates  = out + (size_t)Bn * Tn * Vn;

  __half* wtC1_0h = wth;                    // 1310720 halfs
  __half* wtG1_0h = wth + 1310720;          // 655360
  __half* wtC1_1h = wth + 1966080;          // 1572864
  __half* wtG1_1h = wth + 3538944;          // 786432
  __half* wc2h_0  = wth + 4325376;          // 524288
  __half* wc2h_1  = wth + 4849664;          // 524288
  __half* wrh_0   = wth + 5373952;          // 131072
  __half* wrh_1   = wth + 5505024;          // 262144

  hipMemsetAsync(ws, 0, 24576, stream);     // flags + n0 + gateP

  transpose_h<<<dim3(32, 40), 256, 0, stream>>>(Wc1_0, wtC1_0h, 1280, 1024);
  transpose_h<<<dim3(16, 40), 256, 0, stream>>>(Wg1_0, wtG1_0h, 1280, 512);
  transpose_h<<<dim3(32, 48), 256, 0, stream>>>(Wc1_1, wtC1_1h, 1536, 1024);
  transpose_h<<<dim3(16, 48), 256, 0, stream>>>(Wg1_1, wtG1_1h, 1536, 512);
  conv16_kernel<<<dim3(256), 256, 0, stream>>>(Wc2_0, wc2h_0, 524288);
  conv16_kernel<<<dim3(256), 256, 0, stream>>>(Wc2_1, wc2h_1, 524288);
  conv16_kernel<<<dim3(128), 256, 0, stream>>>(Wr_0,  wrh_0,  131072);
  conv16_kernel<<<dim3(256), 256, 0, stream>>>(Wr_1,  wrh_1,  262144);

  convwh_kernel<<<dim3(99, 512), 256, 0, stream>>>(Wh, whb);

  (void)hipFuncSetAttribute((const void*)rec_kernel,
                            hipFuncAttributeMaxDynamicSharedMemorySize, REC_LDS);

  rec_kernel<<<dim3(NBLK), dim3(RNT), REC_LDS, stream>>>(
      ids, emb,
      wtC1_0h, wtG1_0h, wtC1_1h, wtG1_1h,
      wc2h_0, wc2h_1, wrh_0, wrh_1,
      bc1_0, bg1_0, bc2_0, br_0, Wg2_0, bg2_0,
      bc1_1, bg1_1, bc2_1, br_1, Wg2_1, bg2_1,
      n0buf, gatePb, candPb, rPb, flags, histN, gates);

  scores_kernel<<<dim3(256), 256, 0, stream>>>(histN, Wa1, ba1, Wa2, ba2, scores);

  cumsum_kernel<<<dim3(Bn), 256, 0, stream>>>(scores, histN, att);

  gemm_kernel<<<dim3(393, 16), 256, 0, stream>>>(att, whb, bh, out);
}

// Round 6
// 9082.426 us; speedup vs baseline: 2.6007x; 2.6007x over previous
//
#include <hip/hip_runtime.h>
#include <hip/hip_fp16.h>
#include <cstdint>
#include <cstddef>

typedef unsigned short u16;
typedef unsigned int   u32;
typedef unsigned long long u64;

#define Bn 4
#define Tn 512
#define Hn 512
#define En 256
#define Vn 50257
#define NPAD 50304
#define RG  128
#define RNT 256

typedef _Float16 h2t __attribute__((ext_vector_type(2)));

#if defined(__has_builtin)
#if __has_builtin(__builtin_amdgcn_fdot2)
#define HAS_FDOT2 1
#endif
#endif
__device__ __forceinline__ float fdot2f(h2t a, h2t b, float c) {
#ifdef HAS_FDOT2
  return __builtin_amdgcn_fdot2(a, b, c, false);
#else
  return fmaf((float)a[0], (float)b[0], fmaf((float)a[1], (float)b[1], c));
#endif
}

__device__ __forceinline__ u16 f2bf(float f) {
  u32 x; __builtin_memcpy(&x, &f, 4);
  u32 r = (x + 0x7fffu + ((x >> 16) & 1u)) >> 16;
  return (u16)r;
}
__device__ __forceinline__ u64 packPT(float v, u32 tag) {
  u32 b; __builtin_memcpy(&b, &v, 4);
  return ((u64)tag << 32) | (u64)b;
}
__device__ __forceinline__ float unpackP(u64 v) {
  u32 b = (u32)v; float f; __builtin_memcpy(&f, &b, 4); return f;
}
__device__ __forceinline__ u64 gldu64(const u64* p) {
  return __hip_atomic_load(p, __ATOMIC_RELAXED, __HIP_MEMORY_SCOPE_AGENT);
}
__device__ __forceinline__ void gstu64(u64* p, u64 v) {
  __hip_atomic_store(p, v, __ATOMIC_RELAXED, __HIP_MEMORY_SCOPE_AGENT);
}
__device__ __forceinline__ u32 gldu32(const u32* p) {
  return __hip_atomic_load(p, __ATOMIC_RELAXED, __HIP_MEMORY_SCOPE_AGENT);
}
__device__ __forceinline__ void gstu32(u32* p, u32 v) {
  __hip_atomic_store(p, v, __ATOMIC_RELAXED, __HIP_MEMORY_SCOPE_AGENT);
}
__device__ __forceinline__ void gstf(float* p, float v) {
  __hip_atomic_store(p, v, __ATOMIC_RELAXED, __HIP_MEMORY_SCOPE_AGENT);
}

// ---------------- prep: transpose + fp32->fp16 (col-major) ----------------
__global__ __launch_bounds__(256) void transpose_h(
    const float* __restrict__ src, __half* __restrict__ dst, int K, int N)
{
  __shared__ float tile[32][33];
  const int tx = threadIdx.x & 31, ty = threadIdx.x >> 5;
  const int bn = blockIdx.x * 32, bk = blockIdx.y * 32;
  #pragma unroll
  for (int i = 0; i < 4; ++i)
    tile[ty + i * 8][tx] = src[(size_t)(bk + ty + i * 8) * N + bn + tx];
  __syncthreads();
  #pragma unroll
  for (int i = 0; i < 4; ++i)
    dst[(size_t)(bn + ty + i * 8) * K + bk + tx] = __float2half(tile[tx][ty + i * 8]);
}

// ---------------- prep: Wh fp32 -> bf16 padded [512][NPAD] ----------------
__global__ __launch_bounds__(256) void convwh_kernel(
    const float* __restrict__ wh, u16* __restrict__ whb)
{
  const int k = blockIdx.y;
  const int v0 = (blockIdx.x * 256 + threadIdx.x) * 2;
  if (v0 >= NPAD) return;
  float a = (v0     < Vn) ? wh[(size_t)k * Vn + v0]     : 0.f;
  float b = (v0 + 1 < Vn) ? wh[(size_t)k * Vn + v0 + 1] : 0.f;
  u32 pack = (u32)f2bf(a) | ((u32)f2bf(b) << 16);
  *(u32*)&whb[(size_t)k * NPAD + v0] = pack;
}

// ---- dynamic LDS byte offsets ----
#define XBLH_B  98304
#define XCAND_B 110592
#define HRAW_B  118784
#define HRAW0_B 126976
#define GP_B    135168
#define CTMP_B  136192
#define HLOC_B  136480
#define RLOC_B  136608
#define STW_B   136736
#define STW0_B  136864
#define GATEL_B 136992
#define BC1L_B  137008
#define BG1L_B  137072
#define BC2L_B  137104
#define BRL_B   137136
#define WG2L_B  137168
#define BG2L_B  137200
#define REC_LDS 137216

// ---------------- persistent recurrence: self-detecting message passing ----------------
// 128 blocks: l = g>>6 (layer), gl = g&63. l0 tick n -> step n ; l1 tick n -> step n-1.
__global__ __launch_bounds__(RNT, 1) void rec_kernel(
    const int* __restrict__ ids, const float* __restrict__ emb,
    const __half* wtC1_0, const __half* wtG1_0, const __half* wtC2_0, const __half* wtR_0,
    const __half* wtC1_1, const __half* wtG1_1, const __half* wtC2_1, const __half* wtR_1,
    const float* bc1_0, const float* bg1_0, const float* bc2_0, const float* br_0,
    const float* wg2_0, const float* bg2_0,
    const float* bc1_1, const float* bg1_1, const float* bc2_1, const float* br_1,
    const float* wg2_1, const float* bg2_1,
    u32* flagA, u64* HB, u64* CB,
    float* __restrict__ histN, float* __restrict__ gates_out)
{
  extern __shared__ char smem[];
  __half* WL    = (__half*)smem;
  __half* xblh  = (__half*)(smem + XBLH_B);    // [4][1536]
  __half* xcand = (__half*)(smem + XCAND_B);   // [4][1024]
  float* hraw   = (float*)(smem + HRAW_B);     // [4][512]
  float* hraw0  = (float*)(smem + HRAW0_B);    // [4][512]
  float* gp     = (float*)(smem + GP_B);       // [64][4]
  float* ctmp   = (float*)(smem + CTMP_B);     // [68]
  float* hloc   = (float*)(smem + HLOC_B);     // [32]
  float* rloc   = (float*)(smem + RLOC_B);     // [32]
  float* stw    = (float*)(smem + STW_B);      // [4][8]
  float* stw0   = (float*)(smem + STW0_B);     // [4][8]
  float* gateL  = (float*)(smem + GATEL_B);    // [4]
  float* bc1L   = (float*)(smem + BC1L_B);
  float* bg1L   = (float*)(smem + BG1L_B);
  float* bc2L   = (float*)(smem + BC2L_B);
  float* brL    = (float*)(smem + BRL_B);
  float* wg2L   = (float*)(smem + WG2L_B);
  float* bg2L   = (float*)(smem + BG2L_B);

  const int tid = threadIdx.x, g = blockIdx.x;
  const int l = g >> 6, gl = g & 63;
  const int w = tid >> 6, lane = tid & 63;
  const int C = l ? 1536 : 1280;
  const int e = l ? 512 : 256;
  const int oG1 = 16 * C, oR = 24 * C, oC2 = 24 * C + 8 * e;

  const __half* wtC1 = l ? wtC1_1 : wtC1_0;
  const __half* wtG1 = l ? wtG1_1 : wtG1_0;
  const __half* wtC2 = l ? wtC2_1 : wtC2_0;
  const __half* wtR  = l ? wtR_1  : wtR_0;
  const float* bc1 = l ? bc1_1 : bc1_0;
  const float* bg1 = l ? bg1_1 : bg1_0;
  const float* bc2 = l ? bc2_1 : bc2_0;
  const float* br  = l ? br_1  : br_0;
  const float* wg2 = l ? wg2_1 : wg2_0;
  const float* bg2 = l ? bg2_1 : bg2_0;

  // ---- one-time staging: weight slices (col-major fp16) -> LDS ----
  {
    auto cp = [&](const __half* src, int nh, int offh) {
      const u32* s = (const u32*)src; u32* d = (u32*)(WL + offh);
      for (int i = tid; i < (nh >> 1); i += RNT) d[i] = s[i];
    };
    cp(wtC1 + (size_t)(gl * 16) * C, 16 * C, 0);
    cp(wtG1 + (size_t)(gl * 8) * C,  8 * C, oG1);
    cp(wtR  + (size_t)(gl * 8) * e,  8 * e, oR);
    cp(wtC2 + (size_t)(gl * 8) * 1024, 8 * 1024, oC2);
  }
  if (tid < 16)      bc1L[tid] = bc1[gl * 16 + tid];
  else if (tid < 24) bg1L[tid - 16] = bg1[gl * 8 + tid - 16];
  else if (tid < 32) bc2L[tid - 24] = bc2[gl * 8 + tid - 24];
  else if (tid < 40) brL[tid - 32]  = br[gl * 8 + tid - 32];
  else if (tid < 48) wg2L[tid - 40] = wg2[gl * 8 + tid - 40];
  else if (tid == 48) bg2L[0] = bg2[0];
  // zero xblh + xcand + hraw + hraw0 + gp (bytes 98304..136192)
  for (int i = tid; i < 9472; i += RNT) ((u32*)(smem + XBLH_B))[i] = 0;
  __syncthreads();

  const int nEnd = l ? (Tn + 1) : (Tn - 1);

  for (int n = 0; n <= nEnd; ++n) {
    const int t = n - l;
    const bool prod = (t >= 0) && (t < Tn);
    const bool pollOwn = (t >= 1) && (t <= Tn);
    const bool pollL0  = (l == 1) && prod;

    // ---- early loads (l0): ids + emb row ----
    float4 embv = make_float4(0.f, 0.f, 0.f, 0.f);
    if (l == 0 && prod) {
      int idv = ids[w * Tn + t];
      embv = *(const float4*)(emb + (size_t)idv * En + lane * 4);
    }

    // ---- Phase A: poll h-broadcast (self-detecting 8B words) ----
    if (pollOwn || pollL0) {
      const int parR = (n - 1) & 1;
      const int p = tid >> 2, q0 = (tid & 3) * 8;
      const u64* s1 = HB + ((size_t)(l * 2 + parR) * 64 + p) * 32 + q0;
      const u64* s0 = HB + ((size_t)(parR) * 64 + p) * 32 + q0;
      const u32 want = (u32)n;
      u64 v1[8], v0[8];
      for (;;) {
        bool ok = true;
        if (pollOwn) {
          #pragma unroll
          for (int i = 0; i < 8; ++i) v1[i] = gldu64(s1 + i);
          #pragma unroll
          for (int i = 0; i < 8; ++i) ok &= ((u32)(v1[i] >> 32) == want);
        }
        if (pollL0) {
          #pragma unroll
          for (int i = 0; i < 8; ++i) v0[i] = gldu64(s0 + i);
          #pragma unroll
          for (int i = 0; i < 8; ++i) ok &= ((u32)(v0[i] >> 32) == want);
        }
        if (ok) break;
      }
      if (pollOwn) {
        #pragma unroll
        for (int i = 0; i < 8; ++i) {
          int u = q0 + i;
          hraw[(u & 3) * 512 + p * 8 + (u >> 2)] = unpackP(v1[i]);
        }
      }
      if (pollL0) {
        #pragma unroll
        for (int i = 0; i < 8; ++i) {
          int u = q0 + i;
          hraw0[(u & 3) * 512 + p * 8 + (u >> 2)] = unpackP(v0[i]);
        }
      }
    }
    __syncthreads();
    if (l == 1 && tid == 0) gstu32(flagA + gl * 16, (u32)(n + 1));

    // ---- stats (block-local, from full raw h) ----
    float m4[4], i4[4], m0v[4], i0v[4];
    const bool needStats = prod || pollOwn;
    if (needStats) {
      int j = tid * 2;
      float s[4], q[4];
      #pragma unroll
      for (int b = 0; b < 4; ++b) {
        float a0 = hraw[b * 512 + j], a1 = hraw[b * 512 + j + 1];
        s[b] = a0 + a1; q[b] = a0 * a0 + a1 * a1;
      }
      float s0_[4], q0_[4];
      if (pollL0) {
        #pragma unroll
        for (int b = 0; b < 4; ++b) {
          float a0 = hraw0[b * 512 + j], a1 = hraw0[b * 512 + j + 1];
          s0_[b] = a0 + a1; q0_[b] = a0 * a0 + a1 * a1;
        }
      }
      #pragma unroll
      for (int off = 32; off; off >>= 1) {
        #pragma unroll
        for (int b = 0; b < 4; ++b) {
          s[b] += __shfl_xor(s[b], off); q[b] += __shfl_xor(q[b], off);
          if (pollL0) { s0_[b] += __shfl_xor(s0_[b], off); q0_[b] += __shfl_xor(q0_[b], off); }
        }
      }
      if (lane == 0) {
        #pragma unroll
        for (int b = 0; b < 4; ++b) {
          stw[w * 8 + b] = s[b]; stw[w * 8 + 4 + b] = q[b];
          if (pollL0) { stw0[w * 8 + b] = s0_[b]; stw0[w * 8 + 4 + b] = q0_[b]; }
        }
      }
    }
    __syncthreads();
    if (needStats) {
      #pragma unroll
      for (int b = 0; b < 4; ++b) {
        float S = stw[b] + stw[8 + b] + stw[16 + b] + stw[24 + b];
        float Q = stw[4 + b] + stw[12 + b] + stw[20 + b] + stw[28 + b];
        float m = S * (1.f / 512.f);
        m4[b] = m; i4[b] = rsqrtf(Q * (1.f / 512.f) - m * m + 1e-5f);
        if (pollL0) {
          float S0 = stw0[b] + stw0[8 + b] + stw0[16 + b] + stw0[24 + b];
          float Q0 = stw0[4 + b] + stw0[12 + b] + stw0[20 + b] + stw0[28 + b];
          float mm = S0 * (1.f / 512.f);
          m0v[b] = mm; i0v[b] = rsqrtf(Q0 * (1.f / 512.f) - mm * mm + 1e-5f);
        }
      }
    }

    // ---- histN for last layer (normalized h of step t-1) ----
    if (l == 1 && t >= 1 && t <= Tn && tid < 32) {
      int c = tid >> 2, b = tid & 3, j = gl * 8 + c;
      gstf(histN + ((size_t)(b * Tn + (t - 1))) * Hn + j,
           (hraw[b * 512 + j] - m4[b]) * i4[b]);
    }

    // ---- ctx update: shift h1->h2, write LN(h1), write inp ----
    if (prod) {
      int j = tid * 2;
      #pragma unroll
      for (int b = 0; b < 4; ++b) {
        #pragma unroll
        for (int jj = 0; jj < 2; ++jj) {
          __half old = xblh[b * 1536 + j + jj];
          xblh[b * 1536 + 512 + j + jj] = old;
          xblh[b * 1536 + j + jj] = __float2half((hraw[b * 512 + j + jj] - m4[b]) * i4[b]);
        }
      }
      if (l == 0) {
        #pragma unroll
        for (int ii = 0; ii < 4; ++ii)
          xblh[w * 1536 + 1024 + lane * 4 + ii] = __float2half(((const float*)&embv)[ii]);
      } else {
        #pragma unroll
        for (int b = 0; b < 4; ++b)
          #pragma unroll
          for (int jj = 0; jj < 2; ++jj)
            xblh[b * 1536 + 1024 + j + jj] =
              __float2half((hraw0[b * 512 + j + jj] - m0v[b]) * i0v[b]);
      }
    }
    __syncthreads();

    // ---- matvec1 (fdot2, LDS weights): waves 0/1: Wc1 (8 cols each); w2: Wg1; w3: Wr ----
    if (prod) {
      const __half* wb; int K2, xo;
      if (w < 2)       { wb = WL + w * 8 * C; K2 = C; xo = 0; }
      else if (w == 2) { wb = WL + oG1;       K2 = C; xo = 0; }
      else             { wb = WL + oR;        K2 = e; xo = 1024; }
      float acc[8][4];
      #pragma unroll
      for (int c = 0; c < 8; ++c)
        #pragma unroll
        for (int b = 0; b < 4; ++b) acc[c][b] = 0.f;
      for (int p2 = lane; p2 < (K2 >> 1); p2 += 64) {
        h2t xv[4];
        #pragma unroll
        for (int b = 0; b < 4; ++b)
          xv[b] = *(const h2t*)(xblh + b * 1536 + xo + 2 * p2);
        #pragma unroll
        for (int c = 0; c < 8; ++c) {
          h2t wv = *(const h2t*)(wb + c * K2 + 2 * p2);
          #pragma unroll
          for (int b = 0; b < 4; ++b) acc[c][b] = fdot2f(wv, xv[b], acc[c][b]);
        }
      }
      #pragma unroll
      for (int off = 32; off; off >>= 1)
        #pragma unroll
        for (int c = 0; c < 8; ++c)
          #pragma unroll
          for (int b = 0; b < 4; ++b) acc[c][b] += __shfl_xor(acc[c][b], off);
      float v[4] = {0.f, 0.f, 0.f, 0.f};
      #pragma unroll
      for (int c = 0; c < 8; ++c)
        if (lane == c) { v[0] = acc[c][0]; v[1] = acc[c][1]; v[2] = acc[c][2]; v[3] = acc[c][3]; }
      if (w < 2) {
        if (lane < 8) {
          float bb = bc1L[w * 8 + lane];
          #pragma unroll
          for (int b = 0; b < 4; ++b) ctmp[(w * 8 + lane) * 4 + b] = fmaxf(v[b] + bb, 0.f);
        }
      } else if (w == 2) {
        if (lane < 8) {
          float bb = bg1L[lane], wgv = wg2L[lane];
          float tb[4];
          #pragma unroll
          for (int b = 0; b < 4; ++b) tb[b] = tanhf(v[b] + bb) * wgv;
          #pragma unroll
          for (int off = 1; off < 8; off <<= 1)
            #pragma unroll
            for (int b = 0; b < 4; ++b) tb[b] += __shfl_xor(tb[b], off);
          if (lane == 0) {
            #pragma unroll
            for (int b = 0; b < 4; ++b) ctmp[64 + b] = tb[b];
          }
        }
      } else {
        if (lane < 8) {
          #pragma unroll
          for (int b = 0; b < 4; ++b) rloc[lane * 4 + b] = v[b] + brL[lane];
        }
      }
    }
    __syncthreads();
    // ---- CB store: 68 tagged words ----
    if (prod && tid < 68) {
      u64* CBw = CB + ((size_t)(l * 2 + (n & 1)) * 64 + gl) * 72;
      gstu64(CBw + tid, packPT(ctmp[tid], (u32)(n + 1)));
    }

    // ---- Phase B: poll cand1-broadcast (+ l0: l1 backpressure flag) ----
    if (prod) {
      const u64* CBL = CB + ((size_t)(l * 2 + (n & 1)) * 64) * 72;
      const int p = tid >> 2, w0 = (tid & 3) * 17;
      const u64* src = CBL + (size_t)p * 72 + w0;
      const u32 want = (u32)(n + 1);
      const bool checkF = (l == 0) && (tid < 64);
      const u32* fptr = flagA + (tid & 63) * 16;
      u64 vals[17];
      for (;;) {
        bool ok = true;
        #pragma unroll
        for (int i = 0; i < 17; ++i) vals[i] = gldu64(src + i);
        #pragma unroll
        for (int i = 0; i < 17; ++i) ok &= ((u32)(vals[i] >> 32) == want);
        if (checkF) ok &= (gldu32(fptr) >= (u32)n);
        if (ok) break;
      }
      #pragma unroll
      for (int i = 0; i < 17; ++i) {
        int u = w0 + i;
        float pv = unpackP(vals[i]);
        if (u < 64) xcand[(u & 3) * 1024 + p * 16 + (u >> 2)] = __float2half(pv);
        else        gp[p * 4 + (u - 64)] = pv;
      }
    }
    __syncthreads();

    // ---- gate reduce (wave 0) + matvec2 (all waves, fdot2) ----
    float a2[2][4];
    #pragma unroll
    for (int cc = 0; cc < 2; ++cc)
      #pragma unroll
      for (int b = 0; b < 4; ++b) a2[cc][b] = 0.f;
    if (prod) {
      if (w == 0) {
        float gs[4];
        #pragma unroll
        for (int b = 0; b < 4; ++b) gs[b] = gp[lane * 4 + b];
        #pragma unroll
        for (int off = 32; off; off >>= 1)
          #pragma unroll
          for (int b = 0; b < 4; ++b) gs[b] += __shfl_xor(gs[b], off);
        if (lane == 0) {
          #pragma unroll
          for (int b = 0; b < 4; ++b) gateL[b] = 1.f / (1.f + expf(-(gs[b] + bg2L[0])));
        }
      }
      const __half* wb2 = WL + oC2 + (w * 2) * 1024;
      for (int p2 = lane; p2 < 512; p2 += 64) {
        h2t xv[4];
        #pragma unroll
        for (int b = 0; b < 4; ++b)
          xv[b] = *(const h2t*)(xcand + b * 1024 + 2 * p2);
        #pragma unroll
        for (int cc = 0; cc < 2; ++cc) {
          h2t wv = *(const h2t*)(wb2 + cc * 1024 + 2 * p2);
          #pragma unroll
          for (int b = 0; b < 4; ++b) a2[cc][b] = fdot2f(wv, xv[b], a2[cc][b]);
        }
      }
      #pragma unroll
      for (int off = 32; off; off >>= 1)
        #pragma unroll
        for (int cc = 0; cc < 2; ++cc)
          #pragma unroll
          for (int b = 0; b < 4; ++b) a2[cc][b] += __shfl_xor(a2[cc][b], off);
    }
    __syncthreads();   // gateL ready

    // ---- finalize h ----
    if (prod) {
      float sel = 0.f;
      #pragma unroll
      for (int cc = 0; cc < 2; ++cc)
        #pragma unroll
        for (int b = 0; b < 4; ++b)
          if (lane == cc * 4 + b) sel = a2[cc][b];
      if (lane < 8) {
        int cc = lane >> 2, b = lane & 3, cl = w * 2 + cc;
        float cand = sel + bc2L[cl];
        float h1n = __half2float(xblh[b * 1536 + gl * 8 + cl]);
        float hv = h1n + gateL[b] * cand + 0.1f * rloc[cl * 4 + b];
        hloc[cl * 4 + b] = hv;
      }
    }
    __syncthreads();

    // ---- HB store (tagged) + gates ----
    if (prod) {
      u64* HBw = HB + ((size_t)(l * 2 + (n & 1)) * 64 + gl) * 32;
      if (tid < 32) gstu64(HBw + tid, packPT(hloc[tid], (u32)(n + 1)));
      if (l == 1 && gl == 0 && tid >= 32 && tid < 36)
        gstf(gates_out + (tid - 32) * Tn + t, gateL[tid - 32]);
    }
  }
}

// ---------------- attention scores (histN already normalized) ----------------
__global__ __launch_bounds__(256) void scores_kernel(
    const float* __restrict__ histN,
    const float* __restrict__ wa1, const float* __restrict__ ba1,
    const float* __restrict__ wa2, const float* __restrict__ ba2,
    float* __restrict__ scores)
{
  __shared__ float xs[8][512];
  __shared__ float wacc[4][8];
  const int tid = threadIdx.x, bid = blockIdx.x;

  for (int idx = tid; idx < 4096; idx += 256)
    xs[idx >> 9][idx & 511] = histN[(size_t)(bid * 8) * Hn + idx];
  __syncthreads();

  float pr[8] = {0.f,0.f,0.f,0.f,0.f,0.f,0.f,0.f};
  #pragma unroll
  for (int cc = 0; cc < 2; ++cc) {
    int c = tid + cc * 256;
    float a[8] = {0.f,0.f,0.f,0.f,0.f,0.f,0.f,0.f};
    for (int k = 0; k < 512; ++k) {
      float wv = wa1[(size_t)k * 512 + c];
      #pragma unroll
      for (int r = 0; r < 8; ++r) a[r] = fmaf(xs[r][k], wv, a[r]);
    }
    float b1 = ba1[c], w2 = wa2[c];
    #pragma unroll
    for (int r = 0; r < 8; ++r) pr[r] += tanhf(a[r] + b1) * w2;
  }
  int lane = tid & 63, wq = tid >> 6;
  #pragma unroll
  for (int off = 32; off; off >>= 1)
    #pragma unroll
    for (int r = 0; r < 8; ++r) pr[r] += __shfl_xor(pr[r], off);
  if (lane == 0) {
    #pragma unroll
    for (int r = 0; r < 8; ++r) wacc[wq][r] = pr[r];
  }
  __syncthreads();
  if (tid < 8)
    scores[bid * 8 + tid] = wacc[0][tid] + wacc[1][tid] + wacc[2][tid] + wacc[3][tid] + ba2[0];
}

// ---------------- prefix-softmax cumsum -> attended (bf16) ----------------
__global__ __launch_bounds__(256) void cumsum_kernel(
    const float* __restrict__ scores, const float* __restrict__ histN,
    u16* __restrict__ att)
{
  __shared__ float ee[512], den[512], sb[512], red[256];
  const int tid = threadIdx.x, b = blockIdx.x;
  float s0 = scores[b * Tn + tid], s1 = scores[b * Tn + tid + 256];
  red[tid] = fmaxf(s0, s1);
  __syncthreads();
  for (int s = 128; s; s >>= 1) { if (tid < s) red[tid] = fmaxf(red[tid], red[tid + s]); __syncthreads(); }
  float m = red[0];
  ee[tid] = expf(s0 - m); ee[tid + 256] = expf(s1 - m);
  den[tid] = ee[tid]; den[tid + 256] = ee[tid + 256];
  __syncthreads();
  float* A = den; float* D = sb;
  for (int off = 1; off < 512; off <<= 1) {
    for (int t2 = tid; t2 < 512; t2 += 256) { float v = A[t2]; if (t2 >= off) v += A[t2 - off]; D[t2] = v; }
    __syncthreads();
    float* tmp = A; A = D; D = tmp;
  }
  float* R = D;
  for (int t2 = tid; t2 < 512; t2 += 256) R[t2] = 1.f / A[t2];
  __syncthreads();

  const int h0 = tid * 2;
  float ax = 0.f, ay = 0.f;
  for (int t = 0; t < 512; ++t) {
    const float* hpp = histN + ((size_t)(b * Tn + t)) * Hn + h0;
    float x0 = hpp[0], x1 = hpp[1];
    float et = ee[t], rd = R[t];
    ax = fmaf(et, x0, ax); ay = fmaf(et, x1, ay);
    u32 pack = (u32)f2bf(x0 + ax * rd) | ((u32)f2bf(x1 + ay * rd) << 16);
    *(u32*)(att + ((size_t)(b * Tn + t)) * Hn + h0) = pack;
  }
}

// ---------------- final GEMM: att[2048x512]bf16 @ WhB[512xNPAD]bf16 + bh -> fp32 ----------------
typedef short bf16x8_t __attribute__((ext_vector_type(8)));
typedef float f32x4_t  __attribute__((ext_vector_type(4)));

__global__ __launch_bounds__(256) void gemm_kernel(
    const u16* __restrict__ Aw, const u16* __restrict__ Bw,
    const float* __restrict__ bh, float* __restrict__ out)
{
  __shared__ u16 Alds[128 * 64];
  __shared__ u16 Blds[64 * 128];
  const int tid = threadIdx.x;
  const int n0 = blockIdx.x * 128, m0 = blockIdx.y * 128;
  const int w = tid >> 6, lane = tid & 63;
  const int wm = (w & 1) * 64, wn = (w >> 1) * 64;

  f32x4_t acc[4][4];
  #pragma unroll
  for (int i = 0; i < 4; ++i)
    #pragma unroll
    for (int j = 0; j < 4; ++j) acc[i][j] = (f32x4_t){0.f, 0.f, 0.f, 0.f};

  for (int kt = 0; kt < 8; ++kt) {
    const int k0 = kt * 64;
    {
      int row = tid >> 1, kc = (tid & 1) * 32;
      #pragma unroll
      for (int jj = 0; jj < 4; ++jj) {
        uint4 v = *(const uint4*)(Aw + (size_t)(m0 + row) * 512 + k0 + kc + jj * 8);
        int byte = row * 128 + (kc + jj * 8) * 2;
        byte ^= (row & 7) << 4;
        *(uint4*)((char*)Alds + byte) = v;
      }
    }
    {
      #pragma unroll
      for (int q = 0; q < 4; ++q) {
        int r = (tid >> 4) + q * 16, c8 = (tid & 15) * 8;
        uint4 v = *(const uint4*)(Bw + (size_t)(k0 + r) * NPAD + n0 + c8);
        *(uint4*)&Blds[r * 128 + c8] = v;
      }
    }
    __syncthreads();
    #pragma unroll
    for (int kh = 0; kh < 2; ++kh) {
      bf16x8_t af[4];
      #pragma unroll
      for (int i = 0; i < 4; ++i) {
        int row = wm + i * 16 + (lane & 15);
        int byte = row * 128 + kh * 64 + (lane >> 4) * 16;
        byte ^= (row & 7) << 4;
        af[i] = *(const bf16x8_t*)((const char*)Alds + byte);
      }
      const int kb = kh * 32 + (lane >> 4) * 8;
      #pragma unroll
      for (int j = 0; j < 4; ++j) {
        int col = wn + j * 16 + (lane & 15);
        bf16x8_t bf;
        #pragma unroll
        for (int jj = 0; jj < 8; ++jj) bf[jj] = (short)Blds[(kb + jj) * 128 + col];
        #pragma unroll
        for (int i = 0; i < 4; ++i)
          acc[i][j] = __builtin_amdgcn_mfma_f32_16x16x32_bf16(af[i], bf, acc[i][j], 0, 0, 0);
      }
    }
    __syncthreads();
  }
  #pragma unroll
  for (int j = 0; j < 4; ++j) {
    int col = n0 + wn + j * 16 + (lane & 15);
    if (col < Vn) {
      float bias = bh[col];
      #pragma unroll
      for (int i = 0; i < 4; ++i) {
        int rbase = m0 + wm + i * 16 + (lane >> 4) * 4;
        #pragma unroll
        for (int r = 0; r < 4; ++r)
          out[(size_t)(rbase + r) * Vn + col] = acc[i][j][r] + bias;
      }
    }
  }
}

// ---------------- host ----------------
extern "C" void kernel_launch(void* const* d_in, const int* in_sizes, int n_in,
                              void* d_out, int out_size, void* d_ws, size_t ws_size,
                              hipStream_t stream) {
  const int*   ids  = (const int*)d_in[0];
  const float* emb  = (const float*)d_in[1];
  const float* Wc1_0 = (const float*)d_in[2];  const float* bc1_0 = (const float*)d_in[3];
  const float* Wc2_0 = (const float*)d_in[4];  const float* bc2_0 = (const float*)d_in[5];
  const float* Wg1_0 = (const float*)d_in[6];  const float* bg1_0 = (const float*)d_in[7];
  const float* Wg2_0 = (const float*)d_in[8];  const float* bg2_0 = (const float*)d_in[9];
  const float* Wr_0  = (const float*)d_in[10]; const float* br_0  = (const float*)d_in[11];
  const float* Wc1_1 = (const float*)d_in[12]; const float* bc1_1 = (const float*)d_in[13];
  const float* Wc2_1 = (const float*)d_in[14]; const float* bc2_1 = (const float*)d_in[15];
  const float* Wg1_1 = (const float*)d_in[16]; const float* bg1_1 = (const float*)d_in[17];
  const float* Wg2_1 = (const float*)d_in[18]; const float* bg2_1 = (const float*)d_in[19];
  const float* Wr_1  = (const float*)d_in[20]; const float* br_1  = (const float*)d_in[21];
  const float* Wa1 = (const float*)d_in[22]; const float* ba1 = (const float*)d_in[23];
  const float* Wa2 = (const float*)d_in[24]; const float* ba2 = (const float*)d_in[25];
  const float* Wh  = (const float*)d_in[26]; const float* bh  = (const float*)d_in[27];

  float* out = (float*)d_out;
  char*  ws  = (char*)d_ws;

  const size_t OFF_FLAGA = 0;                          // 4096
  const size_t OFF_HB    = 4096;                       // 65536
  const size_t OFF_CB    = 69632;                      // 147456
  const size_t OFF_WT    = 217088;                     // 11534336
  const size_t OFF_HISTN = OFF_WT + 11534336;          // 4 MB
  const size_t OFF_SCO   = OFF_HISTN + 4194304;        // 8 KB
  const size_t OFF_ATT   = OFF_SCO + 8192;             // 2 MB
  const size_t OFF_WHB   = OFF_ATT + 2097152;          // 51.5 MB

  u32*   flagA  = (u32*)(ws + OFF_FLAGA);
  u64*   HB     = (u64*)(ws + OFF_HB);
  u64*   CB     = (u64*)(ws + OFF_CB);
  __half* wth   = (__half*)(ws + OFF_WT);
  float* histN  = (float*)(ws + OFF_HISTN);
  float* scores = (float*)(ws + OFF_SCO);
  u16*   att    = (u16*)(ws + OFF_ATT);
  u16*   whb    = (u16*)(ws + OFF_WHB);
  float* gates  = out + (size_t)Bn * Tn * Vn;

  __half* wtC1_0h = wth;
  __half* wtG1_0h = wth + 1310720;
  __half* wtC2_0h = wth + 1966080;
  __half* wtR_0h  = wth + 2490368;
  __half* wtC1_1h = wth + 2621440;
  __half* wtG1_1h = wth + 4194304;
  __half* wtC2_1h = wth + 4980736;
  __half* wtR_1h  = wth + 5505024;

  hipMemsetAsync(ws, 0, 217088, stream);   // flagA + HB + CB tags

  transpose_h<<<dim3(32, 40), 256, 0, stream>>>(Wc1_0, wtC1_0h, 1280, 1024);
  transpose_h<<<dim3(16, 40), 256, 0, stream>>>(Wg1_0, wtG1_0h, 1280, 512);
  transpose_h<<<dim3(16, 32), 256, 0, stream>>>(Wc2_0, wtC2_0h, 1024, 512);
  transpose_h<<<dim3(16,  8), 256, 0, stream>>>(Wr_0,  wtR_0h,   256, 512);
  transpose_h<<<dim3(32, 48), 256, 0, stream>>>(Wc1_1, wtC1_1h, 1536, 1024);
  transpose_h<<<dim3(16, 48), 256, 0, stream>>>(Wg1_1, wtG1_1h, 1536, 512);
  transpose_h<<<dim3(16, 32), 256, 0, stream>>>(Wc2_1, wtC2_1h, 1024, 512);
  transpose_h<<<dim3(16, 16), 256, 0, stream>>>(Wr_1,  wtR_1h,   512, 512);

  convwh_kernel<<<dim3(99, 512), 256, 0, stream>>>(Wh, whb);

  (void)hipFuncSetAttribute((const void*)rec_kernel,
                            hipFuncAttributeMaxDynamicSharedMemorySize, REC_LDS);

  rec_kernel<<<dim3(RG), dim3(RNT), REC_LDS, stream>>>(
      ids, emb,
      wtC1_0h, wtG1_0h, wtC2_0h, wtR_0h,
      wtC1_1h, wtG1_1h, wtC2_1h, wtR_1h,
      bc1_0, bg1_0, bc2_0, br_0, Wg2_0, bg2_0,
      bc1_1, bg1_1, bc2_1, br_1, Wg2_1, bg2_1,
      flagA, HB, CB, histN, gates);

  scores_kernel<<<dim3(256), 256, 0, stream>>>(histN, Wa1, ba1, Wa2, ba2, scores);

  cumsum_kernel<<<dim3(Bn), 256, 0, stream>>>(scores, histN, att);

  gemm_kernel<<<dim3(393, 16), 256, 0, stream>>>(att, whb, bh, out);
}

// Round 7
// 7603.219 us; speedup vs baseline: 3.1066x; 1.1946x over previous
//
#include <hip/hip_runtime.h>
#include <hip/hip_fp16.h>
#include <cstdint>
#include <cstddef>

typedef unsigned short u16;
typedef unsigned int   u32;
typedef unsigned long long u64;

#define Bn 4
#define Tn 512
#define Hn 512
#define En 256
#define Vn 50257
#define NPAD 50304
#define RG  128
#define RNT 256

typedef _Float16 h2t __attribute__((ext_vector_type(2)));

#if defined(__has_builtin)
#if __has_builtin(__builtin_amdgcn_fdot2)
#define HAS_FDOT2 1
#endif
#endif
__device__ __forceinline__ float fdot2f(h2t a, h2t b, float c) {
#ifdef HAS_FDOT2
  return __builtin_amdgcn_fdot2(a, b, c, false);
#else
  return fmaf((float)a[0], (float)b[0], fmaf((float)a[1], (float)b[1], c));
#endif
}

__device__ __forceinline__ u16 f2bf(float f) {
  u32 x; __builtin_memcpy(&x, &f, 4);
  u32 r = (x + 0x7fffu + ((x >> 16) & 1u)) >> 16;
  return (u16)r;
}
__device__ __forceinline__ u16 f2h(float f) {
  __half hh = __float2half(f); u16 u; __builtin_memcpy(&u, &hh, 2); return u;
}
__device__ __forceinline__ float unpackP(u64 v) {
  u32 b = (u32)v; float f; __builtin_memcpy(&f, &b, 4); return f;
}
__device__ __forceinline__ u64 gldu64(const u64* p) {
  return __hip_atomic_load(p, __ATOMIC_RELAXED, __HIP_MEMORY_SCOPE_AGENT);
}
__device__ __forceinline__ void gstu64(u64* p, u64 v) {
  __hip_atomic_store(p, v, __ATOMIC_RELAXED, __HIP_MEMORY_SCOPE_AGENT);
}
__device__ __forceinline__ u32 gldu32(const u32* p) {
  return __hip_atomic_load(p, __ATOMIC_RELAXED, __HIP_MEMORY_SCOPE_AGENT);
}
__device__ __forceinline__ void gstu32(u32* p, u32 v) {
  __hip_atomic_store(p, v, __ATOMIC_RELAXED, __HIP_MEMORY_SCOPE_AGENT);
}
__device__ __forceinline__ void gstf(float* p, float v) {
  __hip_atomic_store(p, v, __ATOMIC_RELAXED, __HIP_MEMORY_SCOPE_AGENT);
}

// ---------------- prep: transpose + fp32->fp16 (col-major) ----------------
__global__ __launch_bounds__(256) void transpose_h(
    const float* __restrict__ src, __half* __restrict__ dst, int K, int N)
{
  __shared__ float tile[32][33];
  const int tx = threadIdx.x & 31, ty = threadIdx.x >> 5;
  const int bn = blockIdx.x * 32, bk = blockIdx.y * 32;
  #pragma unroll
  for (int i = 0; i < 4; ++i)
    tile[ty + i * 8][tx] = src[(size_t)(bk + ty + i * 8) * N + bn + tx];
  __syncthreads();
  #pragma unroll
  for (int i = 0; i < 4; ++i)
    dst[(size_t)(bn + ty + i * 8) * K + bk + tx] = __float2half(tile[tx][ty + i * 8]);
}

// ---------------- prep: Wh fp32 -> bf16 padded [512][NPAD] ----------------
__global__ __launch_bounds__(256) void convwh_kernel(
    const float* __restrict__ wh, u16* __restrict__ whb)
{
  const int k = blockIdx.y;
  const int v0 = (blockIdx.x * 256 + threadIdx.x) * 2;
  if (v0 >= NPAD) return;
  float a = (v0     < Vn) ? wh[(size_t)k * Vn + v0]     : 0.f;
  float b = (v0 + 1 < Vn) ? wh[(size_t)k * Vn + v0 + 1] : 0.f;
  u32 pack = (u32)f2bf(a) | ((u32)f2bf(b) << 16);
  *(u32*)&whb[(size_t)k * NPAD + v0] = pack;
}

// ---- dynamic LDS byte offsets ----
#define XBLH_B  98304
#define XCAND_B 110592
#define HRAW_B  118784
#define HRAW0_B 126976
#define GP_B    135168
#define RLOC_B  136192
#define STW_B   136320
#define STW0_B  136448
#define GATEL_B 136576
#define BC1L_B  136592
#define BG1L_B  136848
#define BC2L_B  136880
#define BRL_B   136912
#define WG2L_B  136944
#define BG2L_B  136976
#define REC_LDS 136992

// ---------------- persistent recurrence: coalesced self-detecting messages ----------------
// 128 blocks: l = g>>6 (layer), gl = g&63. l0 tick n -> step n ; l1 tick n -> step n-1.
// HB[(l,par)]: 64 prod x 32 u64 words (fp32 h + tag), linear.
// CB[(l,par)]: 64 prod x 36 u64 words (32 fp16-pair cand1 + 4 fp32 gate-partials), linear.
__global__ __launch_bounds__(RNT, 1) void rec_kernel(
    const int* __restrict__ ids, const float* __restrict__ emb,
    const __half* wtC1_0, const __half* wtG1_0, const __half* wtC2_0, const __half* wtR_0,
    const __half* wtC1_1, const __half* wtG1_1, const __half* wtC2_1, const __half* wtR_1,
    const float* bc1_0, const float* bg1_0, const float* bc2_0, const float* br_0,
    const float* wg2_0, const float* bg2_0,
    const float* bc1_1, const float* bg1_1, const float* bc2_1, const float* br_1,
    const float* wg2_1, const float* bg2_1,
    u32* flagA, u64* HB, u64* CB,
    float* __restrict__ histN, float* __restrict__ gates_out)
{
  extern __shared__ char smem[];
  __half* WL    = (__half*)smem;
  __half* xblh  = (__half*)(smem + XBLH_B);    // [4][1536]
  __half* xcand = (__half*)(smem + XCAND_B);   // [4][1024]
  float* hraw   = (float*)(smem + HRAW_B);     // [512][4]  (j-major)
  float* hraw0  = (float*)(smem + HRAW0_B);    // [512][4]
  float* gp     = (float*)(smem + GP_B);       // [64][4]
  float* rloc   = (float*)(smem + RLOC_B);     // [8][4]
  float* stw    = (float*)(smem + STW_B);      // [4][8]
  float* stw0   = (float*)(smem + STW0_B);     // [4][8]
  float* gateL  = (float*)(smem + GATEL_B);    // [4]
  float* bc1L   = (float*)(smem + BC1L_B);
  float* bg1L   = (float*)(smem + BG1L_B);
  float* bc2L   = (float*)(smem + BC2L_B);
  float* brL    = (float*)(smem + BRL_B);
  float* wg2L   = (float*)(smem + WG2L_B);
  float* bg2L   = (float*)(smem + BG2L_B);

  const int tid = threadIdx.x, g = blockIdx.x;
  const int l = g >> 6, gl = g & 63;
  const int w = tid >> 6, lane = tid & 63;
  const int C = l ? 1536 : 1280;
  const int e = l ? 512 : 256;
  const int oG1 = 16 * C, oR = 24 * C, oC2 = 24 * C + 8 * e;

  const __half* wtC1 = l ? wtC1_1 : wtC1_0;
  const __half* wtG1 = l ? wtG1_1 : wtG1_0;
  const __half* wtC2 = l ? wtC2_1 : wtC2_0;
  const __half* wtR  = l ? wtR_1  : wtR_0;
  const float* bc1 = l ? bc1_1 : bc1_0;
  const float* bg1 = l ? bg1_1 : bg1_0;
  const float* bc2 = l ? bc2_1 : bc2_0;
  const float* br  = l ? br_1  : br_0;
  const float* wg2 = l ? wg2_1 : wg2_0;
  const float* bg2 = l ? bg2_1 : bg2_0;

  // ---- one-time staging: weight slices (col-major fp16) -> LDS ----
  {
    auto cp = [&](const __half* src, int nh, int offh) {
      const u32* s = (const u32*)src; u32* d = (u32*)(WL + offh);
      for (int i = tid; i < (nh >> 1); i += RNT) d[i] = s[i];
    };
    cp(wtC1 + (size_t)(gl * 16) * C, 16 * C, 0);
    cp(wtG1 + (size_t)(gl * 8) * C,  8 * C, oG1);
    cp(wtR  + (size_t)(gl * 8) * e,  8 * e, oR);
    cp(wtC2 + (size_t)(gl * 8) * 1024, 8 * 1024, oC2);
  }
  if (tid < 16)      bc1L[tid] = bc1[gl * 16 + tid];
  else if (tid < 24) bg1L[tid - 16] = bg1[gl * 8 + tid - 16];
  else if (tid < 32) bc2L[tid - 24] = bc2[gl * 8 + tid - 24];
  else if (tid < 40) brL[tid - 32]  = br[gl * 8 + tid - 32];
  else if (tid < 48) wg2L[tid - 40] = wg2[gl * 8 + tid - 40];
  else if (tid == 48) bg2L[0] = bg2[0];
  for (int i = tid; i < 9472; i += RNT) ((u32*)(smem + XBLH_B))[i] = 0;
  __syncthreads();

  const int nEnd = l ? (Tn + 1) : (Tn - 1);

  for (int n = 0; n <= nEnd; ++n) {
    const int t = n - l;
    const bool prod = (t >= 0) && (t < Tn);
    const bool pollOwn = (t >= 1) && (t <= Tn);
    const bool pollL0  = (l == 1) && prod;

    // ---- early loads (l0): ids + emb row ----
    float4 embv = make_float4(0.f, 0.f, 0.f, 0.f);
    if (l == 0 && prod) {
      int idv = ids[w * Tn + t];
      embv = *(const float4*)(emb + (size_t)idv * En + lane * 4);
    }

    // ---- Phase A: poll h-broadcast (coalesced tagged words) ----
    if (pollOwn || pollL0) {
      const int parR = (n - 1) & 1;
      const u64* s1 = HB + (size_t)(l * 2 + parR) * 2048;
      const u64* s0 = HB + (size_t)parR * 2048;
      const u32 want = (u32)n;
      u64 v1[8], v0[8];
      for (;;) {
        bool ok = true;
        if (pollOwn) {
          #pragma unroll
          for (int i = 0; i < 8; ++i) v1[i] = gldu64(s1 + i * 256 + tid);
        }
        if (pollL0) {
          #pragma unroll
          for (int i = 0; i < 8; ++i) v0[i] = gldu64(s0 + i * 256 + tid);
        }
        if (pollOwn) {
          #pragma unroll
          for (int i = 0; i < 8; ++i) ok &= ((u32)(v1[i] >> 32) == want);
        }
        if (pollL0) {
          #pragma unroll
          for (int i = 0; i < 8; ++i) ok &= ((u32)(v0[i] >> 32) == want);
        }
        if (ok) break;
      }
      if (pollOwn) {
        #pragma unroll
        for (int i = 0; i < 8; ++i) {
          int idx = i * 256 + tid;
          int p = idx >> 5, w2 = idx & 31;
          hraw[(p * 8 + (w2 >> 2)) * 4 + (w2 & 3)] = unpackP(v1[i]);
        }
      }
      if (pollL0) {
        #pragma unroll
        for (int i = 0; i < 8; ++i) {
          int idx = i * 256 + tid;
          int p = idx >> 5, w2 = idx & 31;
          hraw0[(p * 8 + (w2 >> 2)) * 4 + (w2 & 3)] = unpackP(v0[i]);
        }
      }
    }
    __syncthreads();
    if (l == 1 && tid == 0) gstu32(flagA + gl * 16, (u32)(n + 1));

    // ---- stats (block-local, from full raw h) ----
    float m4[4], i4[4], m0v[4], i0v[4];
    const bool needStats = prod || pollOwn;
    if (needStats) {
      int j = tid * 2;
      float s[4], q[4], s0_[4], q0_[4];
      #pragma unroll
      for (int b = 0; b < 4; ++b) {
        float a0 = hraw[j * 4 + b], a1 = hraw[(j + 1) * 4 + b];
        s[b] = a0 + a1; q[b] = a0 * a0 + a1 * a1;
      }
      if (pollL0) {
        #pragma unroll
        for (int b = 0; b < 4; ++b) {
          float a0 = hraw0[j * 4 + b], a1 = hraw0[(j + 1) * 4 + b];
          s0_[b] = a0 + a1; q0_[b] = a0 * a0 + a1 * a1;
        }
      }
      #pragma unroll
      for (int off = 32; off; off >>= 1) {
        #pragma unroll
        for (int b = 0; b < 4; ++b) {
          s[b] += __shfl_xor(s[b], off); q[b] += __shfl_xor(q[b], off);
          if (pollL0) { s0_[b] += __shfl_xor(s0_[b], off); q0_[b] += __shfl_xor(q0_[b], off); }
        }
      }
      if (lane == 0) {
        #pragma unroll
        for (int b = 0; b < 4; ++b) {
          stw[w * 8 + b] = s[b]; stw[w * 8 + 4 + b] = q[b];
          if (pollL0) { stw0[w * 8 + b] = s0_[b]; stw0[w * 8 + 4 + b] = q0_[b]; }
        }
      }
    }
    __syncthreads();
    if (needStats) {
      #pragma unroll
      for (int b = 0; b < 4; ++b) {
        float S = stw[b] + stw[8 + b] + stw[16 + b] + stw[24 + b];
        float Q = stw[4 + b] + stw[12 + b] + stw[20 + b] + stw[28 + b];
        float m = S * (1.f / 512.f);
        m4[b] = m; i4[b] = rsqrtf(Q * (1.f / 512.f) - m * m + 1e-5f);
        if (pollL0) {
          float S0 = stw0[b] + stw0[8 + b] + stw0[16 + b] + stw0[24 + b];
          float Q0 = stw0[4 + b] + stw0[12 + b] + stw0[20 + b] + stw0[28 + b];
          float mm = S0 * (1.f / 512.f);
          m0v[b] = mm; i0v[b] = rsqrtf(Q0 * (1.f / 512.f) - mm * mm + 1e-5f);
        }
      }
    }

    // ---- histN for last layer (normalized h of step t-1) ----
    if (l == 1 && t >= 1 && t <= Tn && tid < 32) {
      int c = tid >> 2, b = tid & 3, j = gl * 8 + c;
      gstf(histN + ((size_t)(b * Tn + (t - 1))) * Hn + j,
           (hraw[j * 4 + b] - m4[b]) * i4[b]);
    }

    // ---- ctx update: shift h1->h2, write LN(h1), write inp ----
    if (prod) {
      int j = tid * 2;
      #pragma unroll
      for (int b = 0; b < 4; ++b) {
        #pragma unroll
        for (int jj = 0; jj < 2; ++jj) {
          __half old = xblh[b * 1536 + j + jj];
          xblh[b * 1536 + 512 + j + jj] = old;
          xblh[b * 1536 + j + jj] = __float2half((hraw[(j + jj) * 4 + b] - m4[b]) * i4[b]);
        }
      }
      if (l == 0) {
        #pragma unroll
        for (int ii = 0; ii < 4; ++ii)
          xblh[w * 1536 + 1024 + lane * 4 + ii] = __float2half(((const float*)&embv)[ii]);
      } else {
        #pragma unroll
        for (int b = 0; b < 4; ++b)
          #pragma unroll
          for (int jj = 0; jj < 2; ++jj)
            xblh[b * 1536 + 1024 + j + jj] =
              __float2half((hraw0[(j + jj) * 4 + b] - m0v[b]) * i0v[b]);
      }
    }
    __syncthreads();

    // ---- matvec1 (fdot2, LDS weights) + DIRECT CB stores from registers ----
    if (prod) {
      const __half* wb; int K2, xo;
      if (w < 2)       { wb = WL + w * 8 * C; K2 = C; xo = 0; }
      else if (w == 2) { wb = WL + oG1;       K2 = C; xo = 0; }
      else             { wb = WL + oR;        K2 = e; xo = 1024; }
      float acc[8][4];
      #pragma unroll
      for (int c = 0; c < 8; ++c)
        #pragma unroll
        for (int b = 0; b < 4; ++b) acc[c][b] = 0.f;
      for (int p2 = lane; p2 < (K2 >> 1); p2 += 64) {
        h2t xv[4];
        #pragma unroll
        for (int b = 0; b < 4; ++b)
          xv[b] = *(const h2t*)(xblh + b * 1536 + xo + 2 * p2);
        #pragma unroll
        for (int c = 0; c < 8; ++c) {
          h2t wv = *(const h2t*)(wb + c * K2 + 2 * p2);
          #pragma unroll
          for (int b = 0; b < 4; ++b) acc[c][b] = fdot2f(wv, xv[b], acc[c][b]);
        }
      }
      #pragma unroll
      for (int off = 32; off; off >>= 1)
        #pragma unroll
        for (int c = 0; c < 8; ++c)
          #pragma unroll
          for (int b = 0; b < 4; ++b) acc[c][b] += __shfl_xor(acc[c][b], off);
      float v[4] = {0.f, 0.f, 0.f, 0.f};
      #pragma unroll
      for (int c = 0; c < 8; ++c)
        if (lane == c) { v[0] = acc[c][0]; v[1] = acc[c][1]; v[2] = acc[c][2]; v[3] = acc[c][3]; }

      const u64 tagw = ((u64)(u32)(n + 1)) << 32;
      u64* CBL = CB + (size_t)(l * 2 + (n & 1)) * 2304 + gl * 36;
      if (w < 2) {
        if (lane < 8) {
          int c = w * 8 + lane;
          float bb = bc1L[c];
          float c0 = fmaxf(v[0] + bb, 0.f), c1 = fmaxf(v[1] + bb, 0.f);
          float c2 = fmaxf(v[2] + bb, 0.f), c3 = fmaxf(v[3] + bb, 0.f);
          u32 lo = (u32)f2h(c0) | ((u32)f2h(c1) << 16);
          u32 hi = (u32)f2h(c2) | ((u32)f2h(c3) << 16);
          gstu64(CBL + c * 2,     tagw | lo);
          gstu64(CBL + c * 2 + 1, tagw | hi);
        }
      } else if (w == 2) {
        if (lane < 8) {
          float bgv = bg1L[lane], wgv = wg2L[lane];
          float tb[4];
          #pragma unroll
          for (int b = 0; b < 4; ++b) tb[b] = tanhf(v[b] + bgv) * wgv;
          #pragma unroll
          for (int off = 1; off < 8; off <<= 1)
            #pragma unroll
            for (int b = 0; b < 4; ++b) tb[b] += __shfl_xor(tb[b], off);
          if (lane == 0) {
            #pragma unroll
            for (int b = 0; b < 4; ++b) {
              u32 bits; __builtin_memcpy(&bits, &tb[b], 4);
              gstu64(CBL + 32 + b, tagw | bits);
            }
          }
        }
      } else {
        if (lane < 8) {
          #pragma unroll
          for (int b = 0; b < 4; ++b) rloc[lane * 4 + b] = v[b] + brL[lane];
        }
      }
    }

    // ---- Phase B: poll cand1-broadcast (coalesced) + l0 backpressure ----
    if (prod) {
      const u64* CBL = CB + (size_t)(l * 2 + (n & 1)) * 2304;
      const u32 want = (u32)(n + 1);
      const bool needF = (l == 0) && (tid < 64);
      const u32* fptr = flagA + tid * 16;
      u64 cv[9];
      for (;;) {
        bool ok = true;
        #pragma unroll
        for (int i = 0; i < 9; ++i) cv[i] = gldu64(CBL + i * 256 + tid);
        #pragma unroll
        for (int i = 0; i < 9; ++i) ok &= ((u32)(cv[i] >> 32) == want);
        if (needF) ok &= (gldu32(fptr) >= (u32)n);
        if (ok) break;
      }
      u16* xc16 = (u16*)xcand;
      #pragma unroll
      for (int i = 0; i < 9; ++i) {
        int idx = i * 256 + tid;
        int p = (int)(((u32)idx * 3641u) >> 17);
        int w2 = idx - p * 36;
        u32 pay = (u32)cv[i];
        if (w2 < 32) {
          int c = w2 >> 1, j = p * 16 + c, b0 = (w2 & 1) * 2;
          xc16[b0 * 1024 + j]       = (u16)(pay & 0xffffu);
          xc16[(b0 + 1) * 1024 + j] = (u16)(pay >> 16);
        } else {
          float f; __builtin_memcpy(&f, &pay, 4);
          gp[p * 4 + (w2 - 32)] = f;
        }
      }
    }
    __syncthreads();

    // ---- gate reduce (wave 0) + matvec2 (all waves, fdot2) ----
    float a2[2][4];
    #pragma unroll
    for (int cc = 0; cc < 2; ++cc)
      #pragma unroll
      for (int b = 0; b < 4; ++b) a2[cc][b] = 0.f;
    if (prod) {
      if (w == 0) {
        float gs[4];
        #pragma unroll
        for (int b = 0; b < 4; ++b) gs[b] = gp[lane * 4 + b];
        #pragma unroll
        for (int off = 32; off; off >>= 1)
          #pragma unroll
          for (int b = 0; b < 4; ++b) gs[b] += __shfl_xor(gs[b], off);
        if (lane == 0) {
          #pragma unroll
          for (int b = 0; b < 4; ++b) gateL[b] = 1.f / (1.f + expf(-(gs[b] + bg2L[0])));
        }
      }
      const __half* wb2 = WL + oC2 + (w * 2) * 1024;
      for (int p2 = lane; p2 < 512; p2 += 64) {
        h2t xv[4];
        #pragma unroll
        for (int b = 0; b < 4; ++b)
          xv[b] = *(const h2t*)(xcand + b * 1024 + 2 * p2);
        #pragma unroll
        for (int cc = 0; cc < 2; ++cc) {
          h2t wv = *(const h2t*)(wb2 + cc * 1024 + 2 * p2);
          #pragma unroll
          for (int b = 0; b < 4; ++b) a2[cc][b] = fdot2f(wv, xv[b], a2[cc][b]);
        }
      }
      #pragma unroll
      for (int off = 32; off; off >>= 1)
        #pragma unroll
        for (int cc = 0; cc < 2; ++cc)
          #pragma unroll
          for (int b = 0; b < 4; ++b) a2[cc][b] += __shfl_xor(a2[cc][b], off);
    }
    __syncthreads();   // gateL + rloc ready

    // ---- finalize h + DIRECT HB store from registers ----
    if (prod) {
      float sel = 0.f;
      #pragma unroll
      for (int cc = 0; cc < 2; ++cc)
        #pragma unroll
        for (int b = 0; b < 4; ++b)
          if (lane == cc * 4 + b) sel = a2[cc][b];
      if (lane < 8) {
        int cc = lane >> 2, b = lane & 3, cl = w * 2 + cc;
        float cand = sel + bc2L[cl];
        float h1n = __half2float(xblh[b * 1536 + gl * 8 + cl]);
        float hv = h1n + gateL[b] * cand + 0.1f * rloc[cl * 4 + b];
        u32 bits; __builtin_memcpy(&bits, &hv, 4);
        u64* HBw = HB + (size_t)(l * 2 + (n & 1)) * 2048 + gl * 32;
        gstu64(HBw + cl * 4 + b, (((u64)(u32)(n + 1)) << 32) | bits);
      }
      if (l == 1 && gl == 0 && tid >= 8 && tid < 12)
        gstf(gates_out + (tid - 8) * Tn + t, gateL[tid - 8]);
    }
  }
}

// ---------------- attention scores (histN already normalized) ----------------
__global__ __launch_bounds__(256) void scores_kernel(
    const float* __restrict__ histN,
    const float* __restrict__ wa1, const float* __restrict__ ba1,
    const float* __restrict__ wa2, const float* __restrict__ ba2,
    float* __restrict__ scores)
{
  __shared__ float xs[8][512];
  __shared__ float wacc[4][8];
  const int tid = threadIdx.x, bid = blockIdx.x;

  for (int idx = tid; idx < 4096; idx += 256)
    xs[idx >> 9][idx & 511] = histN[(size_t)(bid * 8) * Hn + idx];
  __syncthreads();

  float pr[8] = {0.f,0.f,0.f,0.f,0.f,0.f,0.f,0.f};
  #pragma unroll
  for (int cc = 0; cc < 2; ++cc) {
    int c = tid + cc * 256;
    float a[8] = {0.f,0.f,0.f,0.f,0.f,0.f,0.f,0.f};
    for (int k = 0; k < 512; ++k) {
      float wv = wa1[(size_t)k * 512 + c];
      #pragma unroll
      for (int r = 0; r < 8; ++r) a[r] = fmaf(xs[r][k], wv, a[r]);
    }
    float b1 = ba1[c], w2 = wa2[c];
    #pragma unroll
    for (int r = 0; r < 8; ++r) pr[r] += tanhf(a[r] + b1) * w2;
  }
  int lane = tid & 63, wq = tid >> 6;
  #pragma unroll
  for (int off = 32; off; off >>= 1)
    #pragma unroll
    for (int r = 0; r < 8; ++r) pr[r] += __shfl_xor(pr[r], off);
  if (lane == 0) {
    #pragma unroll
    for (int r = 0; r < 8; ++r) wacc[wq][r] = pr[r];
  }
  __syncthreads();
  if (tid < 8)
    scores[bid * 8 + tid] = wacc[0][tid] + wacc[1][tid] + wacc[2][tid] + wacc[3][tid] + ba2[0];
}

// ---------------- prefix-softmax cumsum -> attended (bf16) ----------------
__global__ __launch_bounds__(256) void cumsum_kernel(
    const float* __restrict__ scores, const float* __restrict__ histN,
    u16* __restrict__ att)
{
  __shared__ float ee[512], den[512], sb[512], red[256];
  const int tid = threadIdx.x, b = blockIdx.x;
  float s0 = scores[b * Tn + tid], s1 = scores[b * Tn + tid + 256];
  red[tid] = fmaxf(s0, s1);
  __syncthreads();
  for (int s = 128; s; s >>= 1) { if (tid < s) red[tid] = fmaxf(red[tid], red[tid + s]); __syncthreads(); }
  float m = red[0];
  ee[tid] = expf(s0 - m); ee[tid + 256] = expf(s1 - m);
  den[tid] = ee[tid]; den[tid + 256] = ee[tid + 256];
  __syncthreads();
  float* A = den; float* D = sb;
  for (int off = 1; off < 512; off <<= 1) {
    for (int t2 = tid; t2 < 512; t2 += 256) { float v = A[t2]; if (t2 >= off) v += A[t2 - off]; D[t2] = v; }
    __syncthreads();
    float* tmp = A; A = D; D = tmp;
  }
  float* R = D;
  for (int t2 = tid; t2 < 512; t2 += 256) R[t2] = 1.f / A[t2];
  __syncthreads();

  const int h0 = tid * 2;
  float ax = 0.f, ay = 0.f;
  for (int t = 0; t < 512; ++t) {
    const float* hpp = histN + ((size_t)(b * Tn + t)) * Hn + h0;
    float x0 = hpp[0], x1 = hpp[1];
    float et = ee[t], rd = R[t];
    ax = fmaf(et, x0, ax); ay = fmaf(et, x1, ay);
    u32 pack = (u32)f2bf(x0 + ax * rd) | ((u32)f2bf(x1 + ay * rd) << 16);
    *(u32*)(att + ((size_t)(b * Tn + t)) * Hn + h0) = pack;
  }
}

// ---------------- final GEMM: att[2048x512]bf16 @ WhB[512xNPAD]bf16 + bh -> fp32 ----------------
typedef short bf16x8_t __attribute__((ext_vector_type(8)));
typedef float f32x4_t  __attribute__((ext_vector_type(4)));

__global__ __launch_bounds__(256) void gemm_kernel(
    const u16* __restrict__ Aw, const u16* __restrict__ Bw,
    const float* __restrict__ bh, float* __restrict__ out)
{
  __shared__ u16 Alds[128 * 64];
  __shared__ u16 Blds[64 * 128];
  const int tid = threadIdx.x;
  const int n0 = blockIdx.x * 128, m0 = blockIdx.y * 128;
  const int w = tid >> 6, lane = tid & 63;
  const int wm = (w & 1) * 64, wn = (w >> 1) * 64;

  f32x4_t acc[4][4];
  #pragma unroll
  for (int i = 0; i < 4; ++i)
    #pragma unroll
    for (int j = 0; j < 4; ++j) acc[i][j] = (f32x4_t){0.f, 0.f, 0.f, 0.f};

  for (int kt = 0; kt < 8; ++kt) {
    const int k0 = kt * 64;
    {
      int row = tid >> 1, kc = (tid & 1) * 32;
      #pragma unroll
      for (int jj = 0; jj < 4; ++jj) {
        uint4 v = *(const uint4*)(Aw + (size_t)(m0 + row) * 512 + k0 + kc + jj * 8);
        int byte = row * 128 + (kc + jj * 8) * 2;
        byte ^= (row & 7) << 4;
        *(uint4*)((char*)Alds + byte) = v;
      }
    }
    {
      #pragma unroll
      for (int q = 0; q < 4; ++q) {
        int r = (tid >> 4) + q * 16, c8 = (tid & 15) * 8;
        uint4 v = *(const uint4*)(Bw + (size_t)(k0 + r) * NPAD + n0 + c8);
        *(uint4*)&Blds[r * 128 + c8] = v;
      }
    }
    __syncthreads();
    #pragma unroll
    for (int kh = 0; kh < 2; ++kh) {
      bf16x8_t af[4];
      #pragma unroll
      for (int i = 0; i < 4; ++i) {
        int row = wm + i * 16 + (lane & 15);
        int byte = row * 128 + kh * 64 + (lane >> 4) * 16;
        byte ^= (row & 7) << 4;
        af[i] = *(const bf16x8_t*)((const char*)Alds + byte);
      }
      const int kb = kh * 32 + (lane >> 4) * 8;
      #pragma unroll
      for (int j = 0; j < 4; ++j) {
        int col = wn + j * 16 + (lane & 15);
        bf16x8_t bf;
        #pragma unroll
        for (int jj = 0; jj < 8; ++jj) bf[jj] = (short)Blds[(kb + jj) * 128 + col];
        #pragma unroll
        for (int i = 0; i < 4; ++i)
          acc[i][j] = __builtin_amdgcn_mfma_f32_16x16x32_bf16(af[i], bf, acc[i][j], 0, 0, 0);
      }
    }
    __syncthreads();
  }
  #pragma unroll
  for (int j = 0; j < 4; ++j) {
    int col = n0 + wn + j * 16 + (lane & 15);
    if (col < Vn) {
      float bias = bh[col];
      #pragma unroll
      for (int i = 0; i < 4; ++i) {
        int rbase = m0 + wm + i * 16 + (lane >> 4) * 4;
        #pragma unroll
        for (int r = 0; r < 4; ++r)
          out[(size_t)(rbase + r) * Vn + col] = acc[i][j][r] + bias;
      }
    }
  }
}

// ---------------- host ----------------
extern "C" void kernel_launch(void* const* d_in, const int* in_sizes, int n_in,
                              void* d_out, int out_size, void* d_ws, size_t ws_size,
                              hipStream_t stream) {
  const int*   ids  = (const int*)d_in[0];
  const float* emb  = (const float*)d_in[1];
  const float* Wc1_0 = (const float*)d_in[2];  const float* bc1_0 = (const float*)d_in[3];
  const float* Wc2_0 = (const float*)d_in[4];  const float* bc2_0 = (const float*)d_in[5];
  const float* Wg1_0 = (const float*)d_in[6];  const float* bg1_0 = (const float*)d_in[7];
  const float* Wg2_0 = (const float*)d_in[8];  const float* bg2_0 = (const float*)d_in[9];
  const float* Wr_0  = (const float*)d_in[10]; const float* br_0  = (const float*)d_in[11];
  const float* Wc1_1 = (const float*)d_in[12]; const float* bc1_1 = (const float*)d_in[13];
  const float* Wc2_1 = (const float*)d_in[14]; const float* bc2_1 = (const float*)d_in[15];
  const float* Wg1_1 = (const float*)d_in[16]; const float* bg1_1 = (const float*)d_in[17];
  const float* Wg2_1 = (const float*)d_in[18]; const float* bg2_1 = (const float*)d_in[19];
  const float* Wr_1  = (const float*)d_in[20]; const float* br_1  = (const float*)d_in[21];
  const float* Wa1 = (const float*)d_in[22]; const float* ba1 = (const float*)d_in[23];
  const float* Wa2 = (const float*)d_in[24]; const float* ba2 = (const float*)d_in[25];
  const float* Wh  = (const float*)d_in[26]; const float* bh  = (const float*)d_in[27];

  float* out = (float*)d_out;
  char*  ws  = (char*)d_ws;

  const size_t OFF_FLAGA = 0;                          // 4096
  const size_t OFF_HB    = 4096;                       // 65536
  const size_t OFF_CB    = 69632;                      // 73728
  const size_t OFF_WT    = 143360;                     // 11534336
  const size_t OFF_HISTN = OFF_WT + 11534336;          // 4 MB
  const size_t OFF_SCO   = OFF_HISTN + 4194304;        // 8 KB
  const size_t OFF_ATT   = OFF_SCO + 8192;             // 2 MB
  const size_t OFF_WHB   = OFF_ATT + 2097152;          // 51.5 MB

  u32*   flagA  = (u32*)(ws + OFF_FLAGA);
  u64*   HB     = (u64*)(ws + OFF_HB);
  u64*   CB     = (u64*)(ws + OFF_CB);
  __half* wth   = (__half*)(ws + OFF_WT);
  float* histN  = (float*)(ws + OFF_HISTN);
  float* scores = (float*)(ws + OFF_SCO);
  u16*   att    = (u16*)(ws + OFF_ATT);
  u16*   whb    = (u16*)(ws + OFF_WHB);
  float* gates  = out + (size_t)Bn * Tn * Vn;

  __half* wtC1_0h = wth;
  __half* wtG1_0h = wth + 1310720;
  __half* wtC2_0h = wth + 1966080;
  __half* wtR_0h  = wth + 2490368;
  __half* wtC1_1h = wth + 2621440;
  __half* wtG1_1h = wth + 4194304;
  __half* wtC2_1h = wth + 4980736;
  __half* wtR_1h  = wth + 5505024;

  hipMemsetAsync(ws, 0, 143360, stream);   // flagA + HB + CB tags

  transpose_h<<<dim3(32, 40), 256, 0, stream>>>(Wc1_0, wtC1_0h, 1280, 1024);
  transpose_h<<<dim3(16, 40), 256, 0, stream>>>(Wg1_0, wtG1_0h, 1280, 512);
  transpose_h<<<dim3(16, 32), 256, 0, stream>>>(Wc2_0, wtC2_0h, 1024, 512);
  transpose_h<<<dim3(16,  8), 256, 0, stream>>>(Wr_0,  wtR_0h,   256, 512);
  transpose_h<<<dim3(32, 48), 256, 0, stream>>>(Wc1_1, wtC1_1h, 1536, 1024);
  transpose_h<<<dim3(16, 48), 256, 0, stream>>>(Wg1_1, wtG1_1h, 1536, 512);
  transpose_h<<<dim3(16, 32), 256, 0, stream>>>(Wc2_1, wtC2_1h, 1024, 512);
  transpose_h<<<dim3(16, 16), 256, 0, stream>>>(Wr_1,  wtR_1h,   512, 512);

  convwh_kernel<<<dim3(99, 512), 256, 0, stream>>>(Wh, whb);

  (void)hipFuncSetAttribute((const void*)rec_kernel,
                            hipFuncAttributeMaxDynamicSharedMemorySize, REC_LDS);

  rec_kernel<<<dim3(RG), dim3(RNT), REC_LDS, stream>>>(
      ids, emb,
      wtC1_0h, wtG1_0h, wtC2_0h, wtR_0h,
      wtC1_1h, wtG1_1h, wtC2_1h, wtR_1h,
      bc1_0, bg1_0, bc2_0, br_0, Wg2_0, bg2_0,
      bc1_1, bg1_1, bc2_1, br_1, Wg2_1, bg2_1,
      flagA, HB, CB, histN, gates);

  scores_kernel<<<dim3(256), 256, 0, stream>>>(histN, Wa1, ba1, Wa2, ba2, scores);

  cumsum_kernel<<<dim3(Bn), 256, 0, stream>>>(scores, histN, att);

  gemm_kernel<<<dim3(393, 16), 256, 0, stream>>>(att, whb, bh, out);
}

// Round 8
// 5398.149 us; speedup vs baseline: 4.3756x; 1.4085x over previous
//
#include <hip/hip_runtime.h>
#include <hip/hip_fp16.h>
#include <cstdint>
#include <cstddef>

typedef unsigned short u16;
typedef unsigned int   u32;
typedef unsigned long long u64;

#define Bn 4
#define Tn 512
#define Hn 512
#define En 256
#define Vn 50257
#define NPAD 50304
#define RG  256
#define RNT 256

typedef _Float16 h2t __attribute__((ext_vector_type(2)));

#if defined(__has_builtin)
#if __has_builtin(__builtin_amdgcn_fdot2)
#define HAS_FDOT2 1
#endif
#endif
__device__ __forceinline__ float fdot2f(h2t a, h2t b, float c) {
#ifdef HAS_FDOT2
  return __builtin_amdgcn_fdot2(a, b, c, false);
#else
  return fmaf((float)a[0], (float)b[0], fmaf((float)a[1], (float)b[1], c));
#endif
}

__device__ __forceinline__ u16 f2bf(float f) {
  u32 x; __builtin_memcpy(&x, &f, 4);
  u32 r = (x + 0x7fffu + ((x >> 16) & 1u)) >> 16;
  return (u16)r;
}
__device__ __forceinline__ u16 f2h(float f) {
  __half hh = __float2half(f); u16 u; __builtin_memcpy(&u, &hh, 2); return u;
}
__device__ __forceinline__ float h2fu(u16 h) {
  __half hh; __builtin_memcpy(&hh, &h, 2); return __half2float(hh);
}
__device__ __forceinline__ float unpackF(u32 b) {
  float f; __builtin_memcpy(&f, &b, 4); return f;
}
__device__ __forceinline__ u64 gldu64(const u64* p) {
  return __hip_atomic_load(p, __ATOMIC_RELAXED, __HIP_MEMORY_SCOPE_AGENT);
}
__device__ __forceinline__ void gstu64(u64* p, u64 v) {
  __hip_atomic_store(p, v, __ATOMIC_RELAXED, __HIP_MEMORY_SCOPE_AGENT);
}
__device__ __forceinline__ u32 gldu32(const u32* p) {
  return __hip_atomic_load(p, __ATOMIC_RELAXED, __HIP_MEMORY_SCOPE_AGENT);
}
__device__ __forceinline__ void gstu32(u32* p, u32 v) {
  __hip_atomic_store(p, v, __ATOMIC_RELAXED, __HIP_MEMORY_SCOPE_AGENT);
}
__device__ __forceinline__ void gstf(float* p, float v) {
  __hip_atomic_store(p, v, __ATOMIC_RELAXED, __HIP_MEMORY_SCOPE_AGENT);
}

// ---------------- prep kernels ----------------
__global__ __launch_bounds__(256) void transpose_h(
    const float* __restrict__ src, __half* __restrict__ dst, int K, int N)
{
  __shared__ float tile[32][33];
  const int tx = threadIdx.x & 31, ty = threadIdx.x >> 5;
  const int bn = blockIdx.x * 32, bk = blockIdx.y * 32;
  #pragma unroll
  for (int i = 0; i < 4; ++i)
    tile[ty + i * 8][tx] = src[(size_t)(bk + ty + i * 8) * N + bn + tx];
  __syncthreads();
  #pragma unroll
  for (int i = 0; i < 4; ++i)
    dst[(size_t)(bn + ty + i * 8) * K + bk + tx] = __float2half(tile[tx][ty + i * 8]);
}

__global__ __launch_bounds__(256) void convwh_kernel(
    const float* __restrict__ wh, u16* __restrict__ whb)
{
  const int k = blockIdx.y;
  const int v0 = (blockIdx.x * 256 + threadIdx.x) * 2;
  if (v0 >= NPAD) return;
  float a = (v0     < Vn) ? wh[(size_t)k * Vn + v0]     : 0.f;
  float b = (v0 + 1 < Vn) ? wh[(size_t)k * Vn + v0 + 1] : 0.f;
  u32 pack = (u32)f2bf(a) | ((u32)f2bf(b) << 16);
  *(u32*)&whb[(size_t)k * NPAD + v0] = pack;
}

// ---- dynamic LDS byte offsets (weights 0..98303) ----
#define XBLH_B  98304    // [2][1536] fp16 = 6144
#define XCAND_B 104448   // [2][1024] fp16 = 4096
#define HRAW_B  108544   // [512][2] f32 = 4096
#define HRAW0_B 112640   // [512][2] f32 = 4096
#define GP_B    116736   // [64][2] f32 = 512
#define RLOC_B  117248   // [8][2] f32 = 64
#define STW_B   117312   // [4][4] = 64
#define STW0_B  117376   // 64
#define BC1L_B  117440   // 64
#define BG1L_B  117504   // 32
#define BC2L_B  117536   // 32
#define BRL_B   117568   // 32
#define WG2L_B  117600   // 32
#define BG2L_B  117632   // 4
#define REC_LDS 117664

// ---------------- persistent recurrence: 2 batch-groups x 2 layers x 64 blocks ----------------
// g: bp = g>>7 (batch pair), l = (g>>6)&1, gl = g&63. Group bp handles batches {2bp, 2bp+1}.
__global__ __launch_bounds__(RNT, 1) void rec_kernel(
    const int* __restrict__ ids, const float* __restrict__ emb,
    const __half* wtC1_0, const __half* wtG1_0, const __half* wtC2_0, const __half* wtR_0,
    const __half* wtC1_1, const __half* wtG1_1, const __half* wtC2_1, const __half* wtR_1,
    const float* bc1_0, const float* bg1_0, const float* bc2_0, const float* br_0,
    const float* wg2_0, const float* bg2_0,
    const float* bc1_1, const float* bg1_1, const float* bc2_1, const float* br_1,
    const float* wg2_1, const float* bg2_1,
    u32* flagA, u64* HB, u64* CB,
    float* __restrict__ histN, float* __restrict__ gates_out)
{
  extern __shared__ char smem[];
  __half* WL    = (__half*)smem;
  __half* xblh  = (__half*)(smem + XBLH_B);
  __half* xcand = (__half*)(smem + XCAND_B);
  float* hraw   = (float*)(smem + HRAW_B);
  float* hraw0  = (float*)(smem + HRAW0_B);
  float* gp     = (float*)(smem + GP_B);
  float* rloc   = (float*)(smem + RLOC_B);
  float* stw    = (float*)(smem + STW_B);
  float* stw0   = (float*)(smem + STW0_B);
  float* bc1L   = (float*)(smem + BC1L_B);
  float* bg1L   = (float*)(smem + BG1L_B);
  float* bc2L   = (float*)(smem + BC2L_B);
  float* brL    = (float*)(smem + BRL_B);
  float* wg2L   = (float*)(smem + WG2L_B);
  float* bg2L   = (float*)(smem + BG2L_B);

  const int tid = threadIdx.x, g = blockIdx.x;
  const int bp = g >> 7, l = (g >> 6) & 1, gl = g & 63;
  const int w = tid >> 6, lane = tid & 63;
  const int C = l ? 1536 : 1280;
  const int e = l ? 512 : 256;
  const int oG1 = 16 * C, oR = 24 * C, oC2 = 24 * C + 8 * e;

  const __half* wtC1 = l ? wtC1_1 : wtC1_0;
  const __half* wtG1 = l ? wtG1_1 : wtG1_0;
  const __half* wtC2 = l ? wtC2_1 : wtC2_0;
  const __half* wtR  = l ? wtR_1  : wtR_0;
  const float* bc1 = l ? bc1_1 : bc1_0;
  const float* bg1 = l ? bg1_1 : bg1_0;
  const float* bc2 = l ? bc2_1 : bc2_0;
  const float* br  = l ? br_1  : br_0;
  const float* wg2 = l ? wg2_1 : wg2_0;
  const float* bg2 = l ? bg2_1 : bg2_0;

  // message bases
  const int mb = (bp * 2 + l) * 2;     // +parity
  u64* HBown = HB + (size_t)mb * 1024;
  u64* CBown = CB + (size_t)mb * 1152;
  const u64* HBl0 = HB + (size_t)(bp * 2) * 2 * 1024;

  // ---- one-time staging: weight slices -> LDS ----
  {
    auto cp = [&](const __half* src, int nh, int offh) {
      const u32* s = (const u32*)src; u32* d = (u32*)(WL + offh);
      for (int i = tid; i < (nh >> 1); i += RNT) d[i] = s[i];
    };
    cp(wtC1 + (size_t)(gl * 16) * C, 16 * C, 0);
    cp(wtG1 + (size_t)(gl * 8) * C,  8 * C, oG1);
    cp(wtR  + (size_t)(gl * 8) * e,  8 * e, oR);
    cp(wtC2 + (size_t)(gl * 8) * 1024, 8 * 1024, oC2);
  }
  if (tid < 16)      bc1L[tid] = bc1[gl * 16 + tid];
  else if (tid < 24) bg1L[tid - 16] = bg1[gl * 8 + tid - 16];
  else if (tid < 32) bc2L[tid - 24] = bc2[gl * 8 + tid - 24];
  else if (tid < 40) brL[tid - 32]  = br[gl * 8 + tid - 32];
  else if (tid < 48) wg2L[tid - 40] = wg2[gl * 8 + tid - 40];
  else if (tid == 48) bg2L[0] = bg2[0];
  for (int i = tid; i < 4736; i += RNT) ((u32*)(smem + XBLH_B))[i] = 0;
  __syncthreads();

  const int nEnd = l ? (Tn + 1) : (Tn - 1);

  for (int n = 0; n <= nEnd; ++n) {
    const int t = n - l;
    const bool prod = (t >= 0) && (t < Tn);
    const bool pollOwn = (t >= 1) && (t <= Tn);
    const bool pollL0  = (l == 1) && prod;

    // ---- early loads (l0): emb row pieces ----
    float2 e2 = make_float2(0.f, 0.f);
    if (l == 0 && prod) {
      int idv = ids[(bp * 2 + (w >> 1)) * Tn + t];
      e2 = *(const float2*)(emb + (size_t)idv * En + (tid & 127) * 2);
    }

    // ---- Phase A: poll h-broadcast ----
    if (pollOwn || pollL0) {
      const int parR = (n - 1) & 1;
      const u64* s1 = HBown + (size_t)parR * 1024;
      const u64* s0 = HBl0 + (size_t)parR * 1024;
      const u32 want = (u32)n;
      u64 v1[4], v0[4];
      for (;;) {
        bool ok = true;
        if (pollOwn) {
          #pragma unroll
          for (int i = 0; i < 4; ++i) v1[i] = gldu64(s1 + i * 256 + tid);
          #pragma unroll
          for (int i = 0; i < 4; ++i) ok &= ((u32)(v1[i] >> 32) == want);
        }
        if (pollL0) {
          #pragma unroll
          for (int i = 0; i < 4; ++i) v0[i] = gldu64(s0 + i * 256 + tid);
          #pragma unroll
          for (int i = 0; i < 4; ++i) ok &= ((u32)(v0[i] >> 32) == want);
        }
        if (ok) break;
        __builtin_amdgcn_s_sleep(1);
      }
      if (pollOwn) {
        #pragma unroll
        for (int i = 0; i < 4; ++i) {
          int idx = i * 256 + tid;
          int p = idx >> 4, w2 = idx & 15;
          hraw[(p * 8 + (w2 >> 1)) * 2 + (w2 & 1)] = unpackF((u32)v1[i]);
        }
      }
      if (pollL0) {
        #pragma unroll
        for (int i = 0; i < 4; ++i) {
          int idx = i * 256 + tid;
          int p = idx >> 4, w2 = idx & 15;
          hraw0[(p * 8 + (w2 >> 1)) * 2 + (w2 & 1)] = unpackF((u32)v0[i]);
        }
      }
    }
    __syncthreads();
    if (l == 1 && tid == 0) gstu32(flagA + (bp * 64 + gl) * 16, (u32)(n + 1));

    // ---- stats (block-local over full raw h) ----
    float m4[2], i4[2], m0v[2], i0v[2];
    const bool needStats = prod || pollOwn;
    if (needStats) {
      float s[2] = {0.f, 0.f}, q[2] = {0.f, 0.f}, s0_[2] = {0.f, 0.f}, q0_[2] = {0.f, 0.f};
      #pragma unroll
      for (int jj = 0; jj < 2; ++jj) {
        int j = tid + jj * 256;
        #pragma unroll
        for (int b = 0; b < 2; ++b) {
          float a0 = hraw[j * 2 + b];
          s[b] += a0; q[b] += a0 * a0;
          if (pollL0) { float a1 = hraw0[j * 2 + b]; s0_[b] += a1; q0_[b] += a1 * a1; }
        }
      }
      #pragma unroll
      for (int off = 32; off; off >>= 1)
        #pragma unroll
        for (int b = 0; b < 2; ++b) {
          s[b] += __shfl_xor(s[b], off); q[b] += __shfl_xor(q[b], off);
          if (pollL0) { s0_[b] += __shfl_xor(s0_[b], off); q0_[b] += __shfl_xor(q0_[b], off); }
        }
      if (lane == 0) {
        #pragma unroll
        for (int b = 0; b < 2; ++b) {
          stw[w * 4 + b] = s[b]; stw[w * 4 + 2 + b] = q[b];
          if (pollL0) { stw0[w * 4 + b] = s0_[b]; stw0[w * 4 + 2 + b] = q0_[b]; }
        }
      }
    }
    __syncthreads();
    if (needStats) {
      #pragma unroll
      for (int b = 0; b < 2; ++b) {
        float S = stw[b] + stw[4 + b] + stw[8 + b] + stw[12 + b];
        float Q = stw[2 + b] + stw[6 + b] + stw[10 + b] + stw[14 + b];
        float m = S * (1.f / 512.f);
        m4[b] = m; i4[b] = rsqrtf(Q * (1.f / 512.f) - m * m + 1e-5f);
        if (pollL0) {
          float S0 = stw0[b] + stw0[4 + b] + stw0[8 + b] + stw0[12 + b];
          float Q0 = stw0[2 + b] + stw0[6 + b] + stw0[10 + b] + stw0[14 + b];
          float mm = S0 * (1.f / 512.f);
          m0v[b] = mm; i0v[b] = rsqrtf(Q0 * (1.f / 512.f) - mm * mm + 1e-5f);
        }
      }
    }

    // ---- histN (last layer, normalized h of step t-1) ----
    if (l == 1 && t >= 1 && t <= Tn && tid < 16) {
      int c = tid >> 1, b = tid & 1, j = gl * 8 + c;
      gstf(histN + ((size_t)((bp * 2 + b) * Tn + (t - 1))) * Hn + j,
           (hraw[j * 2 + b] - m4[b]) * i4[b]);
    }

    // ---- ctx update ----
    if (prod) {
      #pragma unroll
      for (int jj = 0; jj < 2; ++jj) {
        int j = tid + jj * 256;
        #pragma unroll
        for (int b = 0; b < 2; ++b) {
          __half old = xblh[b * 1536 + j];
          xblh[b * 1536 + 512 + j] = old;
          xblh[b * 1536 + j] = __float2half((hraw[j * 2 + b] - m4[b]) * i4[b]);
        }
      }
      if (l == 0) {
        int b = w >> 1, j2 = (tid & 127) * 2;
        xblh[b * 1536 + 1024 + j2]     = __float2half(e2.x);
        xblh[b * 1536 + 1024 + j2 + 1] = __float2half(e2.y);
      } else {
        #pragma unroll
        for (int jj = 0; jj < 2; ++jj) {
          int j = tid + jj * 256;
          #pragma unroll
          for (int b = 0; b < 2; ++b)
            xblh[b * 1536 + 1024 + j] =
              __float2half((hraw0[j * 2 + b] - m0v[b]) * i0v[b]);
        }
      }
    }
    __syncthreads();

    // ---- matvec1 + direct CB stores ----
    if (prod) {
      const __half* wb; int K2, xo;
      if (w < 2)       { wb = WL + w * 8 * C; K2 = C; xo = 0; }
      else if (w == 2) { wb = WL + oG1;       K2 = C; xo = 0; }
      else             { wb = WL + oR;        K2 = e; xo = 1024; }
      float acc[8][2];
      #pragma unroll
      for (int c = 0; c < 8; ++c) { acc[c][0] = 0.f; acc[c][1] = 0.f; }
      for (int p2 = lane; p2 < (K2 >> 1); p2 += 64) {
        h2t xv0 = *(const h2t*)(xblh + xo + 2 * p2);
        h2t xv1 = *(const h2t*)(xblh + 1536 + xo + 2 * p2);
        #pragma unroll
        for (int c = 0; c < 8; ++c) {
          h2t wv = *(const h2t*)(wb + c * K2 + 2 * p2);
          acc[c][0] = fdot2f(wv, xv0, acc[c][0]);
          acc[c][1] = fdot2f(wv, xv1, acc[c][1]);
        }
      }
      #pragma unroll
      for (int off = 32; off; off >>= 1)
        #pragma unroll
        for (int c = 0; c < 8; ++c) {
          acc[c][0] += __shfl_xor(acc[c][0], off);
          acc[c][1] += __shfl_xor(acc[c][1], off);
        }
      float v0s = 0.f, v1s = 0.f;
      #pragma unroll
      for (int c = 0; c < 8; ++c)
        if (lane == c) { v0s = acc[c][0]; v1s = acc[c][1]; }

      const u64 tagw = ((u64)(u32)(n + 1)) << 32;
      u64* CBw = CBown + (size_t)(n & 1) * 1152 + gl * 18;
      if (w < 2) {
        if (lane < 8) {
          int c = w * 8 + lane;
          float bb = bc1L[c];
          float c0 = fmaxf(v0s + bb, 0.f), c1 = fmaxf(v1s + bb, 0.f);
          u32 pay = (u32)f2h(c0) | ((u32)f2h(c1) << 16);
          gstu64(CBw + c, tagw | pay);
        }
      } else if (w == 2) {
        if (lane < 8) {
          float bgv = bg1L[lane], wgv = wg2L[lane];
          float t0 = tanhf(v0s + bgv) * wgv, t1 = tanhf(v1s + bgv) * wgv;
          #pragma unroll
          for (int off = 1; off < 8; off <<= 1) { t0 += __shfl_xor(t0, off); t1 += __shfl_xor(t1, off); }
          if (lane == 0) {
            u32 b0, b1; __builtin_memcpy(&b0, &t0, 4); __builtin_memcpy(&b1, &t1, 4);
            gstu64(CBw + 16, tagw | b0);
            gstu64(CBw + 17, tagw | b1);
          }
        }
      } else {
        if (lane < 8) { rloc[lane * 2] = v0s + brL[lane]; rloc[lane * 2 + 1] = v1s + brL[lane]; }
      }
    }

    // ---- Phase B: poll cand1-broadcast + l0 backpressure ----
    if (prod) {
      const u64* CBL = CBown + (size_t)(n & 1) * 1152;
      const u32 want = (u32)(n + 1);
      const bool needF = (l == 0) && (tid < 64);
      const u32* fptr = flagA + (bp * 64 + tid) * 16;
      u64 cv[5];
      const bool last = (tid < 128);
      for (;;) {
        bool ok = true;
        #pragma unroll
        for (int i = 0; i < 4; ++i) cv[i] = gldu64(CBL + i * 256 + tid);
        if (last) cv[4] = gldu64(CBL + 1024 + tid);
        #pragma unroll
        for (int i = 0; i < 4; ++i) ok &= ((u32)(cv[i] >> 32) == want);
        if (last) ok &= ((u32)(cv[4] >> 32) == want);
        if (needF) ok &= (gldu32(fptr) >= (u32)n);
        if (ok) break;
        __builtin_amdgcn_s_sleep(1);
      }
      u16* xc16 = (u16*)xcand;
      #pragma unroll
      for (int i = 0; i < 5; ++i) {
        if (i == 4 && !last) break;
        int idx = i * 256 + tid;
        int p = (int)(((u32)idx * 3641u) >> 16);
        int w2 = idx - p * 18;
        u32 pay = (u32)cv[i];
        if (w2 < 16) {
          int j = p * 16 + w2;
          xc16[j]        = (u16)(pay & 0xffffu);
          xc16[1024 + j] = (u16)(pay >> 16);
        } else {
          gp[p * 2 + (w2 - 16)] = unpackF(pay);
        }
      }
    }
    __syncthreads();

    // ---- gate (redundant per wave) + matvec2 + finalize + HB store (no cross-wave wait) ----
    if (prod) {
      float gs0 = gp[lane * 2], gs1 = gp[lane * 2 + 1];
      #pragma unroll
      for (int off = 32; off; off >>= 1) { gs0 += __shfl_xor(gs0, off); gs1 += __shfl_xor(gs1, off); }
      float gate[2];
      gate[0] = 1.f / (1.f + expf(-(gs0 + bg2L[0])));
      gate[1] = 1.f / (1.f + expf(-(gs1 + bg2L[0])));

      float a2[2][2];
      a2[0][0] = a2[0][1] = a2[1][0] = a2[1][1] = 0.f;
      const __half* wb2 = WL + oC2 + (w * 2) * 1024;
      for (int p2 = lane; p2 < 512; p2 += 64) {
        h2t xv0 = *(const h2t*)(xcand + 2 * p2);
        h2t xv1 = *(const h2t*)(xcand + 1024 + 2 * p2);
        #pragma unroll
        for (int cc = 0; cc < 2; ++cc) {
          h2t wv = *(const h2t*)(wb2 + cc * 1024 + 2 * p2);
          a2[cc][0] = fdot2f(wv, xv0, a2[cc][0]);
          a2[cc][1] = fdot2f(wv, xv1, a2[cc][1]);
        }
      }
      #pragma unroll
      for (int off = 32; off; off >>= 1)
        #pragma unroll
        for (int cc = 0; cc < 2; ++cc) {
          a2[cc][0] += __shfl_xor(a2[cc][0], off);
          a2[cc][1] += __shfl_xor(a2[cc][1], off);
        }
      float sel = 0.f;
      #pragma unroll
      for (int cc = 0; cc < 2; ++cc)
        #pragma unroll
        for (int b = 0; b < 2; ++b)
          if (lane == cc * 2 + b) sel = a2[cc][b];
      if (lane < 4) {
        int cc = lane >> 1, b = lane & 1, cl = w * 2 + cc;
        float cand = sel + bc2L[cl];
        float h1n = h2fu(*(const u16*)(xblh + b * 1536 + gl * 8 + cl));
        float hv = h1n + gate[b] * cand + 0.1f * rloc[cl * 2 + b];
        u32 bits; __builtin_memcpy(&bits, &hv, 4);
        u64* HBw = HBown + (size_t)(n & 1) * 1024 + gl * 16;
        gstu64(HBw + cl * 2 + b, (((u64)(u32)(n + 1)) << 32) | bits);
      }
      if (l == 1 && gl == 0 && w == 0 && lane == 0) {
        gstf(gates_out + (bp * 2) * Tn + t, gate[0]);
        gstf(gates_out + (bp * 2 + 1) * Tn + t, gate[1]);
      }
    }
  }
}

// ---------------- attention scores ----------------
__global__ __launch_bounds__(256) void scores_kernel(
    const float* __restrict__ histN,
    const float* __restrict__ wa1, const float* __restrict__ ba1,
    const float* __restrict__ wa2, const float* __restrict__ ba2,
    float* __restrict__ scores)
{
  __shared__ float xs[8][512];
  __shared__ float wacc[4][8];
  const int tid = threadIdx.x, bid = blockIdx.x;

  for (int idx = tid; idx < 4096; idx += 256)
    xs[idx >> 9][idx & 511] = histN[(size_t)(bid * 8) * Hn + idx];
  __syncthreads();

  float pr[8] = {0.f,0.f,0.f,0.f,0.f,0.f,0.f,0.f};
  #pragma unroll
  for (int cc = 0; cc < 2; ++cc) {
    int c = tid + cc * 256;
    float a[8] = {0.f,0.f,0.f,0.f,0.f,0.f,0.f,0.f};
    for (int k = 0; k < 512; ++k) {
      float wv = wa1[(size_t)k * 512 + c];
      #pragma unroll
      for (int r = 0; r < 8; ++r) a[r] = fmaf(xs[r][k], wv, a[r]);
    }
    float b1 = ba1[c], w2 = wa2[c];
    #pragma unroll
    for (int r = 0; r < 8; ++r) pr[r] += tanhf(a[r] + b1) * w2;
  }
  int lane = tid & 63, wq = tid >> 6;
  #pragma unroll
  for (int off = 32; off; off >>= 1)
    #pragma unroll
    for (int r = 0; r < 8; ++r) pr[r] += __shfl_xor(pr[r], off);
  if (lane == 0) {
    #pragma unroll
    for (int r = 0; r < 8; ++r) wacc[wq][r] = pr[r];
  }
  __syncthreads();
  if (tid < 8)
    scores[bid * 8 + tid] = wacc[0][tid] + wacc[1][tid] + wacc[2][tid] + wacc[3][tid] + ba2[0];
}

// ---------------- prefix-softmax: tiled parallel scan -> attended (bf16) ----------------
__global__ __launch_bounds__(256) void cumsum_scan_kernel(
    const float* __restrict__ scores, const float* __restrict__ histN,
    u16* __restrict__ att)
{
  __shared__ float ee[512], sa[512], sb[512], red[256];
  __shared__ float tile[64][64];
  const int tid = threadIdx.x;
  const int b = blockIdx.y, j0 = blockIdx.x * 64;

  float s0 = scores[b * Tn + tid], s1 = scores[b * Tn + tid + 256];
  red[tid] = fmaxf(s0, s1);
  __syncthreads();
  for (int s = 128; s; s >>= 1) { if (tid < s) red[tid] = fmaxf(red[tid], red[tid + s]); __syncthreads(); }
  float m = red[0];
  ee[tid] = expf(s0 - m); ee[tid + 256] = expf(s1 - m);
  sa[tid] = ee[tid]; sa[tid + 256] = ee[tid + 256];
  __syncthreads();
  float* A = sa; float* D = sb;
  for (int off = 1; off < 512; off <<= 1) {
    for (int t2 = tid; t2 < 512; t2 += 256) { float v = A[t2]; if (t2 >= off) v += A[t2 - off]; D[t2] = v; }
    __syncthreads();
    float* tmp = A; A = D; D = tmp;
  }
  float* R = D;
  for (int t2 = tid; t2 < 512; t2 += 256) R[t2] = 1.f / A[t2];
  __syncthreads();

  float ax = 0.f;
  for (int tt = 0; tt < 8; ++tt) {
    #pragma unroll
    for (int k = 0; k < 16; ++k) {
      int idx = tid + k * 256;
      int r = idx >> 6, c = idx & 63;
      tile[r][c] = histN[(size_t)(b * Tn + tt * 64 + r) * Hn + j0 + c];
    }
    __syncthreads();
    if (tid < 64) {
      for (int r = 0; r < 64; ++r) {
        int t = tt * 64 + r;
        float x = tile[r][tid];
        ax = fmaf(ee[t], x, ax);
        att[((size_t)(b * Tn + t)) * Hn + j0 + tid] = f2bf(x + ax * R[t]);
      }
    }
    __syncthreads();
  }
}

// ---------------- final GEMM ----------------
typedef short bf16x8_t __attribute__((ext_vector_type(8)));
typedef float f32x4_t  __attribute__((ext_vector_type(4)));

__global__ __launch_bounds__(256) void gemm_kernel(
    const u16* __restrict__ Aw, const u16* __restrict__ Bw,
    const float* __restrict__ bh, float* __restrict__ out)
{
  __shared__ u16 Alds[128 * 64];
  __shared__ u16 Blds[64 * 128];
  const int tid = threadIdx.x;
  const int n0 = blockIdx.x * 128, m0 = blockIdx.y * 128;
  const int w = tid >> 6, lane = tid & 63;
  const int wm = (w & 1) * 64, wn = (w >> 1) * 64;

  f32x4_t acc[4][4];
  #pragma unroll
  for (int i = 0; i < 4; ++i)
    #pragma unroll
    for (int j = 0; j < 4; ++j) acc[i][j] = (f32x4_t){0.f, 0.f, 0.f, 0.f};

  for (int kt = 0; kt < 8; ++kt) {
    const int k0 = kt * 64;
    {
      int row = tid >> 1, kc = (tid & 1) * 32;
      #pragma unroll
      for (int jj = 0; jj < 4; ++jj) {
        uint4 v = *(const uint4*)(Aw + (size_t)(m0 + row) * 512 + k0 + kc + jj * 8);
        int byte = row * 128 + (kc + jj * 8) * 2;
        byte ^= (row & 7) << 4;
        *(uint4*)((char*)Alds + byte) = v;
      }
    }
    {
      #pragma unroll
      for (int q = 0; q < 4; ++q) {
        int r = (tid >> 4) + q * 16, c8 = (tid & 15) * 8;
        uint4 v = *(const uint4*)(Bw + (size_t)(k0 + r) * NPAD + n0 + c8);
        *(uint4*)&Blds[r * 128 + c8] = v;
      }
    }
    __syncthreads();
    #pragma unroll
    for (int kh = 0; kh < 2; ++kh) {
      bf16x8_t af[4];
      #pragma unroll
      for (int i = 0; i < 4; ++i) {
        int row = wm + i * 16 + (lane & 15);
        int byte = row * 128 + kh * 64 + (lane >> 4) * 16;
        byte ^= (row & 7) << 4;
        af[i] = *(const bf16x8_t*)((const char*)Alds + byte);
      }
      const int kb = kh * 32 + (lane >> 4) * 8;
      #pragma unroll
      for (int j = 0; j < 4; ++j) {
        int col = wn + j * 16 + (lane & 15);
        bf16x8_t bf;
        #pragma unroll
        for (int jj = 0; jj < 8; ++jj) bf[jj] = (short)Blds[(kb + jj) * 128 + col];
        #pragma unroll
        for (int i = 0; i < 4; ++i)
          acc[i][j] = __builtin_amdgcn_mfma_f32_16x16x32_bf16(af[i], bf, acc[i][j], 0, 0, 0);
      }
    }
    __syncthreads();
  }
  #pragma unroll
  for (int j = 0; j < 4; ++j) {
    int col = n0 + wn + j * 16 + (lane & 15);
    if (col < Vn) {
      float bias = bh[col];
      #pragma unroll
      for (int i = 0; i < 4; ++i) {
        int rbase = m0 + wm + i * 16 + (lane >> 4) * 4;
        #pragma unroll
        for (int r = 0; r < 4; ++r)
          out[(size_t)(rbase + r) * Vn + col] = acc[i][j][r] + bias;
      }
    }
  }
}

// ---------------- host ----------------
extern "C" void kernel_launch(void* const* d_in, const int* in_sizes, int n_in,
                              void* d_out, int out_size, void* d_ws, size_t ws_size,
                              hipStream_t stream) {
  const int*   ids  = (const int*)d_in[0];
  const float* emb  = (const float*)d_in[1];
  const float* Wc1_0 = (const float*)d_in[2];  const float* bc1_0 = (const float*)d_in[3];
  const float* Wc2_0 = (const float*)d_in[4];  const float* bc2_0 = (const float*)d_in[5];
  const float* Wg1_0 = (const float*)d_in[6];  const float* bg1_0 = (const float*)d_in[7];
  const float* Wg2_0 = (const float*)d_in[8];  const float* bg2_0 = (const float*)d_in[9];
  const float* Wr_0  = (const float*)d_in[10]; const float* br_0  = (const float*)d_in[11];
  const float* Wc1_1 = (const float*)d_in[12]; const float* bc1_1 = (const float*)d_in[13];
  const float* Wc2_1 = (const float*)d_in[14]; const float* bc2_1 = (const float*)d_in[15];
  const float* Wg1_1 = (const float*)d_in[16]; const float* bg1_1 = (const float*)d_in[17];
  const float* Wg2_1 = (const float*)d_in[18]; const float* bg2_1 = (const float*)d_in[19];
  const float* Wr_1  = (const float*)d_in[20]; const float* br_1  = (const float*)d_in[21];
  const float* Wa1 = (const float*)d_in[22]; const float* ba1 = (const float*)d_in[23];
  const float* Wa2 = (const float*)d_in[24]; const float* ba2 = (const float*)d_in[25];
  const float* Wh  = (const float*)d_in[26]; const float* bh  = (const float*)d_in[27];

  float* out = (float*)d_out;
  char*  ws  = (char*)d_ws;

  const size_t OFF_FLAGA = 0;                          // 32768
  const size_t OFF_HB    = 32768;                      // 65536
  const size_t OFF_CB    = 98304;                      // 73728
  const size_t OFF_WT    = 172032;                     // 11534336
  const size_t OFF_HISTN = OFF_WT + 11534336;
  const size_t OFF_SCO   = OFF_HISTN + 4194304;
  const size_t OFF_ATT   = OFF_SCO + 8192;
  const size_t OFF_WHB   = OFF_ATT + 2097152;

  u32*   flagA  = (u32*)(ws + OFF_FLAGA);
  u64*   HB     = (u64*)(ws + OFF_HB);
  u64*   CB     = (u64*)(ws + OFF_CB);
  __half* wth   = (__half*)(ws + OFF_WT);
  float* histN  = (float*)(ws + OFF_HISTN);
  float* scores = (float*)(ws + OFF_SCO);
  u16*   att    = (u16*)(ws + OFF_ATT);
  u16*   whb    = (u16*)(ws + OFF_WHB);
  float* gates  = out + (size_t)Bn * Tn * Vn;

  __half* wtC1_0h = wth;
  __half* wtG1_0h = wth + 1310720;
  __half* wtC2_0h = wth + 1966080;
  __half* wtR_0h  = wth + 2490368;
  __half* wtC1_1h = wth + 2621440;
  __half* wtG1_1h = wth + 4194304;
  __half* wtC2_1h = wth + 4980736;
  __half* wtR_1h  = wth + 5505024;

  hipMemsetAsync(ws, 0, 172032, stream);   // flagA + HB + CB tags

  transpose_h<<<dim3(32, 40), 256, 0, stream>>>(Wc1_0, wtC1_0h, 1280, 1024);
  transpose_h<<<dim3(16, 40), 256, 0, stream>>>(Wg1_0, wtG1_0h, 1280, 512);
  transpose_h<<<dim3(16, 32), 256, 0, stream>>>(Wc2_0, wtC2_0h, 1024, 512);
  transpose_h<<<dim3(16,  8), 256, 0, stream>>>(Wr_0,  wtR_0h,   256, 512);
  transpose_h<<<dim3(32, 48), 256, 0, stream>>>(Wc1_1, wtC1_1h, 1536, 1024);
  transpose_h<<<dim3(16, 48), 256, 0, stream>>>(Wg1_1, wtG1_1h, 1536, 512);
  transpose_h<<<dim3(16, 32), 256, 0, stream>>>(Wc2_1, wtC2_1h, 1024, 512);
  transpose_h<<<dim3(16, 16), 256, 0, stream>>>(Wr_1,  wtR_1h,   512, 512);

  convwh_kernel<<<dim3(99, 512), 256, 0, stream>>>(Wh, whb);

  (void)hipFuncSetAttribute((const void*)rec_kernel,
                            hipFuncAttributeMaxDynamicSharedMemorySize, REC_LDS);

  rec_kernel<<<dim3(RG), dim3(RNT), REC_LDS, stream>>>(
      ids, emb,
      wtC1_0h, wtG1_0h, wtC2_0h, wtR_0h,
      wtC1_1h, wtG1_1h, wtC2_1h, wtR_1h,
      bc1_0, bg1_0, bc2_0, br_0, Wg2_0, bg2_0,
      bc1_1, bg1_1, bc2_1, br_1, Wg2_1, bg2_1,
      flagA, HB, CB, histN, gates);

  scores_kernel<<<dim3(256), 256, 0, stream>>>(histN, Wa1, ba1, Wa2, ba2, scores);

  cumsum_scan_kernel<<<dim3(8, Bn), 256, 0, stream>>>(scores, histN, att);

  gemm_kernel<<<dim3(393, 16), 256, 0, stream>>>(att, whb, bh, out);
}

// Round 9
// 4521.933 us; speedup vs baseline: 5.2235x; 1.1938x over previous
//
#include <hip/hip_runtime.h>
#include <hip/hip_fp16.h>
#include <cstdint>
#include <cstddef>

typedef unsigned short u16;
typedef unsigned int   u32;
typedef unsigned long long u64;

#define Bn 4
#define Tn 512
#define Hn 512
#define En 256
#define Vn 50257
#define NPAD 50304
#define RG  256
#define RNT 256

typedef _Float16 h2t __attribute__((ext_vector_type(2)));

#if defined(__has_builtin)
#if __has_builtin(__builtin_amdgcn_fdot2)
#define HAS_FDOT2 1
#endif
#endif
__device__ __forceinline__ float fdot2f(h2t a, h2t b, float c) {
#ifdef HAS_FDOT2
  return __builtin_amdgcn_fdot2(a, b, c, false);
#else
  return fmaf((float)a[0], (float)b[0], fmaf((float)a[1], (float)b[1], c));
#endif
}

__device__ __forceinline__ u16 f2bf(float f) {
  u32 x; __builtin_memcpy(&x, &f, 4);
  u32 r = (x + 0x7fffu + ((x >> 16) & 1u)) >> 16;
  return (u16)r;
}
__device__ __forceinline__ u16 f2h(float f) {
  __half hh = __float2half(f); u16 u; __builtin_memcpy(&u, &hh, 2); return u;
}
__device__ __forceinline__ float h2fu(u16 h) {
  __half hh; __builtin_memcpy(&hh, &h, 2); return __half2float(hh);
}
__device__ __forceinline__ u64 gldu64(const u64* p) {
  return __hip_atomic_load(p, __ATOMIC_RELAXED, __HIP_MEMORY_SCOPE_AGENT);
}
__device__ __forceinline__ void gstu64(u64* p, u64 v) {
  __hip_atomic_store(p, v, __ATOMIC_RELAXED, __HIP_MEMORY_SCOPE_AGENT);
}
__device__ __forceinline__ u32 gldu32(const u32* p) {
  return __hip_atomic_load(p, __ATOMIC_RELAXED, __HIP_MEMORY_SCOPE_AGENT);
}
__device__ __forceinline__ void gstu32(u32* p, u32 v) {
  __hip_atomic_store(p, v, __ATOMIC_RELAXED, __HIP_MEMORY_SCOPE_AGENT);
}
__device__ __forceinline__ void gstf(float* p, float v) {
  __hip_atomic_store(p, v, __ATOMIC_RELAXED, __HIP_MEMORY_SCOPE_AGENT);
}

// ---------------- prep kernels ----------------
__global__ __launch_bounds__(256) void transpose_h(
    const float* __restrict__ src, __half* __restrict__ dst, int K, int N)
{
  __shared__ float tile[32][33];
  const int tx = threadIdx.x & 31, ty = threadIdx.x >> 5;
  const int bn = blockIdx.x * 32, bk = blockIdx.y * 32;
  #pragma unroll
  for (int i = 0; i < 4; ++i)
    tile[ty + i * 8][tx] = src[(size_t)(bk + ty + i * 8) * N + bn + tx];
  __syncthreads();
  #pragma unroll
  for (int i = 0; i < 4; ++i)
    dst[(size_t)(bn + ty + i * 8) * K + bk + tx] = __float2half(tile[tx][ty + i * 8]);
}

__global__ __launch_bounds__(256) void convwh_kernel(
    const float* __restrict__ wh, u16* __restrict__ whb)
{
  const int k = blockIdx.y;
  const int v0 = (blockIdx.x * 256 + threadIdx.x) * 2;
  if (v0 >= NPAD) return;
  float a = (v0     < Vn) ? wh[(size_t)k * Vn + v0]     : 0.f;
  float b = (v0 + 1 < Vn) ? wh[(size_t)k * Vn + v0 + 1] : 0.f;
  u32 pack = (u32)f2bf(a) | ((u32)f2bf(b) << 16);
  *(u32*)&whb[(size_t)k * NPAD + v0] = pack;
}

// ---- dynamic LDS byte offsets (weights 0..98303) ----
#define HR16_B  98304    // [2 par][2 b][512] fp16 = 4096
#define HR0_B   102400   // [2 b][512] fp16 = 2048
#define EMB_B   104448   // [2 b][256] fp16 = 1024
#define XCAND_B 105472   // [2 b][1024] fp16 = 4096
#define GP_B    109568   // [64][2] f32 = 512
#define RLOC_B  110080   // [8][2] f32 = 64
#define SS_B    110144   // 80 f32 = 320
#define BC1L_B  110464   // 16 f32
#define BG1L_B  110528   // 8
#define BC2L_B  110560   // 8
#define BRL_B   110592   // 8
#define WG2L_B  110624   // 8
#define BG2L_B  110656   // 4
#define REC_LDS 110720

// ---------------- persistent recurrence ----------------
// g: bp=g>>7, l=(g>>6)&1, gl=g&63. Raw-h fp16 broadcast, analytic LN fixup.
// HB[(bp,l,par)]: 64 prod x 8 u64 (fp16-pair raw h + tag).
// CB[(bp,l,par)]: 64 prod x 18 u64 (16 fp16-pair cand1 + 2 fp32 gate partials).
__global__ __launch_bounds__(RNT, 1) void rec_kernel(
    const int* __restrict__ ids, const float* __restrict__ emb,
    const __half* wtC1_0, const __half* wtG1_0, const __half* wtC2_0, const __half* wtR_0,
    const __half* wtC1_1, const __half* wtG1_1, const __half* wtC2_1, const __half* wtR_1,
    const float* bc1_0, const float* bg1_0, const float* bc2_0, const float* br_0,
    const float* wg2_0, const float* bg2_0,
    const float* bc1_1, const float* bg1_1, const float* bc2_1, const float* br_1,
    const float* wg2_1, const float* bg2_1,
    u32* flagA, u64* HB, u64* CB,
    float* __restrict__ histN, float* __restrict__ gates_out)
{
  extern __shared__ char smem[];
  __half* WL    = (__half*)smem;
  __half* hr16  = (__half*)(smem + HR16_B);
  __half* hr0   = (__half*)(smem + HR0_B);
  __half* emb16 = (__half*)(smem + EMB_B);
  __half* xcand = (__half*)(smem + XCAND_B);
  float* gp     = (float*)(smem + GP_B);
  float* rloc   = (float*)(smem + RLOC_B);
  float* Ss     = (float*)(smem + SS_B);
  float* bc1L   = (float*)(smem + BC1L_B);
  float* bg1L   = (float*)(smem + BG1L_B);
  float* bc2L   = (float*)(smem + BC2L_B);
  float* brL    = (float*)(smem + BRL_B);
  float* wg2L   = (float*)(smem + WG2L_B);
  float* bg2L   = (float*)(smem + BG2L_B);

  const int tid = threadIdx.x, g = blockIdx.x;
  const int bp = g >> 7, l = (g >> 6) & 1, gl = g & 63;
  const int w = tid >> 6, lane = tid & 63;
  const int C = l ? 1536 : 1280;
  const int e = l ? 512 : 256;
  const int oG1 = 16 * C, oR = 24 * C, oC2 = 24 * C + 8 * e;

  const __half* wtC1 = l ? wtC1_1 : wtC1_0;
  const __half* wtG1 = l ? wtG1_1 : wtG1_0;
  const __half* wtC2 = l ? wtC2_1 : wtC2_0;
  const __half* wtR  = l ? wtR_1  : wtR_0;
  const float* bc1 = l ? bc1_1 : bc1_0;
  const float* bg1 = l ? bg1_1 : bg1_0;
  const float* bc2 = l ? bc2_1 : bc2_0;
  const float* br  = l ? br_1  : br_0;
  const float* wg2 = l ? wg2_1 : wg2_0;
  const float* bg2 = l ? bg2_1 : bg2_0;

  u64* HBown = HB + (size_t)((bp * 2 + l) * 2) * 512;
  u64* CBown = CB + (size_t)((bp * 2 + l) * 2) * 1152;
  const u64* HBl0 = HB + (size_t)((bp * 2) * 2) * 512;

  // ---- init: stage weights + zero comm LDS ----
  {
    auto cp = [&](const __half* src, int nh, int offh) {
      const u32* s = (const u32*)src; u32* d = (u32*)(WL + offh);
      for (int i = tid; i < (nh >> 1); i += RNT) d[i] = s[i];
    };
    cp(wtC1 + (size_t)(gl * 16) * C, 16 * C, 0);
    cp(wtG1 + (size_t)(gl * 8) * C,  8 * C, oG1);
    cp(wtR  + (size_t)(gl * 8) * e,  8 * e, oR);
    cp(wtC2 + (size_t)(gl * 8) * 1024, 8 * 1024, oC2);
  }
  for (int i = tid; i < 2960; i += RNT) ((u32*)(smem + HR16_B))[i] = 0;
  __syncthreads();

  // biases + per-column weight section-sums
  if (tid < 16)      bc1L[tid] = bc1[gl * 16 + tid];
  else if (tid < 24) bg1L[tid - 16] = bg1[gl * 8 + tid - 16];
  else if (tid < 32) bc2L[tid - 24] = bc2[gl * 8 + tid - 24];
  else if (tid < 40) brL[tid - 32]  = br[gl * 8 + tid - 32];
  else if (tid < 48) wg2L[tid - 40] = wg2[gl * 8 + tid - 40];
  else if (tid == 48) bg2L[0] = bg2[0];
  for (int task = w; task < 32; task += 4) {
    const __half* colp; int K;
    if (task < 16)      { colp = WL + (size_t)task * C;              K = C; }
    else if (task < 24) { colp = WL + oG1 + (size_t)(task - 16) * C; K = C; }
    else                { colp = WL + oR  + (size_t)(task - 24) * e; K = e; }
    float s1 = 0.f, s2 = 0.f, s3 = 0.f;
    for (int k = lane; k < K; k += 64) {
      float v = __half2float(colp[k]);
      if (K == e) s1 += v;
      else if (k < 512) s1 += v;
      else if (k < 1024) s2 += v;
      else s3 += v;
    }
    #pragma unroll
    for (int off = 32; off; off >>= 1) {
      s1 += __shfl_xor(s1, off); s2 += __shfl_xor(s2, off); s3 += __shfl_xor(s3, off);
    }
    if (lane == 0) {
      if (task < 16)      { Ss[task] = s1; Ss[16 + task] = s2; Ss[32 + task] = s3; }
      else if (task < 24) { Ss[48 + task - 16] = s1; Ss[56 + task - 16] = s2; Ss[64 + task - 16] = s3; }
      else                { Ss[72 + task - 24] = s1; }
    }
  }
  __syncthreads();

  const int nEnd = l ? (Tn + 1) : (Tn - 1);
  float mp[2] = {0.f, 0.f}, ipv[2] = {0.f, 0.f};   // prev-step stats (h(t-2))

  for (int n = 0; n <= nEnd; ++n) {
    const int t = n - l;
    const bool prod = (t >= 0) && (t < Tn);
    const bool pollOwn = (t >= 1) && (t <= Tn);
    const bool pollL0  = (l == 1) && prod;
    const int parR = (n - 1) & 1;

    // ---- early loads (l0): ids + emb ----
    float2 e2 = make_float2(0.f, 0.f);
    if (l == 0 && prod) {
      int idv = ids[(bp * 2 + (w >> 1)) * Tn + t];
      e2 = *(const float2*)(emb + (size_t)idv * En + (tid & 127) * 2);
    }

    // ---- Phase A: poll raw-h broadcast (fp16 pairs) ----
    if (pollOwn || pollL0) {
      const u64* s1 = HBown + (size_t)parR * 512;
      const u64* s0 = HBl0 + (size_t)parR * 512;
      const u32 want = (u32)n;
      u64 v1[2], v0[2];
      for (;;) {
        bool ok = true;
        if (pollOwn) { v1[0] = gldu64(s1 + tid); v1[1] = gldu64(s1 + 256 + tid); }
        if (pollL0)  { v0[0] = gldu64(s0 + tid); v0[1] = gldu64(s0 + 256 + tid); }
        if (pollOwn) ok &= ((u32)(v1[0] >> 32) == want) & ((u32)(v1[1] >> 32) == want);
        if (pollL0)  ok &= ((u32)(v0[0] >> 32) == want) & ((u32)(v0[1] >> 32) == want);
        if (ok) break;
        __builtin_amdgcn_s_sleep(1);
      }
      if (pollOwn) {
        #pragma unroll
        for (int i = 0; i < 2; ++i) {
          int W = i * 256 + tid;
          int glp = W >> 3, q = W & 7, cpp = q >> 1, b = q & 1;
          ((u32*)(hr16 + (parR * 2 + b) * 512))[glp * 4 + cpp] = (u32)v1[i];
        }
      }
      if (pollL0) {
        #pragma unroll
        for (int i = 0; i < 2; ++i) {
          int W = i * 256 + tid;
          int glp = W >> 3, q = W & 7, cpp = q >> 1, b = q & 1;
          ((u32*)(hr0 + b * 512))[glp * 4 + cpp] = (u32)v0[i];
        }
      }
    }
    if (l == 0 && prod) {
      u32 pp = (u32)f2h(e2.x) | ((u32)f2h(e2.y) << 16);
      ((u32*)emb16)[(w >> 1) * 128 + (tid & 127)] = pp;
    }
    __syncthreads();
    if (l == 1 && tid == 0) gstu32(flagA + (bp * 64 + gl) * 16, (u32)(n + 1));

    // ---- per-wave redundant stats (no barrier) ----
    float m1[2] = {0.f, 0.f}, i1v[2] = {0.f, 0.f};
    float m3[2] = {0.f, 0.f}, i3v[2] = {0.f, 0.f};
    if (pollOwn) {
      float s[2] = {0.f, 0.f}, q[2] = {0.f, 0.f};
      #pragma unroll
      for (int b = 0; b < 2; ++b) {
        const u32* hp = (const u32*)(hr16 + (parR * 2 + b) * 512);
        #pragma unroll
        for (int i2 = 0; i2 < 4; ++i2) {
          u32 vv = hp[lane + i2 * 64];
          __half2 hh; __builtin_memcpy(&hh, &vv, 4);
          float2 f2 = __half22float2(hh);
          s[b] += f2.x + f2.y; q[b] += f2.x * f2.x + f2.y * f2.y;
        }
      }
      #pragma unroll
      for (int off = 32; off; off >>= 1) {
        s[0] += __shfl_xor(s[0], off); q[0] += __shfl_xor(q[0], off);
        s[1] += __shfl_xor(s[1], off); q[1] += __shfl_xor(q[1], off);
      }
      #pragma unroll
      for (int b = 0; b < 2; ++b) {
        float m = s[b] * (1.f / 512.f);
        m1[b] = m; i1v[b] = rsqrtf(q[b] * (1.f / 512.f) - m * m + 1e-5f);
      }
    }
    if (pollL0) {
      float s[2] = {0.f, 0.f}, q[2] = {0.f, 0.f};
      #pragma unroll
      for (int b = 0; b < 2; ++b) {
        const u32* hp = (const u32*)(hr0 + b * 512);
        #pragma unroll
        for (int i2 = 0; i2 < 4; ++i2) {
          u32 vv = hp[lane + i2 * 64];
          __half2 hh; __builtin_memcpy(&hh, &vv, 4);
          float2 f2 = __half22float2(hh);
          s[b] += f2.x + f2.y; q[b] += f2.x * f2.x + f2.y * f2.y;
        }
      }
      #pragma unroll
      for (int off = 32; off; off >>= 1) {
        s[0] += __shfl_xor(s[0], off); q[0] += __shfl_xor(q[0], off);
        s[1] += __shfl_xor(s[1], off); q[1] += __shfl_xor(q[1], off);
      }
      #pragma unroll
      for (int b = 0; b < 2; ++b) {
        float m = s[b] * (1.f / 512.f);
        m3[b] = m; i3v[b] = rsqrtf(q[b] * (1.f / 512.f) - m * m + 1e-5f);
      }
    }

    // ---- histN (l1): normalized h(t-1) ----
    if (l == 1 && pollOwn && tid < 16) {
      int c = tid >> 1, b = tid & 1, j = gl * 8 + c;
      float rv = __half2float(hr16[(parR * 2 + b) * 512 + j]);
      gstf(histN + ((size_t)((bp * 2 + b) * Tn + (t - 1))) * Hn + j, (rv - m1[b]) * i1v[b]);
    }

    // ---- matvec1 on raw h (3-section, analytic fixup) + CB store ----
    if (prod) {
      float comb[8][2];
      #pragma unroll
      for (int c = 0; c < 8; ++c) { comb[c][0] = 0.f; comb[c][1] = 0.f; }
      const __half* h1p[2] = { hr16 + (parR * 2) * 512, hr16 + (parR * 2 + 1) * 512 };
      const __half* h2p[2] = { hr16 + ((parR ^ 1) * 2) * 512, hr16 + ((parR ^ 1) * 2 + 1) * 512 };
      float a[8][2];

      if (w < 3) {
        const __half* wbase = (w < 2) ? (WL + (size_t)(w * 8) * C) : (WL + oG1);
        // sec1: h1 raw
        #pragma unroll
        for (int c = 0; c < 8; ++c) { a[c][0] = 0.f; a[c][1] = 0.f; }
        #pragma unroll
        for (int it = 0; it < 4; ++it) {
          int p2 = lane + it * 64;
          h2t x0 = *(const h2t*)(h1p[0] + 2 * p2);
          h2t x1 = *(const h2t*)(h1p[1] + 2 * p2);
          #pragma unroll
          for (int c = 0; c < 8; ++c) {
            h2t wv = *(const h2t*)(wbase + (size_t)c * C + 2 * p2);
            a[c][0] = fdot2f(wv, x0, a[c][0]);
            a[c][1] = fdot2f(wv, x1, a[c][1]);
          }
        }
        #pragma unroll
        for (int c = 0; c < 8; ++c) { comb[c][0] += i1v[0] * a[c][0]; comb[c][1] += i1v[1] * a[c][1]; }
        // sec2: h2 raw (prev parity, prev stats)
        #pragma unroll
        for (int c = 0; c < 8; ++c) { a[c][0] = 0.f; a[c][1] = 0.f; }
        #pragma unroll
        for (int it = 0; it < 4; ++it) {
          int p2 = lane + it * 64;
          h2t x0 = *(const h2t*)(h2p[0] + 2 * p2);
          h2t x1 = *(const h2t*)(h2p[1] + 2 * p2);
          #pragma unroll
          for (int c = 0; c < 8; ++c) {
            h2t wv = *(const h2t*)(wbase + (size_t)c * C + 512 + 2 * p2);
            a[c][0] = fdot2f(wv, x0, a[c][0]);
            a[c][1] = fdot2f(wv, x1, a[c][1]);
          }
        }
        #pragma unroll
        for (int c = 0; c < 8; ++c) { comb[c][0] += ipv[0] * a[c][0]; comb[c][1] += ipv[1] * a[c][1]; }
        // sec3: inp
        #pragma unroll
        for (int c = 0; c < 8; ++c) { a[c][0] = 0.f; a[c][1] = 0.f; }
        if (l == 0) {
          #pragma unroll
          for (int it = 0; it < 2; ++it) {
            int p2 = lane + it * 64;
            h2t x0 = *(const h2t*)(emb16 + 2 * p2);
            h2t x1 = *(const h2t*)(emb16 + 256 + 2 * p2);
            #pragma unroll
            for (int c = 0; c < 8; ++c) {
              h2t wv = *(const h2t*)(wbase + (size_t)c * C + 1024 + 2 * p2);
              a[c][0] = fdot2f(wv, x0, a[c][0]);
              a[c][1] = fdot2f(wv, x1, a[c][1]);
            }
          }
          #pragma unroll
          for (int c = 0; c < 8; ++c) { comb[c][0] += a[c][0]; comb[c][1] += a[c][1]; }
        } else {
          #pragma unroll
          for (int it = 0; it < 4; ++it) {
            int p2 = lane + it * 64;
            h2t x0 = *(const h2t*)(hr0 + 2 * p2);
            h2t x1 = *(const h2t*)(hr0 + 512 + 2 * p2);
            #pragma unroll
            for (int c = 0; c < 8; ++c) {
              h2t wv = *(const h2t*)(wbase + (size_t)c * C + 1024 + 2 * p2);
              a[c][0] = fdot2f(wv, x0, a[c][0]);
              a[c][1] = fdot2f(wv, x1, a[c][1]);
            }
          }
          #pragma unroll
          for (int c = 0; c < 8; ++c) { comb[c][0] += i3v[0] * a[c][0]; comb[c][1] += i3v[1] * a[c][1]; }
        }
      } else {
        // w==3: Wr over inp
        #pragma unroll
        for (int c = 0; c < 8; ++c) { a[c][0] = 0.f; a[c][1] = 0.f; }
        if (l == 0) {
          #pragma unroll
          for (int it = 0; it < 2; ++it) {
            int p2 = lane + it * 64;
            h2t x0 = *(const h2t*)(emb16 + 2 * p2);
            h2t x1 = *(const h2t*)(emb16 + 256 + 2 * p2);
            #pragma unroll
            for (int c = 0; c < 8; ++c) {
              h2t wv = *(const h2t*)(WL + oR + (size_t)c * e + 2 * p2);
              a[c][0] = fdot2f(wv, x0, a[c][0]);
              a[c][1] = fdot2f(wv, x1, a[c][1]);
            }
          }
          #pragma unroll
          for (int c = 0; c < 8; ++c) { comb[c][0] = a[c][0]; comb[c][1] = a[c][1]; }
        } else {
          #pragma unroll
          for (int it = 0; it < 4; ++it) {
            int p2 = lane + it * 64;
            h2t x0 = *(const h2t*)(hr0 + 2 * p2);
            h2t x1 = *(const h2t*)(hr0 + 512 + 2 * p2);
            #pragma unroll
            for (int c = 0; c < 8; ++c) {
              h2t wv = *(const h2t*)(WL + oR + (size_t)c * e + 2 * p2);
              a[c][0] = fdot2f(wv, x0, a[c][0]);
              a[c][1] = fdot2f(wv, x1, a[c][1]);
            }
          }
          #pragma unroll
          for (int c = 0; c < 8; ++c) { comb[c][0] = i3v[0] * a[c][0]; comb[c][1] = i3v[1] * a[c][1]; }
        }
      }
      #pragma unroll
      for (int off = 32; off; off >>= 1)
        #pragma unroll
        for (int c = 0; c < 8; ++c) {
          comb[c][0] += __shfl_xor(comb[c][0], off);
          comb[c][1] += __shfl_xor(comb[c][1], off);
        }
      float v0s = 0.f, v1s = 0.f;
      #pragma unroll
      for (int c = 0; c < 8; ++c)
        if (lane == c) { v0s = comb[c][0]; v1s = comb[c][1]; }

      const u64 tagw = ((u64)(u32)(n + 1)) << 32;
      u64* CBw = CBown + (size_t)(n & 1) * 1152 + gl * 18;
      if (w < 2) {
        if (lane < 8) {
          int cg = w * 8 + lane;
          float k0 = i1v[0] * m1[0] * Ss[cg] + ipv[0] * mp[0] * Ss[16 + cg];
          float k1 = i1v[1] * m1[1] * Ss[cg] + ipv[1] * mp[1] * Ss[16 + cg];
          if (l) { k0 += i3v[0] * m3[0] * Ss[32 + cg]; k1 += i3v[1] * m3[1] * Ss[32 + cg]; }
          float bb = bc1L[cg];
          float c0 = fmaxf(v0s - k0 + bb, 0.f), c1 = fmaxf(v1s - k1 + bb, 0.f);
          u32 pay = (u32)f2h(c0) | ((u32)f2h(c1) << 16);
          gstu64(CBw + cg, tagw | pay);
        }
      } else if (w == 2) {
        if (lane < 8) {
          float k0 = i1v[0] * m1[0] * Ss[48 + lane] + ipv[0] * mp[0] * Ss[56 + lane];
          float k1 = i1v[1] * m1[1] * Ss[48 + lane] + ipv[1] * mp[1] * Ss[56 + lane];
          if (l) { k0 += i3v[0] * m3[0] * Ss[64 + lane]; k1 += i3v[1] * m3[1] * Ss[64 + lane]; }
          float bgv = bg1L[lane], wgv = wg2L[lane];
          float t0 = tanhf(v0s - k0 + bgv) * wgv;
          float t1 = tanhf(v1s - k1 + bgv) * wgv;
          #pragma unroll
          for (int off = 1; off < 8; off <<= 1) { t0 += __shfl_xor(t0, off); t1 += __shfl_xor(t1, off); }
          if (lane == 0) {
            u32 b0, b1; __builtin_memcpy(&b0, &t0, 4); __builtin_memcpy(&b1, &t1, 4);
            gstu64(CBw + 16, tagw | b0);
            gstu64(CBw + 17, tagw | b1);
          }
        }
      } else {
        if (lane < 8) {
          float k0 = l ? i3v[0] * m3[0] * Ss[72 + lane] : 0.f;
          float k1 = l ? i3v[1] * m3[1] * Ss[72 + lane] : 0.f;
          rloc[lane * 2]     = v0s - k0 + brL[lane];
          rloc[lane * 2 + 1] = v1s - k1 + brL[lane];
        }
      }
    }

    // ---- Phase B: poll cand1-broadcast + l0 backpressure ----
    if (prod) {
      const u64* CBL = CBown + (size_t)(n & 1) * 1152;
      const u32 want = (u32)(n + 1);
      const bool needF = (l == 0) && (tid < 64);
      const u32* fptr = flagA + (bp * 64 + tid) * 16;
      u64 cv[5];
      const bool last = (tid < 128);
      for (;;) {
        bool ok = true;
        #pragma unroll
        for (int i = 0; i < 4; ++i) cv[i] = gldu64(CBL + i * 256 + tid);
        if (last) cv[4] = gldu64(CBL + 1024 + tid);
        #pragma unroll
        for (int i = 0; i < 4; ++i) ok &= ((u32)(cv[i] >> 32) == want);
        if (last) ok &= ((u32)(cv[4] >> 32) == want);
        if (needF) ok &= (gldu32(fptr) >= (u32)n);
        if (ok) break;
        __builtin_amdgcn_s_sleep(1);
      }
      u16* xc16 = (u16*)xcand;
      #pragma unroll
      for (int i = 0; i < 5; ++i) {
        if (i == 4 && !last) break;
        int idx = i * 256 + tid;
        int p = (int)(((u32)idx * 3641u) >> 16);
        int w2 = idx - p * 18;
        u32 pay = (u32)cv[i];
        if (w2 < 16) {
          int j = p * 16 + w2;
          xc16[j]        = (u16)(pay & 0xffffu);
          xc16[1024 + j] = (u16)(pay >> 16);
        } else {
          float f; __builtin_memcpy(&f, &pay, 4);
          gp[p * 2 + (w2 - 16)] = f;
        }
      }
    }
    __syncthreads();

    // ---- gate (redundant/wave) + matvec2 + finalize + HB store ----
    if (prod) {
      float gs0 = gp[lane * 2], gs1 = gp[lane * 2 + 1];
      #pragma unroll
      for (int off = 32; off; off >>= 1) { gs0 += __shfl_xor(gs0, off); gs1 += __shfl_xor(gs1, off); }
      float gate[2];
      gate[0] = 1.f / (1.f + expf(-(gs0 + bg2L[0])));
      gate[1] = 1.f / (1.f + expf(-(gs1 + bg2L[0])));

      float a2[2][2];
      a2[0][0] = a2[0][1] = a2[1][0] = a2[1][1] = 0.f;
      const __half* wb2 = WL + oC2 + (w * 2) * 1024;
      #pragma unroll
      for (int it = 0; it < 8; ++it) {
        int p2 = lane + it * 64;
        h2t xv0 = *(const h2t*)(xcand + 2 * p2);
        h2t xv1 = *(const h2t*)(xcand + 1024 + 2 * p2);
        #pragma unroll
        for (int cc = 0; cc < 2; ++cc) {
          h2t wv = *(const h2t*)(wb2 + cc * 1024 + 2 * p2);
          a2[cc][0] = fdot2f(wv, xv0, a2[cc][0]);
          a2[cc][1] = fdot2f(wv, xv1, a2[cc][1]);
        }
      }
      #pragma unroll
      for (int off = 32; off; off >>= 1)
        #pragma unroll
        for (int cc = 0; cc < 2; ++cc) {
          a2[cc][0] += __shfl_xor(a2[cc][0], off);
          a2[cc][1] += __shfl_xor(a2[cc][1], off);
        }
      float sel = 0.f;
      #pragma unroll
      for (int cc = 0; cc < 2; ++cc)
        #pragma unroll
        for (int b = 0; b < 2; ++b)
          if (lane == cc * 2 + b) sel = a2[cc][b];
      // finalize for lanes 0..3 (cc=lane>>1, b=lane&1)
      int cc = (lane >> 1) & 1, b = lane & 1, cl = w * 2 + cc;
      float rv = __half2float(hr16[(parR * 2 + b) * 512 + gl * 8 + cl]);
      float h1n = (rv - m1[b]) * i1v[b];
      float hv = h1n + gate[b] * (sel + bc2L[cl]) + 0.1f * rloc[cl * 2 + b];
      float hv0 = __shfl(hv, 0), hv1 = __shfl(hv, 1);
      float hv2 = __shfl(hv, 2), hv3 = __shfl(hv, 3);
      if (lane < 2) {
        u32 pay = (lane == 0) ? ((u32)f2h(hv0) | ((u32)f2h(hv2) << 16))
                              : ((u32)f2h(hv1) | ((u32)f2h(hv3) << 16));
        u64* HBw = HBown + (size_t)(n & 1) * 512 + gl * 8;
        gstu64(HBw + w * 2 + lane, (((u64)(u32)(n + 1)) << 32) | pay);
      }
      if (l == 1 && gl == 0 && w == 0 && lane == 0) {
        gstf(gates_out + (bp * 2) * Tn + t, gate[0]);
        gstf(gates_out + (bp * 2 + 1) * Tn + t, gate[1]);
      }
    }

    // ---- save prev stats ----
    if (pollOwn) { mp[0] = m1[0]; mp[1] = m1[1]; ipv[0] = i1v[0]; ipv[1] = i1v[1]; }
  }
}

// ---------------- attention scores ----------------
__global__ __launch_bounds__(256) void scores_kernel(
    const float* __restrict__ histN,
    const float* __restrict__ wa1, const float* __restrict__ ba1,
    const float* __restrict__ wa2, const float* __restrict__ ba2,
    float* __restrict__ scores)
{
  __shared__ float xs[8][512];
  __shared__ float wacc[4][8];
  const int tid = threadIdx.x, bid = blockIdx.x;

  for (int idx = tid; idx < 4096; idx += 256)
    xs[idx >> 9][idx & 511] = histN[(size_t)(bid * 8) * Hn + idx];
  __syncthreads();

  float pr[8] = {0.f,0.f,0.f,0.f,0.f,0.f,0.f,0.f};
  #pragma unroll
  for (int cc = 0; cc < 2; ++cc) {
    int c = tid + cc * 256;
    float a[8] = {0.f,0.f,0.f,0.f,0.f,0.f,0.f,0.f};
    for (int k = 0; k < 512; ++k) {
      float wv = wa1[(size_t)k * 512 + c];
      #pragma unroll
      for (int r = 0; r < 8; ++r) a[r] = fmaf(xs[r][k], wv, a[r]);
    }
    float b1 = ba1[c], w2 = wa2[c];
    #pragma unroll
    for (int r = 0; r < 8; ++r) pr[r] += tanhf(a[r] + b1) * w2;
  }
  int lane = tid & 63, wq = tid >> 6;
  #pragma unroll
  for (int off = 32; off; off >>= 1)
    #pragma unroll
    for (int r = 0; r < 8; ++r) pr[r] += __shfl_xor(pr[r], off);
  if (lane == 0) {
    #pragma unroll
    for (int r = 0; r < 8; ++r) wacc[wq][r] = pr[r];
  }
  __syncthreads();
  if (tid < 8)
    scores[bid * 8 + tid] = wacc[0][tid] + wacc[1][tid] + wacc[2][tid] + wacc[3][tid] + ba2[0];
}

// ---------------- prefix-softmax tiled scan -> attended (bf16) ----------------
__global__ __launch_bounds__(256) void cumsum_scan_kernel(
    const float* __restrict__ scores, const float* __restrict__ histN,
    u16* __restrict__ att)
{
  __shared__ float ee[512], sa[512], sb[512], red[256];
  __shared__ float tile[64][64];
  const int tid = threadIdx.x;
  const int b = blockIdx.y, j0 = blockIdx.x * 64;

  float s0 = scores[b * Tn + tid], s1 = scores[b * Tn + tid + 256];
  red[tid] = fmaxf(s0, s1);
  __syncthreads();
  for (int s = 128; s; s >>= 1) { if (tid < s) red[tid] = fmaxf(red[tid], red[tid + s]); __syncthreads(); }
  float m = red[0];
  ee[tid] = expf(s0 - m); ee[tid + 256] = expf(s1 - m);
  sa[tid] = ee[tid]; sa[tid + 256] = ee[tid + 256];
  __syncthreads();
  float* A = sa; float* D = sb;
  for (int off = 1; off < 512; off <<= 1) {
    for (int t2 = tid; t2 < 512; t2 += 256) { float v = A[t2]; if (t2 >= off) v += A[t2 - off]; D[t2] = v; }
    __syncthreads();
    float* tmp = A; A = D; D = tmp;
  }
  float* R = D;
  for (int t2 = tid; t2 < 512; t2 += 256) R[t2] = 1.f / A[t2];
  __syncthreads();

  float ax = 0.f;
  for (int tt = 0; tt < 8; ++tt) {
    #pragma unroll
    for (int k = 0; k < 16; ++k) {
      int idx = tid + k * 256;
      int r = idx >> 6, c = idx & 63;
      tile[r][c] = histN[(size_t)(b * Tn + tt * 64 + r) * Hn + j0 + c];
    }
    __syncthreads();
    if (tid < 64) {
      for (int r = 0; r < 64; ++r) {
        int t = tt * 64 + r;
        float x = tile[r][tid];
        ax = fmaf(ee[t], x, ax);
        att[((size_t)(b * Tn + t)) * Hn + j0 + tid] = f2bf(x + ax * R[t]);
      }
    }
    __syncthreads();
  }
}

// ---------------- final GEMM ----------------
typedef short bf16x8_t __attribute__((ext_vector_type(8)));
typedef float f32x4_t  __attribute__((ext_vector_type(4)));

__global__ __launch_bounds__(256) void gemm_kernel(
    const u16* __restrict__ Aw, const u16* __restrict__ Bw,
    const float* __restrict__ bh, float* __restrict__ out)
{
  __shared__ u16 Alds[128 * 64];
  __shared__ u16 Blds[64 * 128];
  const int tid = threadIdx.x;
  const int n0 = blockIdx.x * 128, m0 = blockIdx.y * 128;
  const int w = tid >> 6, lane = tid & 63;
  const int wm = (w & 1) * 64, wn = (w >> 1) * 64;

  f32x4_t acc[4][4];
  #pragma unroll
  for (int i = 0; i < 4; ++i)
    #pragma unroll
    for (int j = 0; j < 4; ++j) acc[i][j] = (f32x4_t){0.f, 0.f, 0.f, 0.f};

  for (int kt = 0; kt < 8; ++kt) {
    const int k0 = kt * 64;
    {
      int row = tid >> 1, kc = (tid & 1) * 32;
      #pragma unroll
      for (int jj = 0; jj < 4; ++jj) {
        uint4 v = *(const uint4*)(Aw + (size_t)(m0 + row) * 512 + k0 + kc + jj * 8);
        int byte = row * 128 + (kc + jj * 8) * 2;
        byte ^= (row & 7) << 4;
        *(uint4*)((char*)Alds + byte) = v;
      }
    }
    {
      #pragma unroll
      for (int q = 0; q < 4; ++q) {
        int r = (tid >> 4) + q * 16, c8 = (tid & 15) * 8;
        uint4 v = *(const uint4*)(Bw + (size_t)(k0 + r) * NPAD + n0 + c8);
        *(uint4*)&Blds[r * 128 + c8] = v;
      }
    }
    __syncthreads();
    #pragma unroll
    for (int kh = 0; kh < 2; ++kh) {
      bf16x8_t af[4];
      #pragma unroll
      for (int i = 0; i < 4; ++i) {
        int row = wm + i * 16 + (lane & 15);
        int byte = row * 128 + kh * 64 + (lane >> 4) * 16;
        byte ^= (row & 7) << 4;
        af[i] = *(const bf16x8_t*)((const char*)Alds + byte);
      }
      const int kb = kh * 32 + (lane >> 4) * 8;
      #pragma unroll
      for (int j = 0; j < 4; ++j) {
        int col = wn + j * 16 + (lane & 15);
        bf16x8_t bf;
        #pragma unroll
        for (int jj = 0; jj < 8; ++jj) bf[jj] = (short)Blds[(kb + jj) * 128 + col];
        #pragma unroll
        for (int i = 0; i < 4; ++i)
          acc[i][j] = __builtin_amdgcn_mfma_f32_16x16x32_bf16(af[i], bf, acc[i][j], 0, 0, 0);
      }
    }
    __syncthreads();
  }
  #pragma unroll
  for (int j = 0; j < 4; ++j) {
    int col = n0 + wn + j * 16 + (lane & 15);
    if (col < Vn) {
      float bias = bh[col];
      #pragma unroll
      for (int i = 0; i < 4; ++i) {
        int rbase = m0 + wm + i * 16 + (lane >> 4) * 4;
        #pragma unroll
        for (int r = 0; r < 4; ++r)
          out[(size_t)(rbase + r) * Vn + col] = acc[i][j][r] + bias;
      }
    }
  }
}

// ---------------- host ----------------
extern "C" void kernel_launch(void* const* d_in, const int* in_sizes, int n_in,
                              void* d_out, int out_size, void* d_ws, size_t ws_size,
                              hipStream_t stream) {
  const int*   ids  = (const int*)d_in[0];
  const float* emb  = (const float*)d_in[1];
  const float* Wc1_0 = (const float*)d_in[2];  const float* bc1_0 = (const float*)d_in[3];
  const float* Wc2_0 = (const float*)d_in[4];  const float* bc2_0 = (const float*)d_in[5];
  const float* Wg1_0 = (const float*)d_in[6];  const float* bg1_0 = (const float*)d_in[7];
  const float* Wg2_0 = (const float*)d_in[8];  const float* bg2_0 = (const float*)d_in[9];
  const float* Wr_0  = (const float*)d_in[10]; const float* br_0  = (const float*)d_in[11];
  const float* Wc1_1 = (const float*)d_in[12]; const float* bc1_1 = (const float*)d_in[13];
  const float* Wc2_1 = (const float*)d_in[14]; const float* bc2_1 = (const float*)d_in[15];
  const float* Wg1_1 = (const float*)d_in[16]; const float* bg1_1 = (const float*)d_in[17];
  const float* Wg2_1 = (const float*)d_in[18]; const float* bg2_1 = (const float*)d_in[19];
  const float* Wr_1  = (const float*)d_in[20]; const float* br_1  = (const float*)d_in[21];
  const float* Wa1 = (const float*)d_in[22]; const float* ba1 = (const float*)d_in[23];
  const float* Wa2 = (const float*)d_in[24]; const float* ba2 = (const float*)d_in[25];
  const float* Wh  = (const float*)d_in[26]; const float* bh  = (const float*)d_in[27];

  float* out = (float*)d_out;
  char*  ws  = (char*)d_ws;

  const size_t OFF_FLAGA = 0;                          // 8192
  const size_t OFF_HB    = 8192;                       // 32768 (4096 u64)
  const size_t OFF_CB    = 40960;                      // 73728 (9216 u64)
  const size_t OFF_WT    = 114688;                     // 11534336
  const size_t OFF_HISTN = OFF_WT + 11534336;
  const size_t OFF_SCO   = OFF_HISTN + 4194304;
  const size_t OFF_ATT   = OFF_SCO + 8192;
  const size_t OFF_WHB   = OFF_ATT + 2097152;

  u32*   flagA  = (u32*)(ws + OFF_FLAGA);
  u64*   HB     = (u64*)(ws + OFF_HB);
  u64*   CB     = (u64*)(ws + OFF_CB);
  __half* wth   = (__half*)(ws + OFF_WT);
  float* histN  = (float*)(ws + OFF_HISTN);
  float* scores = (float*)(ws + OFF_SCO);
  u16*   att    = (u16*)(ws + OFF_ATT);
  u16*   whb    = (u16*)(ws + OFF_WHB);
  float* gates  = out + (size_t)Bn * Tn * Vn;

  __half* wtC1_0h = wth;
  __half* wtG1_0h = wth + 1310720;
  __half* wtC2_0h = wth + 1966080;
  __half* wtR_0h  = wth + 2490368;
  __half* wtC1_1h = wth + 2621440;
  __half* wtG1_1h = wth + 4194304;
  __half* wtC2_1h = wth + 4980736;
  __half* wtR_1h  = wth + 5505024;

  hipMemsetAsync(ws, 0, 114688, stream);   // flagA + HB + CB tags

  transpose_h<<<dim3(32, 40), 256, 0, stream>>>(Wc1_0, wtC1_0h, 1280, 1024);
  transpose_h<<<dim3(16, 40), 256, 0, stream>>>(Wg1_0, wtG1_0h, 1280, 512);
  transpose_h<<<dim3(16, 32), 256, 0, stream>>>(Wc2_0, wtC2_0h, 1024, 512);
  transpose_h<<<dim3(16,  8), 256, 0, stream>>>(Wr_0,  wtR_0h,   256, 512);
  transpose_h<<<dim3(32, 48), 256, 0, stream>>>(Wc1_1, wtC1_1h, 1536, 1024);
  transpose_h<<<dim3(16, 48), 256, 0, stream>>>(Wg1_1, wtG1_1h, 1536, 512);
  transpose_h<<<dim3(16, 32), 256, 0, stream>>>(Wc2_1, wtC2_1h, 1024, 512);
  transpose_h<<<dim3(16, 16), 256, 0, stream>>>(Wr_1,  wtR_1h,   512, 512);

  convwh_kernel<<<dim3(99, 512), 256, 0, stream>>>(Wh, whb);

  (void)hipFuncSetAttribute((const void*)rec_kernel,
                            hipFuncAttributeMaxDynamicSharedMemorySize, REC_LDS);

  rec_kernel<<<dim3(RG), dim3(RNT), REC_LDS, stream>>>(
      ids, emb,
      wtC1_0h, wtG1_0h, wtC2_0h, wtR_0h,
      wtC1_1h, wtG1_1h, wtC2_1h, wtR_1h,
      bc1_0, bg1_0, bc2_0, br_0, Wg2_0, bg2_0,
      bc1_1, bg1_1, bc2_1, br_1, Wg2_1, bg2_1,
      flagA, HB, CB, histN, gates);

  scores_kernel<<<dim3(256), 256, 0, stream>>>(histN, Wa1, ba1, Wa2, ba2, scores);

  cumsum_scan_kernel<<<dim3(8, Bn), 256, 0, stream>>>(scores, histN, att);

  gemm_kernel<<<dim3(393, 16), 256, 0, stream>>>(att, whb, bh, out);
}

// Round 10
// 4331.119 us; speedup vs baseline: 5.4536x; 1.0441x over previous
//
#include <hip/hip_runtime.h>
#include <hip/hip_fp16.h>
#include <cstdint>
#include <cstddef>

typedef unsigned short u16;
typedef unsigned int   u32;
typedef unsigned long long u64;

#define Bn 4
#define Tn 512
#define Hn 512
#define En 256
#define Vn 50257
#define NPAD 50304
#define RG  256
#define RNT 256

typedef _Float16 h2t __attribute__((ext_vector_type(2)));

#if defined(__has_builtin)
#if __has_builtin(__builtin_amdgcn_fdot2)
#define HAS_FDOT2 1
#endif
#endif
__device__ __forceinline__ float fdot2f(h2t a, h2t b, float c) {
#ifdef HAS_FDOT2
  return __builtin_amdgcn_fdot2(a, b, c, false);
#else
  return fmaf((float)a[0], (float)b[0], fmaf((float)a[1], (float)b[1], c));
#endif
}

__device__ __forceinline__ u16 f2bf(float f) {
  u32 x; __builtin_memcpy(&x, &f, 4);
  u32 r = (x + 0x7fffu + ((x >> 16) & 1u)) >> 16;
  return (u16)r;
}
__device__ __forceinline__ u16 f2h(float f) {
  __half hh = __float2half(f); u16 u; __builtin_memcpy(&u, &hh, 2); return u;
}
__device__ __forceinline__ u64 gldu64(const u64* p) {
  return __hip_atomic_load(p, __ATOMIC_RELAXED, __HIP_MEMORY_SCOPE_AGENT);
}
__device__ __forceinline__ void gstu64(u64* p, u64 v) {
  __hip_atomic_store(p, v, __ATOMIC_RELAXED, __HIP_MEMORY_SCOPE_AGENT);
}
__device__ __forceinline__ u32 gldu32(const u32* p) {
  return __hip_atomic_load(p, __ATOMIC_RELAXED, __HIP_MEMORY_SCOPE_AGENT);
}
__device__ __forceinline__ void gstu32(u32* p, u32 v) {
  __hip_atomic_store(p, v, __ATOMIC_RELAXED, __HIP_MEMORY_SCOPE_AGENT);
}
__device__ __forceinline__ void gstf(float* p, float v) {
  __hip_atomic_store(p, v, __ATOMIC_RELAXED, __HIP_MEMORY_SCOPE_AGENT);
}

// ---------------- prep kernels ----------------
__global__ __launch_bounds__(256) void transpose_h(
    const float* __restrict__ src, __half* __restrict__ dst, int K, int N)
{
  __shared__ float tile[32][33];
  const int tx = threadIdx.x & 31, ty = threadIdx.x >> 5;
  const int bn = blockIdx.x * 32, bk = blockIdx.y * 32;
  #pragma unroll
  for (int i = 0; i < 4; ++i)
    tile[ty + i * 8][tx] = src[(size_t)(bk + ty + i * 8) * N + bn + tx];
  __syncthreads();
  #pragma unroll
  for (int i = 0; i < 4; ++i)
    dst[(size_t)(bn + ty + i * 8) * K + bk + tx] = __float2half(tile[tx][ty + i * 8]);
}

__global__ __launch_bounds__(256) void convwh_kernel(
    const float* __restrict__ wh, u16* __restrict__ whb)
{
  const int k = blockIdx.y;
  const int v0 = (blockIdx.x * 256 + threadIdx.x) * 2;
  if (v0 >= NPAD) return;
  float a = (v0     < Vn) ? wh[(size_t)k * Vn + v0]     : 0.f;
  float b = (v0 + 1 < Vn) ? wh[(size_t)k * Vn + v0 + 1] : 0.f;
  u32 pack = (u32)f2bf(a) | ((u32)f2bf(b) << 16);
  *(u32*)&whb[(size_t)k * NPAD + v0] = pack;
}

// ---- dynamic LDS byte offsets (weights 0..98303) ----
#define HR16_B  98304    // [2 par][2 b][512] fp16 = 4096
#define HR0_B   102400   // [2 b][512] fp16 = 2048
#define EMB_B   104448   // unused (kept for layout) = 1024
#define XCAND_B 105472   // [2 b][1024] fp16 = 4096
#define GP_B    109568   // [64][2] f32 = 512
#define RLOC_B  110080   // [8][2] f32 = 64
#define SS_B    110144   // 80 f32 = 320
#define BC1L_B  110464
#define BG1L_B  110528
#define BC2L_B  110560
#define BRL_B   110592
#define WG2L_B  110624
#define BG2L_B  110656
#define STW_B   110720   // [4][4] f32 = 64
#define STW0_B  110784   // 64
#define REC_LDS 110848

// ---------------- persistent recurrence ----------------
// g: bp=g>>7, l=(g>>6)&1, gl=g&63. Raw-h fp16 broadcast, analytic LN fixup,
// sec2/sec3 precomputed before the h-rendezvous; stats folded into poll decode.
__global__ __launch_bounds__(RNT, 1) void rec_kernel(
    const int* __restrict__ ids, const float* __restrict__ emb,
    const __half* wtC1_0, const __half* wtG1_0, const __half* wtC2_0, const __half* wtR_0,
    const __half* wtC1_1, const __half* wtG1_1, const __half* wtC2_1, const __half* wtR_1,
    const float* bc1_0, const float* bg1_0, const float* bc2_0, const float* br_0,
    const float* wg2_0, const float* bg2_0,
    const float* bc1_1, const float* bg1_1, const float* bc2_1, const float* br_1,
    const float* wg2_1, const float* bg2_1,
    u32* flagA, u64* HB, u64* CB,
    float* __restrict__ histN, float* __restrict__ gates_out)
{
  extern __shared__ char smem[];
  __half* WL    = (__half*)smem;
  __half* hr16  = (__half*)(smem + HR16_B);
  __half* hr0   = (__half*)(smem + HR0_B);
  __half* xcand = (__half*)(smem + XCAND_B);
  float* gp     = (float*)(smem + GP_B);
  float* rloc   = (float*)(smem + RLOC_B);
  float* Ss     = (float*)(smem + SS_B);
  float* bc1L   = (float*)(smem + BC1L_B);
  float* bg1L   = (float*)(smem + BG1L_B);
  float* bc2L   = (float*)(smem + BC2L_B);
  float* brL    = (float*)(smem + BRL_B);
  float* wg2L   = (float*)(smem + WG2L_B);
  float* bg2L   = (float*)(smem + BG2L_B);
  float* stw    = (float*)(smem + STW_B);
  float* stw0   = (float*)(smem + STW0_B);

  const int tid = threadIdx.x, g = blockIdx.x;
  const int bp = g >> 7, l = (g >> 6) & 1, gl = g & 63;
  const int w = tid >> 6, lane = tid & 63;
  const int C = l ? 1536 : 1280;
  const int e = l ? 512 : 256;
  const int oG1 = 16 * C, oR = 24 * C, oC2 = 24 * C + 8 * e;

  const __half* wtC1 = l ? wtC1_1 : wtC1_0;
  const __half* wtG1 = l ? wtG1_1 : wtG1_0;
  const __half* wtC2 = l ? wtC2_1 : wtC2_0;
  const __half* wtR  = l ? wtR_1  : wtR_0;
  const float* bc1 = l ? bc1_1 : bc1_0;
  const float* bg1 = l ? bg1_1 : bg1_0;
  const float* bc2 = l ? bc2_1 : bc2_0;
  const float* br  = l ? br_1  : br_0;
  const float* wg2 = l ? wg2_1 : wg2_0;
  const float* bg2 = l ? bg2_1 : bg2_0;

  u64* HBown = HB + (size_t)((bp * 2 + l) * 2) * 512;
  u64* CBown = CB + (size_t)((bp * 2 + l) * 2) * 1152;
  const u64* HBl0 = HB + (size_t)((bp * 2) * 2) * 512;

  // ---- init: stage weights + zero comm LDS ----
  {
    auto cp = [&](const __half* src, int nh, int offh) {
      const u32* s = (const u32*)src; u32* d = (u32*)(WL + offh);
      for (int i = tid; i < (nh >> 1); i += RNT) d[i] = s[i];
    };
    cp(wtC1 + (size_t)(gl * 16) * C, 16 * C, 0);
    cp(wtG1 + (size_t)(gl * 8) * C,  8 * C, oG1);
    cp(wtR  + (size_t)(gl * 8) * e,  8 * e, oR);
    cp(wtC2 + (size_t)(gl * 8) * 1024, 8 * 1024, oC2);
  }
  for (int i = tid; i < 2960; i += RNT) ((u32*)(smem + HR16_B))[i] = 0;
  __syncthreads();

  if (tid < 16)      bc1L[tid] = bc1[gl * 16 + tid];
  else if (tid < 24) bg1L[tid - 16] = bg1[gl * 8 + tid - 16];
  else if (tid < 32) bc2L[tid - 24] = bc2[gl * 8 + tid - 24];
  else if (tid < 40) brL[tid - 32]  = br[gl * 8 + tid - 32];
  else if (tid < 48) wg2L[tid - 40] = wg2[gl * 8 + tid - 40];
  else if (tid == 48) bg2L[0] = bg2[0];
  for (int task = w; task < 32; task += 4) {
    const __half* colp; int K;
    if (task < 16)      { colp = WL + (size_t)task * C;              K = C; }
    else if (task < 24) { colp = WL + oG1 + (size_t)(task - 16) * C; K = C; }
    else                { colp = WL + oR  + (size_t)(task - 24) * e; K = e; }
    float s1 = 0.f, s2 = 0.f, s3 = 0.f;
    for (int k = lane; k < K; k += 64) {
      float v = __half2float(colp[k]);
      if (K == e) s1 += v;
      else if (k < 512) s1 += v;
      else if (k < 1024) s2 += v;
      else s3 += v;
    }
    #pragma unroll
    for (int off = 32; off; off >>= 1) {
      s1 += __shfl_xor(s1, off); s2 += __shfl_xor(s2, off); s3 += __shfl_xor(s3, off);
    }
    if (lane == 0) {
      if (task < 16)      { Ss[task] = s1; Ss[16 + task] = s2; Ss[32 + task] = s3; }
      else if (task < 24) { Ss[48 + task - 16] = s1; Ss[56 + task - 16] = s2; Ss[64 + task - 16] = s3; }
      else                { Ss[72 + task - 24] = s1; }
    }
  }
  __syncthreads();

  const int nEnd = l ? (Tn + 1) : (Tn - 1);
  float mp[2] = {0.f, 0.f}, ipv[2] = {0.f, 0.f};   // prev-step stats (h(t-2))

  for (int n = 0; n <= nEnd; ++n) {
    const int t = n - l;
    const bool prod = (t >= 0) && (t < Tn);
    const bool pollOwn = (t >= 1) && (t <= Tn);
    const bool pollL0  = (l == 1) && prod;
    const int parR = (n - 1) & 1;

    // ---- early loads (l0): ids + emb into per-wave registers ----
    h2t er0[2], er1[2];
    er0[0] = (h2t)0; er0[1] = (h2t)0; er1[0] = (h2t)0; er1[1] = (h2t)0;
    if (l == 0 && prod) {
      int id0 = ids[(bp * 2) * Tn + t];
      int id1 = ids[(bp * 2 + 1) * Tn + t];
      float2 fa0 = *(const float2*)(emb + (size_t)id0 * En + 2 * lane);
      float2 fb0 = *(const float2*)(emb + (size_t)id0 * En + 2 * (lane + 64));
      float2 fa1 = *(const float2*)(emb + (size_t)id1 * En + 2 * lane);
      float2 fb1 = *(const float2*)(emb + (size_t)id1 * En + 2 * (lane + 64));
      er0[0][0] = (_Float16)fa0.x; er0[0][1] = (_Float16)fa0.y;
      er0[1][0] = (_Float16)fb0.x; er0[1][1] = (_Float16)fb0.y;
      er1[0][0] = (_Float16)fa1.x; er1[0][1] = (_Float16)fa1.y;
      er1[1][0] = (_Float16)fb1.x; er1[1][1] = (_Float16)fb1.y;
    }

    // ---- PRECOMPUTE: sec2 (h2 plane) + sec3-l0 (emb regs) before the poll ----
    float comb[8][2];
    #pragma unroll
    for (int c = 0; c < 8; ++c) { comb[c][0] = 0.f; comb[c][1] = 0.f; }
    if (prod) {
      const __half* h2pl[2] = { hr16 + ((parR ^ 1) * 2) * 512,
                                hr16 + ((parR ^ 1) * 2 + 1) * 512 };
      float a[8][2];
      if (w < 3) {
        const __half* wbase = (w < 2) ? (WL + (size_t)(w * 8) * C) : (WL + oG1);
        #pragma unroll
        for (int c = 0; c < 8; ++c) { a[c][0] = 0.f; a[c][1] = 0.f; }
        #pragma unroll
        for (int it = 0; it < 4; ++it) {
          int p2 = lane + it * 64;
          h2t x0 = *(const h2t*)(h2pl[0] + 2 * p2);
          h2t x1 = *(const h2t*)(h2pl[1] + 2 * p2);
          #pragma unroll
          for (int c = 0; c < 8; ++c) {
            h2t wv = *(const h2t*)(wbase + (size_t)c * C + 512 + 2 * p2);
            a[c][0] = fdot2f(wv, x0, a[c][0]);
            a[c][1] = fdot2f(wv, x1, a[c][1]);
          }
        }
        #pragma unroll
        for (int c = 0; c < 8; ++c) { comb[c][0] += ipv[0] * a[c][0]; comb[c][1] += ipv[1] * a[c][1]; }
        if (l == 0) {
          #pragma unroll
          for (int c = 0; c < 8; ++c) { a[c][0] = 0.f; a[c][1] = 0.f; }
          #pragma unroll
          for (int it = 0; it < 2; ++it) {
            int p2 = lane + it * 64;
            #pragma unroll
            for (int c = 0; c < 8; ++c) {
              h2t wv = *(const h2t*)(wbase + (size_t)c * C + 1024 + 2 * p2);
              a[c][0] = fdot2f(wv, er0[it], a[c][0]);
              a[c][1] = fdot2f(wv, er1[it], a[c][1]);
            }
          }
          #pragma unroll
          for (int c = 0; c < 8; ++c) { comb[c][0] += a[c][0]; comb[c][1] += a[c][1]; }
        }
      } else if (l == 0) {
        #pragma unroll
        for (int c = 0; c < 8; ++c) { a[c][0] = 0.f; a[c][1] = 0.f; }
        #pragma unroll
        for (int it = 0; it < 2; ++it) {
          int p2 = lane + it * 64;
          #pragma unroll
          for (int c = 0; c < 8; ++c) {
            h2t wv = *(const h2t*)(WL + oR + (size_t)c * e + 2 * p2);
            a[c][0] = fdot2f(wv, er0[it], a[c][0]);
            a[c][1] = fdot2f(wv, er1[it], a[c][1]);
          }
        }
        #pragma unroll
        for (int c = 0; c < 8; ++c) { comb[c][0] = a[c][0]; comb[c][1] = a[c][1]; }
      }
    }

    // ---- Phase A: poll raw-h broadcast; stats folded into decode ----
    if (pollOwn || pollL0) {
      const u64* s1 = HBown + (size_t)parR * 512;
      const u64* s0 = HBl0 + (size_t)parR * 512;
      const u32 want = (u32)n;
      u64 v1[2], v0[2];
      for (;;) {
        bool ok = true;
        if (pollOwn) { v1[0] = gldu64(s1 + tid); v1[1] = gldu64(s1 + 256 + tid); }
        if (pollL0)  { v0[0] = gldu64(s0 + tid); v0[1] = gldu64(s0 + 256 + tid); }
        if (pollOwn) ok &= ((u32)(v1[0] >> 32) == want) & ((u32)(v1[1] >> 32) == want);
        if (pollL0)  ok &= ((u32)(v0[0] >> 32) == want) & ((u32)(v0[1] >> 32) == want);
        if (ok) break;
        __builtin_amdgcn_s_sleep(2);
      }
      if (pollOwn) {
        float sb0 = 0.f, sb1 = 0.f, qb0 = 0.f, qb1 = 0.f;
        #pragma unroll
        for (int i = 0; i < 2; ++i) {
          int W = i * 256 + tid;
          int glp = W >> 3, q = W & 7, cpp = q >> 1, b = q & 1;
          u32 pay = (u32)v1[i];
          ((u32*)(hr16 + (parR * 2 + b) * 512))[glp * 4 + cpp] = pay;
          __half2 hh; __builtin_memcpy(&hh, &pay, 4);
          float2 fv = __half22float2(hh);
          float sv = fv.x + fv.y, qv = fv.x * fv.x + fv.y * fv.y;
          if (b == 0) { sb0 += sv; qb0 += qv; } else { sb1 += sv; qb1 += qv; }
        }
        #pragma unroll
        for (int off = 32; off; off >>= 1) {
          sb0 += __shfl_xor(sb0, off); qb0 += __shfl_xor(qb0, off);
          sb1 += __shfl_xor(sb1, off); qb1 += __shfl_xor(qb1, off);
        }
        if (lane == 0) { stw[w * 4] = sb0; stw[w * 4 + 1] = sb1; stw[w * 4 + 2] = qb0; stw[w * 4 + 3] = qb1; }
      }
      if (pollL0) {
        float sb0 = 0.f, sb1 = 0.f, qb0 = 0.f, qb1 = 0.f;
        #pragma unroll
        for (int i = 0; i < 2; ++i) {
          int W = i * 256 + tid;
          int glp = W >> 3, q = W & 7, cpp = q >> 1, b = q & 1;
          u32 pay = (u32)v0[i];
          ((u32*)(hr0 + b * 512))[glp * 4 + cpp] = pay;
          __half2 hh; __builtin_memcpy(&hh, &pay, 4);
          float2 fv = __half22float2(hh);
          float sv = fv.x + fv.y, qv = fv.x * fv.x + fv.y * fv.y;
          if (b == 0) { sb0 += sv; qb0 += qv; } else { sb1 += sv; qb1 += qv; }
        }
        #pragma unroll
        for (int off = 32; off; off >>= 1) {
          sb0 += __shfl_xor(sb0, off); qb0 += __shfl_xor(qb0, off);
          sb1 += __shfl_xor(sb1, off); qb1 += __shfl_xor(qb1, off);
        }
        if (lane == 0) { stw0[w * 4] = sb0; stw0[w * 4 + 1] = sb1; stw0[w * 4 + 2] = qb0; stw0[w * 4 + 3] = qb1; }
      }
    }
    __syncthreads();
    if (l == 1 && tid == 0) gstu32(flagA + (bp * 64 + gl) * 16, (u32)(n + 1));

    // ---- finalize stats from wave partials ----
    float m1[2] = {0.f, 0.f}, i1v[2] = {0.f, 0.f};
    float m3[2] = {0.f, 0.f}, i3v[2] = {0.f, 0.f};
    if (pollOwn) {
      float S0 = stw[0] + stw[4] + stw[8] + stw[12];
      float S1 = stw[1] + stw[5] + stw[9] + stw[13];
      float Q0 = stw[2] + stw[6] + stw[10] + stw[14];
      float Q1 = stw[3] + stw[7] + stw[11] + stw[15];
      m1[0] = S0 * (1.f / 512.f); i1v[0] = rsqrtf(Q0 * (1.f / 512.f) - m1[0] * m1[0] + 1e-5f);
      m1[1] = S1 * (1.f / 512.f); i1v[1] = rsqrtf(Q1 * (1.f / 512.f) - m1[1] * m1[1] + 1e-5f);
    }
    if (pollL0) {
      float S0 = stw0[0] + stw0[4] + stw0[8] + stw0[12];
      float S1 = stw0[1] + stw0[5] + stw0[9] + stw0[13];
      float Q0 = stw0[2] + stw0[6] + stw0[10] + stw0[14];
      float Q1 = stw0[3] + stw0[7] + stw0[11] + stw0[15];
      m3[0] = S0 * (1.f / 512.f); i3v[0] = rsqrtf(Q0 * (1.f / 512.f) - m3[0] * m3[0] + 1e-5f);
      m3[1] = S1 * (1.f / 512.f); i3v[1] = rsqrtf(Q1 * (1.f / 512.f) - m3[1] * m3[1] + 1e-5f);
    }

    // ---- histN (l1): normalized h(t-1) ----
    if (l == 1 && pollOwn && tid < 16) {
      int c = tid >> 1, b = tid & 1, j = gl * 8 + c;
      float rv = __half2float(hr16[(parR * 2 + b) * 512 + j]);
      gstf(histN + ((size_t)((bp * 2 + b) * Tn + (t - 1))) * Hn + j, (rv - m1[b]) * i1v[b]);
    }

    // ---- post-poll matvec: sec1 (+ l1 sec3 / l1 Wr) + CB store ----
    if (prod) {
      const __half* h1pl[2] = { hr16 + (parR * 2) * 512, hr16 + (parR * 2 + 1) * 512 };
      float a[8][2];
      if (w < 3) {
        const __half* wbase = (w < 2) ? (WL + (size_t)(w * 8) * C) : (WL + oG1);
        #pragma unroll
        for (int c = 0; c < 8; ++c) { a[c][0] = 0.f; a[c][1] = 0.f; }
        #pragma unroll
        for (int it = 0; it < 4; ++it) {
          int p2 = lane + it * 64;
          h2t x0 = *(const h2t*)(h1pl[0] + 2 * p2);
          h2t x1 = *(const h2t*)(h1pl[1] + 2 * p2);
          #pragma unroll
          for (int c = 0; c < 8; ++c) {
            h2t wv = *(const h2t*)(wbase + (size_t)c * C + 2 * p2);
            a[c][0] = fdot2f(wv, x0, a[c][0]);
            a[c][1] = fdot2f(wv, x1, a[c][1]);
          }
        }
        #pragma unroll
        for (int c = 0; c < 8; ++c) { comb[c][0] += i1v[0] * a[c][0]; comb[c][1] += i1v[1] * a[c][1]; }
        if (l == 1) {
          #pragma unroll
          for (int c = 0; c < 8; ++c) { a[c][0] = 0.f; a[c][1] = 0.f; }
          #pragma unroll
          for (int it = 0; it < 4; ++it) {
            int p2 = lane + it * 64;
            h2t x0 = *(const h2t*)(hr0 + 2 * p2);
            h2t x1 = *(const h2t*)(hr0 + 512 + 2 * p2);
            #pragma unroll
            for (int c = 0; c < 8; ++c) {
              h2t wv = *(const h2t*)(wbase + (size_t)c * C + 1024 + 2 * p2);
              a[c][0] = fdot2f(wv, x0, a[c][0]);
              a[c][1] = fdot2f(wv, x1, a[c][1]);
            }
          }
          #pragma unroll
          for (int c = 0; c < 8; ++c) { comb[c][0] += i3v[0] * a[c][0]; comb[c][1] += i3v[1] * a[c][1]; }
        }
      } else if (l == 1) {
        #pragma unroll
        for (int c = 0; c < 8; ++c) { a[c][0] = 0.f; a[c][1] = 0.f; }
        #pragma unroll
        for (int it = 0; it < 4; ++it) {
          int p2 = lane + it * 64;
          h2t x0 = *(const h2t*)(hr0 + 2 * p2);
          h2t x1 = *(const h2t*)(hr0 + 512 + 2 * p2);
          #pragma unroll
          for (int c = 0; c < 8; ++c) {
            h2t wv = *(const h2t*)(WL + oR + (size_t)c * e + 2 * p2);
            a[c][0] = fdot2f(wv, x0, a[c][0]);
            a[c][1] = fdot2f(wv, x1, a[c][1]);
          }
        }
        #pragma unroll
        for (int c = 0; c < 8; ++c) { comb[c][0] = i3v[0] * a[c][0]; comb[c][1] = i3v[1] * a[c][1]; }
      }

      #pragma unroll
      for (int off = 32; off; off >>= 1)
        #pragma unroll
        for (int c = 0; c < 8; ++c) {
          comb[c][0] += __shfl_xor(comb[c][0], off);
          comb[c][1] += __shfl_xor(comb[c][1], off);
        }
      float v0s = 0.f, v1s = 0.f;
      #pragma unroll
      for (int c = 0; c < 8; ++c)
        if (lane == c) { v0s = comb[c][0]; v1s = comb[c][1]; }

      const u64 tagw = ((u64)(u32)(n + 1)) << 32;
      u64* CBw = CBown + (size_t)(n & 1) * 1152 + gl * 18;
      if (w < 2) {
        if (lane < 8) {
          int cg = w * 8 + lane;
          float k0 = i1v[0] * m1[0] * Ss[cg] + ipv[0] * mp[0] * Ss[16 + cg];
          float k1 = i1v[1] * m1[1] * Ss[cg] + ipv[1] * mp[1] * Ss[16 + cg];
          if (l) { k0 += i3v[0] * m3[0] * Ss[32 + cg]; k1 += i3v[1] * m3[1] * Ss[32 + cg]; }
          float bb = bc1L[cg];
          float c0 = fmaxf(v0s - k0 + bb, 0.f), c1 = fmaxf(v1s - k1 + bb, 0.f);
          u32 pay = (u32)f2h(c0) | ((u32)f2h(c1) << 16);
          gstu64(CBw + cg, tagw | pay);
        }
      } else if (w == 2) {
        if (lane < 8) {
          float k0 = i1v[0] * m1[0] * Ss[48 + lane] + ipv[0] * mp[0] * Ss[56 + lane];
          float k1 = i1v[1] * m1[1] * Ss[48 + lane] + ipv[1] * mp[1] * Ss[56 + lane];
          if (l) { k0 += i3v[0] * m3[0] * Ss[64 + lane]; k1 += i3v[1] * m3[1] * Ss[64 + lane]; }
          float bgv = bg1L[lane], wgv = wg2L[lane];
          float t0 = tanhf(v0s - k0 + bgv) * wgv;
          float t1 = tanhf(v1s - k1 + bgv) * wgv;
          #pragma unroll
          for (int off = 1; off < 8; off <<= 1) { t0 += __shfl_xor(t0, off); t1 += __shfl_xor(t1, off); }
          if (lane == 0) {
            u32 b0, b1; __builtin_memcpy(&b0, &t0, 4); __builtin_memcpy(&b1, &t1, 4);
            gstu64(CBw + 16, tagw | b0);
            gstu64(CBw + 17, tagw | b1);
          }
        }
      } else {
        if (lane < 8) {
          float k0 = l ? i3v[0] * m3[0] * Ss[72 + lane] : 0.f;
          float k1 = l ? i3v[1] * m3[1] * Ss[72 + lane] : 0.f;
          rloc[lane * 2]     = v0s - k0 + brL[lane];
          rloc[lane * 2 + 1] = v1s - k1 + brL[lane];
        }
      }
    }

    // ---- Phase B: poll cand1-broadcast + l0 backpressure ----
    if (prod) {
      const u64* CBL = CBown + (size_t)(n & 1) * 1152;
      const u32 want = (u32)(n + 1);
      const bool needF = (l == 0) && (tid < 64);
      const u32* fptr = flagA + (bp * 64 + tid) * 16;
      u64 cv[5];
      const bool last = (tid < 128);
      for (;;) {
        bool ok = true;
        #pragma unroll
        for (int i = 0; i < 4; ++i) cv[i] = gldu64(CBL + i * 256 + tid);
        if (last) cv[4] = gldu64(CBL + 1024 + tid);
        #pragma unroll
        for (int i = 0; i < 4; ++i) ok &= ((u32)(cv[i] >> 32) == want);
        if (last) ok &= ((u32)(cv[4] >> 32) == want);
        if (needF) ok &= (gldu32(fptr) >= (u32)n);
        if (ok) break;
        __builtin_amdgcn_s_sleep(2);
      }
      u16* xc16 = (u16*)xcand;
      #pragma unroll
      for (int i = 0; i < 5; ++i) {
        if (i == 4 && !last) break;
        int idx = i * 256 + tid;
        int p = (int)(((u32)idx * 3641u) >> 16);
        int w2 = idx - p * 18;
        u32 pay = (u32)cv[i];
        if (w2 < 16) {
          int j = p * 16 + w2;
          xc16[j]        = (u16)(pay & 0xffffu);
          xc16[1024 + j] = (u16)(pay >> 16);
        } else {
          float f; __builtin_memcpy(&f, &pay, 4);
          gp[p * 2 + (w2 - 16)] = f;
        }
      }
    }
    __syncthreads();

    // ---- gate (redundant/wave) + matvec2 + finalize + HB store ----
    if (prod) {
      float gs0 = gp[lane * 2], gs1 = gp[lane * 2 + 1];
      #pragma unroll
      for (int off = 32; off; off >>= 1) { gs0 += __shfl_xor(gs0, off); gs1 += __shfl_xor(gs1, off); }
      float gate[2];
      gate[0] = 1.f / (1.f + expf(-(gs0 + bg2L[0])));
      gate[1] = 1.f / (1.f + expf(-(gs1 + bg2L[0])));

      float a2[2][2];
      a2[0][0] = a2[0][1] = a2[1][0] = a2[1][1] = 0.f;
      const __half* wb2 = WL + oC2 + (w * 2) * 1024;
      #pragma unroll
      for (int it = 0; it < 8; ++it) {
        int p2 = lane + it * 64;
        h2t xv0 = *(const h2t*)(xcand + 2 * p2);
        h2t xv1 = *(const h2t*)(xcand + 1024 + 2 * p2);
        #pragma unroll
        for (int cc = 0; cc < 2; ++cc) {
          h2t wv = *(const h2t*)(wb2 + cc * 1024 + 2 * p2);
          a2[cc][0] = fdot2f(wv, xv0, a2[cc][0]);
          a2[cc][1] = fdot2f(wv, xv1, a2[cc][1]);
        }
      }
      #pragma unroll
      for (int off = 32; off; off >>= 1)
        #pragma unroll
        for (int cc = 0; cc < 2; ++cc) {
          a2[cc][0] += __shfl_xor(a2[cc][0], off);
          a2[cc][1] += __shfl_xor(a2[cc][1], off);
        }
      float sel = 0.f;
      #pragma unroll
      for (int cc = 0; cc < 2; ++cc)
        #pragma unroll
        for (int b = 0; b < 2; ++b)
          if (lane == cc * 2 + b) sel = a2[cc][b];
      int cc = (lane >> 1) & 1, b = lane & 1, cl = w * 2 + cc;
      float rv = __half2float(hr16[(parR * 2 + b) * 512 + gl * 8 + cl]);
      float h1n = (rv - m1[b]) * i1v[b];
      float hv = h1n + gate[b] * (sel + bc2L[cl]) + 0.1f * rloc[cl * 2 + b];
      float hv0 = __shfl(hv, 0), hv1 = __shfl(hv, 1);
      float hv2 = __shfl(hv, 2), hv3 = __shfl(hv, 3);
      if (lane < 2) {
        u32 pay = (lane == 0) ? ((u32)f2h(hv0) | ((u32)f2h(hv2) << 16))
                              : ((u32)f2h(hv1) | ((u32)f2h(hv3) << 16));
        u64* HBw = HBown + (size_t)(n & 1) * 512 + gl * 8;
        gstu64(HBw + w * 2 + lane, (((u64)(u32)(n + 1)) << 32) | pay);
      }
      if (l == 1 && gl == 0 && w == 0 && lane == 0) {
        gstf(gates_out + (bp * 2) * Tn + t, gate[0]);
        gstf(gates_out + (bp * 2 + 1) * Tn + t, gate[1]);
      }
    }

    if (pollOwn) { mp[0] = m1[0]; mp[1] = m1[1]; ipv[0] = i1v[0]; ipv[1] = i1v[1]; }
  }
}

// ---------------- attention scores ----------------
__global__ __launch_bounds__(256) void scores_kernel(
    const float* __restrict__ histN,
    const float* __restrict__ wa1, const float* __restrict__ ba1,
    const float* __restrict__ wa2, const float* __restrict__ ba2,
    float* __restrict__ scores)
{
  __shared__ float xs[8][512];
  __shared__ float wacc[4][8];
  const int tid = threadIdx.x, bid = blockIdx.x;

  for (int idx = tid; idx < 4096; idx += 256)
    xs[idx >> 9][idx & 511] = histN[(size_t)(bid * 8) * Hn + idx];
  __syncthreads();

  float pr[8] = {0.f,0.f,0.f,0.f,0.f,0.f,0.f,0.f};
  #pragma unroll
  for (int cc = 0; cc < 2; ++cc) {
    int c = tid + cc * 256;
    float a[8] = {0.f,0.f,0.f,0.f,0.f,0.f,0.f,0.f};
    for (int k = 0; k < 512; ++k) {
      float wv = wa1[(size_t)k * 512 + c];
      #pragma unroll
      for (int r = 0; r < 8; ++r) a[r] = fmaf(xs[r][k], wv, a[r]);
    }
    float b1 = ba1[c], w2 = wa2[c];
    #pragma unroll
    for (int r = 0; r < 8; ++r) pr[r] += tanhf(a[r] + b1) * w2;
  }
  int lane = tid & 63, wq = tid >> 6;
  #pragma unroll
  for (int off = 32; off; off >>= 1)
    #pragma unroll
    for (int r = 0; r < 8; ++r) pr[r] += __shfl_xor(pr[r], off);
  if (lane == 0) {
    #pragma unroll
    for (int r = 0; r < 8; ++r) wacc[wq][r] = pr[r];
  }
  __syncthreads();
  if (tid < 8)
    scores[bid * 8 + tid] = wacc[0][tid] + wacc[1][tid] + wacc[2][tid] + wacc[3][tid] + ba2[0];
}

// ---------------- prefix-softmax tiled scan -> attended (bf16) ----------------
__global__ __launch_bounds__(256) void cumsum_scan_kernel(
    const float* __restrict__ scores, const float* __restrict__ histN,
    u16* __restrict__ att)
{
  __shared__ float ee[512], sa[512], sb[512], red[256];
  __shared__ float tile[64][64];
  const int tid = threadIdx.x;
  const int b = blockIdx.y, j0 = blockIdx.x * 64;

  float s0 = scores[b * Tn + tid], s1 = scores[b * Tn + tid + 256];
  red[tid] = fmaxf(s0, s1);
  __syncthreads();
  for (int s = 128; s; s >>= 1) { if (tid < s) red[tid] = fmaxf(red[tid], red[tid + s]); __syncthreads(); }
  float m = red[0];
  ee[tid] = expf(s0 - m); ee[tid + 256] = expf(s1 - m);
  sa[tid] = ee[tid]; sa[tid + 256] = ee[tid + 256];
  __syncthreads();
  float* A = sa; float* D = sb;
  for (int off = 1; off < 512; off <<= 1) {
    for (int t2 = tid; t2 < 512; t2 += 256) { float v = A[t2]; if (t2 >= off) v += A[t2 - off]; D[t2] = v; }
    __syncthreads();
    float* tmp = A; A = D; D = tmp;
  }
  float* R = D;
  for (int t2 = tid; t2 < 512; t2 += 256) R[t2] = 1.f / A[t2];
  __syncthreads();

  float ax = 0.f;
  for (int tt = 0; tt < 8; ++tt) {
    #pragma unroll
    for (int k = 0; k < 16; ++k) {
      int idx = tid + k * 256;
      int r = idx >> 6, c = idx & 63;
      tile[r][c] = histN[(size_t)(b * Tn + tt * 64 + r) * Hn + j0 + c];
    }
    __syncthreads();
    if (tid < 64) {
      for (int r = 0; r < 64; ++r) {
        int t = tt * 64 + r;
        float x = tile[r][tid];
        ax = fmaf(ee[t], x, ax);
        att[((size_t)(b * Tn + t)) * Hn + j0 + tid] = f2bf(x + ax * R[t]);
      }
    }
    __syncthreads();
  }
}

// ---------------- final GEMM ----------------
typedef short bf16x8_t __attribute__((ext_vector_type(8)));
typedef float f32x4_t  __attribute__((ext_vector_type(4)));

__global__ __launch_bounds__(256) void gemm_kernel(
    const u16* __restrict__ Aw, const u16* __restrict__ Bw,
    const float* __restrict__ bh, float* __restrict__ out)
{
  __shared__ u16 Alds[128 * 64];
  __shared__ u16 Blds[64 * 128];
  const int tid = threadIdx.x;
  const int n0 = blockIdx.x * 128, m0 = blockIdx.y * 128;
  const int w = tid >> 6, lane = tid & 63;
  const int wm = (w & 1) * 64, wn = (w >> 1) * 64;

  f32x4_t acc[4][4];
  #pragma unroll
  for (int i = 0; i < 4; ++i)
    #pragma unroll
    for (int j = 0; j < 4; ++j) acc[i][j] = (f32x4_t){0.f, 0.f, 0.f, 0.f};

  for (int kt = 0; kt < 8; ++kt) {
    const int k0 = kt * 64;
    {
      int row = tid >> 1, kc = (tid & 1) * 32;
      #pragma unroll
      for (int jj = 0; jj < 4; ++jj) {
        uint4 v = *(const uint4*)(Aw + (size_t)(m0 + row) * 512 + k0 + kc + jj * 8);
        int byte = row * 128 + (kc + jj * 8) * 2;
        byte ^= (row & 7) << 4;
        *(uint4*)((char*)Alds + byte) = v;
      }
    }
    {
      #pragma unroll
      for (int q = 0; q < 4; ++q) {
        int r = (tid >> 4) + q * 16, c8 = (tid & 15) * 8;
        uint4 v = *(const uint4*)(Bw + (size_t)(k0 + r) * NPAD + n0 + c8);
        *(uint4*)&Blds[r * 128 + c8] = v;
      }
    }
    __syncthreads();
    #pragma unroll
    for (int kh = 0; kh < 2; ++kh) {
      bf16x8_t af[4];
      #pragma unroll
      for (int i = 0; i < 4; ++i) {
        int row = wm + i * 16 + (lane & 15);
        int byte = row * 128 + kh * 64 + (lane >> 4) * 16;
        byte ^= (row & 7) << 4;
        af[i] = *(const bf16x8_t*)((const char*)Alds + byte);
      }
      const int kb = kh * 32 + (lane >> 4) * 8;
      #pragma unroll
      for (int j = 0; j < 4; ++j) {
        int col = wn + j * 16 + (lane & 15);
        bf16x8_t bf;
        #pragma unroll
        for (int jj = 0; jj < 8; ++jj) bf[jj] = (short)Blds[(kb + jj) * 128 + col];
        #pragma unroll
        for (int i = 0; i < 4; ++i)
          acc[i][j] = __builtin_amdgcn_mfma_f32_16x16x32_bf16(af[i], bf, acc[i][j], 0, 0, 0);
      }
    }
    __syncthreads();
  }
  #pragma unroll
  for (int j = 0; j < 4; ++j) {
    int col = n0 + wn + j * 16 + (lane & 15);
    if (col < Vn) {
      float bias = bh[col];
      #pragma unroll
      for (int i = 0; i < 4; ++i) {
        int rbase = m0 + wm + i * 16 + (lane >> 4) * 4;
        #pragma unroll
        for (int r = 0; r < 4; ++r)
          out[(size_t)(rbase + r) * Vn + col] = acc[i][j][r] + bias;
      }
    }
  }
}

// ---------------- host ----------------
extern "C" void kernel_launch(void* const* d_in, const int* in_sizes, int n_in,
                              void* d_out, int out_size, void* d_ws, size_t ws_size,
                              hipStream_t stream) {
  const int*   ids  = (const int*)d_in[0];
  const float* emb  = (const float*)d_in[1];
  const float* Wc1_0 = (const float*)d_in[2];  const float* bc1_0 = (const float*)d_in[3];
  const float* Wc2_0 = (const float*)d_in[4];  const float* bc2_0 = (const float*)d_in[5];
  const float* Wg1_0 = (const float*)d_in[6];  const float* bg1_0 = (const float*)d_in[7];
  const float* Wg2_0 = (const float*)d_in[8];  const float* bg2_0 = (const float*)d_in[9];
  const float* Wr_0  = (const float*)d_in[10]; const float* br_0  = (const float*)d_in[11];
  const float* Wc1_1 = (const float*)d_in[12]; const float* bc1_1 = (const float*)d_in[13];
  const float* Wc2_1 = (const float*)d_in[14]; const float* bc2_1 = (const float*)d_in[15];
  const float* Wg1_1 = (const float*)d_in[16]; const float* bg1_1 = (const float*)d_in[17];
  const float* Wg2_1 = (const float*)d_in[18]; const float* bg2_1 = (const float*)d_in[19];
  const float* Wr_1  = (const float*)d_in[20]; const float* br_1  = (const float*)d_in[21];
  const float* Wa1 = (const float*)d_in[22]; const float* ba1 = (const float*)d_in[23];
  const float* Wa2 = (const float*)d_in[24]; const float* ba2 = (const float*)d_in[25];
  const float* Wh  = (const float*)d_in[26]; const float* bh  = (const float*)d_in[27];

  float* out = (float*)d_out;
  char*  ws  = (char*)d_ws;

  const size_t OFF_FLAGA = 0;                          // 8192
  const size_t OFF_HB    = 8192;                       // 32768 (4096 u64)
  const size_t OFF_CB    = 40960;                      // 73728 (9216 u64)
  const size_t OFF_WT    = 114688;                     // 11534336
  const size_t OFF_HISTN = OFF_WT + 11534336;
  const size_t OFF_SCO   = OFF_HISTN + 4194304;
  const size_t OFF_ATT   = OFF_SCO + 8192;
  const size_t OFF_WHB   = OFF_ATT + 2097152;

  u32*   flagA  = (u32*)(ws + OFF_FLAGA);
  u64*   HB     = (u64*)(ws + OFF_HB);
  u64*   CB     = (u64*)(ws + OFF_CB);
  __half* wth   = (__half*)(ws + OFF_WT);
  float* histN  = (float*)(ws + OFF_HISTN);
  float* scores = (float*)(ws + OFF_SCO);
  u16*   att    = (u16*)(ws + OFF_ATT);
  u16*   whb    = (u16*)(ws + OFF_WHB);
  float* gates  = out + (size_t)Bn * Tn * Vn;

  __half* wtC1_0h = wth;
  __half* wtG1_0h = wth + 1310720;
  __half* wtC2_0h = wth + 1966080;
  __half* wtR_0h  = wth + 2490368;
  __half* wtC1_1h = wth + 2621440;
  __half* wtG1_1h = wth + 4194304;
  __half* wtC2_1h = wth + 4980736;
  __half* wtR_1h  = wth + 5505024;

  hipMemsetAsync(ws, 0, 114688, stream);   // flagA + HB + CB tags

  transpose_h<<<dim3(32, 40), 256, 0, stream>>>(Wc1_0, wtC1_0h, 1280, 1024);
  transpose_h<<<dim3(16, 40), 256, 0, stream>>>(Wg1_0, wtG1_0h, 1280, 512);
  transpose_h<<<dim3(16, 32), 256, 0, stream>>>(Wc2_0, wtC2_0h, 1024, 512);
  transpose_h<<<dim3(16,  8), 256, 0, stream>>>(Wr_0,  wtR_0h,   256, 512);
  transpose_h<<<dim3(32, 48), 256, 0, stream>>>(Wc1_1, wtC1_1h, 1536, 1024);
  transpose_h<<<dim3(16, 48), 256, 0, stream>>>(Wg1_1, wtG1_1h, 1536, 512);
  transpose_h<<<dim3(16, 32), 256, 0, stream>>>(Wc2_1, wtC2_1h, 1024, 512);
  transpose_h<<<dim3(16, 16), 256, 0, stream>>>(Wr_1,  wtR_1h,   512, 512);

  convwh_kernel<<<dim3(99, 512), 256, 0, stream>>>(Wh, whb);

  (void)hipFuncSetAttribute((const void*)rec_kernel,
                            hipFuncAttributeMaxDynamicSharedMemorySize, REC_LDS);

  rec_kernel<<<dim3(RG), dim3(RNT), REC_LDS, stream>>>(
      ids, emb,
      wtC1_0h, wtG1_0h, wtC2_0h, wtR_0h,
      wtC1_1h, wtG1_1h, wtC2_1h, wtR_1h,
      bc1_0, bg1_0, bc2_0, br_0, Wg2_0, bg2_0,
      bc1_1, bg1_1, bc2_1, br_1, Wg2_1, bg2_1,
      flagA, HB, CB, histN, gates);

  scores_kernel<<<dim3(256), 256, 0, stream>>>(histN, Wa1, ba1, Wa2, ba2, scores);

  cumsum_scan_kernel<<<dim3(8, Bn), 256, 0, stream>>>(scores, histN, att);

  gemm_kernel<<<dim3(393, 16), 256, 0, stream>>>(att, whb, bh, out);
}

// Round 11
// 4227.053 us; speedup vs baseline: 5.5879x; 1.0246x over previous
//
#include <hip/hip_runtime.h>
#include <hip/hip_fp16.h>
#include <cstdint>
#include <cstddef>

typedef unsigned short u16;
typedef unsigned int   u32;
typedef unsigned long long u64;

#define Bn 4
#define Tn 512
#define Hn 512
#define En 256
#define Vn 50257
#define NPAD 50304
#define RG  256
#define RNT 256

typedef _Float16 h2t __attribute__((ext_vector_type(2)));

#if defined(__has_builtin)
#if __has_builtin(__builtin_amdgcn_fdot2)
#define HAS_FDOT2 1
#endif
#endif
__device__ __forceinline__ float fdot2f(h2t a, h2t b, float c) {
#ifdef HAS_FDOT2
  return __builtin_amdgcn_fdot2(a, b, c, false);
#else
  return fmaf((float)a[0], (float)b[0], fmaf((float)a[1], (float)b[1], c));
#endif
}

__device__ __forceinline__ u16 f2bf(float f) {
  u32 x; __builtin_memcpy(&x, &f, 4);
  u32 r = (x + 0x7fffu + ((x >> 16) & 1u)) >> 16;
  return (u16)r;
}
__device__ __forceinline__ u16 f2h(float f) {
  __half hh = __float2half(f); u16 u; __builtin_memcpy(&u, &hh, 2); return u;
}
__device__ __forceinline__ u64 gldu64(const u64* p) {
  return __hip_atomic_load(p, __ATOMIC_RELAXED, __HIP_MEMORY_SCOPE_AGENT);
}
__device__ __forceinline__ void gstu64(u64* p, u64 v) {
  __hip_atomic_store(p, v, __ATOMIC_RELAXED, __HIP_MEMORY_SCOPE_AGENT);
}
__device__ __forceinline__ u32 gldu32(const u32* p) {
  return __hip_atomic_load(p, __ATOMIC_RELAXED, __HIP_MEMORY_SCOPE_AGENT);
}
__device__ __forceinline__ void gstu32(u32* p, u32 v) {
  __hip_atomic_store(p, v, __ATOMIC_RELAXED, __HIP_MEMORY_SCOPE_AGENT);
}
__device__ __forceinline__ void gstf(float* p, float v) {
  __hip_atomic_store(p, v, __ATOMIC_RELAXED, __HIP_MEMORY_SCOPE_AGENT);
}

// ---------------- prep kernels ----------------
__global__ __launch_bounds__(256) void transpose_h(
    const float* __restrict__ src, __half* __restrict__ dst, int K, int N)
{
  __shared__ float tile[32][33];
  const int tx = threadIdx.x & 31, ty = threadIdx.x >> 5;
  const int bn = blockIdx.x * 32, bk = blockIdx.y * 32;
  #pragma unroll
  for (int i = 0; i < 4; ++i)
    tile[ty + i * 8][tx] = src[(size_t)(bk + ty + i * 8) * N + bn + tx];
  __syncthreads();
  #pragma unroll
  for (int i = 0; i < 4; ++i)
    dst[(size_t)(bn + ty + i * 8) * K + bk + tx] = __float2half(tile[tx][ty + i * 8]);
}

__global__ __launch_bounds__(256) void convwh_kernel(
    const float* __restrict__ wh, u16* __restrict__ whb)
{
  const int k = blockIdx.y;
  const int v0 = (blockIdx.x * 256 + threadIdx.x) * 2;
  if (v0 >= NPAD) return;
  float a = (v0     < Vn) ? wh[(size_t)k * Vn + v0]     : 0.f;
  float b = (v0 + 1 < Vn) ? wh[(size_t)k * Vn + v0 + 1] : 0.f;
  u32 pack = (u32)f2bf(a) | ((u32)f2bf(b) << 16);
  *(u32*)&whb[(size_t)k * NPAD + v0] = pack;
}

// ---- dynamic LDS byte offsets (weights 0..98303) ----
#define HR16_B  98304    // [2 par][2 b][512] fp16 = 4096
#define HR0_B   102400   // [2 b][512] fp16 = 2048
#define EMB_B   104448   // unused = 1024
#define XCAND_B 105472   // [2 b][1024] fp16 = 4096
#define GP_B    109568   // [64][2] f32 = 512
#define RLOC_B  110080   // [8][2] f32 = 64
#define SS_B    110144   // 80 f32 = 320
#define BC1L_B  110464
#define BG1L_B  110528
#define BC2L_B  110560
#define BRL_B   110592
#define WG2L_B  110624
#define BG2L_B  110656
#define STW_B   110720   // [4][4] f32 = 64
#define STW0_B  110784   // 64
#define REC_LDS 110848

// ---------------- persistent recurrence ----------------
// g: bp=g>>7, l=(g>>6)&1, gl=g&63. Raw-h fp16 broadcast, analytic LN fixup.
// l1's hr0 pipeline (poll/stats/sec3/Wr) is fully pre-critical-path (hr0 is a tick old).
__global__ __launch_bounds__(RNT, 1) void rec_kernel(
    const int* __restrict__ ids, const float* __restrict__ emb,
    const __half* wtC1_0, const __half* wtG1_0, const __half* wtC2_0, const __half* wtR_0,
    const __half* wtC1_1, const __half* wtG1_1, const __half* wtC2_1, const __half* wtR_1,
    const float* bc1_0, const float* bg1_0, const float* bc2_0, const float* br_0,
    const float* wg2_0, const float* bg2_0,
    const float* bc1_1, const float* bg1_1, const float* bc2_1, const float* br_1,
    const float* wg2_1, const float* bg2_1,
    u32* flagA, u64* HB, u64* CB,
    float* __restrict__ histN, float* __restrict__ gates_out)
{
  extern __shared__ char smem[];
  __half* WL    = (__half*)smem;
  __half* hr16  = (__half*)(smem + HR16_B);
  __half* hr0   = (__half*)(smem + HR0_B);
  __half* xcand = (__half*)(smem + XCAND_B);
  float* gp     = (float*)(smem + GP_B);
  float* rloc   = (float*)(smem + RLOC_B);
  float* Ss     = (float*)(smem + SS_B);
  float* bc1L   = (float*)(smem + BC1L_B);
  float* bg1L   = (float*)(smem + BG1L_B);
  float* bc2L   = (float*)(smem + BC2L_B);
  float* brL    = (float*)(smem + BRL_B);
  float* wg2L   = (float*)(smem + WG2L_B);
  float* bg2L   = (float*)(smem + BG2L_B);
  float* stw    = (float*)(smem + STW_B);
  float* stw0   = (float*)(smem + STW0_B);

  const int tid = threadIdx.x, g = blockIdx.x;
  const int bp = g >> 7, l = (g >> 6) & 1, gl = g & 63;
  const int w = tid >> 6, lane = tid & 63;
  const int C = l ? 1536 : 1280;
  const int e = l ? 512 : 256;
  const int oG1 = 16 * C, oR = 24 * C, oC2 = 24 * C + 8 * e;

  const __half* wtC1 = l ? wtC1_1 : wtC1_0;
  const __half* wtG1 = l ? wtG1_1 : wtG1_0;
  const __half* wtC2 = l ? wtC2_1 : wtC2_0;
  const __half* wtR  = l ? wtR_1  : wtR_0;
  const float* bc1 = l ? bc1_1 : bc1_0;
  const float* bg1 = l ? bg1_1 : bg1_0;
  const float* bc2 = l ? bc2_1 : bc2_0;
  const float* br  = l ? br_1  : br_0;
  const float* wg2 = l ? wg2_1 : wg2_0;
  const float* bg2 = l ? bg2_1 : bg2_0;

  u64* HBown = HB + (size_t)((bp * 2 + l) * 2) * 512;
  u64* CBown = CB + (size_t)((bp * 2 + l) * 2) * 1152;
  const u64* HBl0 = HB + (size_t)((bp * 2) * 2) * 512;

  // ---- init: stage weights + zero comm LDS ----
  {
    auto cp = [&](const __half* src, int nh, int offh) {
      const u32* s = (const u32*)src; u32* d = (u32*)(WL + offh);
      for (int i = tid; i < (nh >> 1); i += RNT) d[i] = s[i];
    };
    cp(wtC1 + (size_t)(gl * 16) * C, 16 * C, 0);
    cp(wtG1 + (size_t)(gl * 8) * C,  8 * C, oG1);
    cp(wtR  + (size_t)(gl * 8) * e,  8 * e, oR);
    cp(wtC2 + (size_t)(gl * 8) * 1024, 8 * 1024, oC2);
  }
  for (int i = tid; i < 2960; i += RNT) ((u32*)(smem + HR16_B))[i] = 0;
  __syncthreads();

  if (tid < 16)      bc1L[tid] = bc1[gl * 16 + tid];
  else if (tid < 24) bg1L[tid - 16] = bg1[gl * 8 + tid - 16];
  else if (tid < 32) bc2L[tid - 24] = bc2[gl * 8 + tid - 24];
  else if (tid < 40) brL[tid - 32]  = br[gl * 8 + tid - 32];
  else if (tid < 48) wg2L[tid - 40] = wg2[gl * 8 + tid - 40];
  else if (tid == 48) bg2L[0] = bg2[0];
  for (int task = w; task < 32; task += 4) {
    const __half* colp; int K;
    if (task < 16)      { colp = WL + (size_t)task * C;              K = C; }
    else if (task < 24) { colp = WL + oG1 + (size_t)(task - 16) * C; K = C; }
    else                { colp = WL + oR  + (size_t)(task - 24) * e; K = e; }
    float s1 = 0.f, s2 = 0.f, s3 = 0.f;
    for (int k = lane; k < K; k += 64) {
      float v = __half2float(colp[k]);
      if (K == e) s1 += v;
      else if (k < 512) s1 += v;
      else if (k < 1024) s2 += v;
      else s3 += v;
    }
    #pragma unroll
    for (int off = 32; off; off >>= 1) {
      s1 += __shfl_xor(s1, off); s2 += __shfl_xor(s2, off); s3 += __shfl_xor(s3, off);
    }
    if (lane == 0) {
      if (task < 16)      { Ss[task] = s1; Ss[16 + task] = s2; Ss[32 + task] = s3; }
      else if (task < 24) { Ss[48 + task - 16] = s1; Ss[56 + task - 16] = s2; Ss[64 + task - 16] = s3; }
      else                { Ss[72 + task - 24] = s1; }
    }
  }
  __syncthreads();

  const int nEnd = l ? (Tn + 1) : (Tn - 1);
  float mp[2] = {0.f, 0.f}, ipv[2] = {0.f, 0.f};   // prev-step stats (h(t-2))

  for (int n = 0; n <= nEnd; ++n) {
    const int t = n - l;
    const bool prod = (t >= 0) && (t < Tn);
    const bool pollOwn = (t >= 1) && (t <= Tn);
    const bool pollL0  = (l == 1) && prod;
    const int parR = (n - 1) & 1;

    // ---- early loads (l0): ids + emb into per-wave registers ----
    h2t er0[2], er1[2];
    er0[0] = (h2t)0; er0[1] = (h2t)0; er1[0] = (h2t)0; er1[1] = (h2t)0;
    if (l == 0 && prod) {
      int id0 = ids[(bp * 2) * Tn + t];
      int id1 = ids[(bp * 2 + 1) * Tn + t];
      float2 fa0 = *(const float2*)(emb + (size_t)id0 * En + 2 * lane);
      float2 fb0 = *(const float2*)(emb + (size_t)id0 * En + 2 * (lane + 64));
      float2 fa1 = *(const float2*)(emb + (size_t)id1 * En + 2 * lane);
      float2 fb1 = *(const float2*)(emb + (size_t)id1 * En + 2 * (lane + 64));
      er0[0][0] = (_Float16)fa0.x; er0[0][1] = (_Float16)fa0.y;
      er0[1][0] = (_Float16)fb0.x; er0[1][1] = (_Float16)fb0.y;
      er1[0][0] = (_Float16)fa1.x; er1[0][1] = (_Float16)fa1.y;
      er1[1][0] = (_Float16)fb1.x; er1[1][1] = (_Float16)fb1.y;
    }

    // ---- PRECOMPUTE: sec2 (h2 plane) + sec3-l0 (emb regs) before any poll ----
    float comb[8][2];
    #pragma unroll
    for (int c = 0; c < 8; ++c) { comb[c][0] = 0.f; comb[c][1] = 0.f; }
    if (prod) {
      const __half* h2pl[2] = { hr16 + ((parR ^ 1) * 2) * 512,
                                hr16 + ((parR ^ 1) * 2 + 1) * 512 };
      float a[8][2];
      if (w < 3) {
        const __half* wbase = (w < 2) ? (WL + (size_t)(w * 8) * C) : (WL + oG1);
        #pragma unroll
        for (int c = 0; c < 8; ++c) { a[c][0] = 0.f; a[c][1] = 0.f; }
        #pragma unroll
        for (int it = 0; it < 4; ++it) {
          int p2 = lane + it * 64;
          h2t x0 = *(const h2t*)(h2pl[0] + 2 * p2);
          h2t x1 = *(const h2t*)(h2pl[1] + 2 * p2);
          #pragma unroll
          for (int c = 0; c < 8; ++c) {
            h2t wv = *(const h2t*)(wbase + (size_t)c * C + 512 + 2 * p2);
            a[c][0] = fdot2f(wv, x0, a[c][0]);
            a[c][1] = fdot2f(wv, x1, a[c][1]);
          }
        }
        #pragma unroll
        for (int c = 0; c < 8; ++c) { comb[c][0] += ipv[0] * a[c][0]; comb[c][1] += ipv[1] * a[c][1]; }
        if (l == 0) {
          #pragma unroll
          for (int c = 0; c < 8; ++c) { a[c][0] = 0.f; a[c][1] = 0.f; }
          #pragma unroll
          for (int it = 0; it < 2; ++it) {
            int p2 = lane + it * 64;
            #pragma unroll
            for (int c = 0; c < 8; ++c) {
              h2t wv = *(const h2t*)(wbase + (size_t)c * C + 1024 + 2 * p2);
              a[c][0] = fdot2f(wv, er0[it], a[c][0]);
              a[c][1] = fdot2f(wv, er1[it], a[c][1]);
            }
          }
          #pragma unroll
          for (int c = 0; c < 8; ++c) { comb[c][0] += a[c][0]; comb[c][1] += a[c][1]; }
        }
      } else if (l == 0) {
        #pragma unroll
        for (int c = 0; c < 8; ++c) { a[c][0] = 0.f; a[c][1] = 0.f; }
        #pragma unroll
        for (int it = 0; it < 2; ++it) {
          int p2 = lane + it * 64;
          #pragma unroll
          for (int c = 0; c < 8; ++c) {
            h2t wv = *(const h2t*)(WL + oR + (size_t)c * e + 2 * p2);
            a[c][0] = fdot2f(wv, er0[it], a[c][0]);
            a[c][1] = fdot2f(wv, er1[it], a[c][1]);
          }
        }
        #pragma unroll
        for (int c = 0; c < 8; ++c) { comb[c][0] += a[c][0]; comb[c][1] += a[c][1]; }
      }
    }

    // ---- l1 pre-poll hr0 pipeline (hr0 published a tick ago: off critical path) ----
    float m3[2] = {0.f, 0.f}, i3v[2] = {0.f, 0.f};
    if (l == 1) {
      if (pollL0) {
        const u64* s0 = HBl0 + (size_t)parR * 512;
        const u32 want = (u32)n;
        u64 v0[2];
        for (;;) {
          v0[0] = gldu64(s0 + tid); v0[1] = gldu64(s0 + 256 + tid);
          if (((u32)(v0[0] >> 32) == want) & ((u32)(v0[1] >> 32) == want)) break;
          __builtin_amdgcn_s_sleep(2);
        }
        float sb0 = 0.f, sb1 = 0.f, qb0 = 0.f, qb1 = 0.f;
        #pragma unroll
        for (int i = 0; i < 2; ++i) {
          int W = i * 256 + tid;
          int glp = W >> 3, q = W & 7, cpp = q >> 1, b = q & 1;
          u32 pay = (u32)v0[i];
          ((u32*)(hr0 + b * 512))[glp * 4 + cpp] = pay;
          __half2 hh; __builtin_memcpy(&hh, &pay, 4);
          float2 fv = __half22float2(hh);
          float sv = fv.x + fv.y, qv = fv.x * fv.x + fv.y * fv.y;
          if (b == 0) { sb0 += sv; qb0 += qv; } else { sb1 += sv; qb1 += qv; }
        }
        #pragma unroll
        for (int off = 32; off; off >>= 1) {
          sb0 += __shfl_xor(sb0, off); qb0 += __shfl_xor(qb0, off);
          sb1 += __shfl_xor(sb1, off); qb1 += __shfl_xor(qb1, off);
        }
        if (lane == 0) { stw0[w * 4] = sb0; stw0[w * 4 + 1] = sb1; stw0[w * 4 + 2] = qb0; stw0[w * 4 + 3] = qb1; }
      }
      __syncthreads();
      if (tid == 0) gstu32(flagA + (bp * 64 + gl) * 16, (u32)(n + 1));
      if (pollL0) {
        {
          float S0 = stw0[0] + stw0[4] + stw0[8] + stw0[12];
          float S1 = stw0[1] + stw0[5] + stw0[9] + stw0[13];
          float Q0 = stw0[2] + stw0[6] + stw0[10] + stw0[14];
          float Q1 = stw0[3] + stw0[7] + stw0[11] + stw0[15];
          m3[0] = S0 * (1.f / 512.f); i3v[0] = rsqrtf(Q0 * (1.f / 512.f) - m3[0] * m3[0] + 1e-5f);
          m3[1] = S1 * (1.f / 512.f); i3v[1] = rsqrtf(Q1 * (1.f / 512.f) - m3[1] * m3[1] + 1e-5f);
        }
        // sec3 matvec over hr0 (c1/g1 cols for w<3; Wr for w==3)
        float a[8][2];
        #pragma unroll
        for (int c = 0; c < 8; ++c) { a[c][0] = 0.f; a[c][1] = 0.f; }
        if (w < 3) {
          const __half* wbase = (w < 2) ? (WL + (size_t)(w * 8) * C) : (WL + oG1);
          #pragma unroll
          for (int it = 0; it < 4; ++it) {
            int p2 = lane + it * 64;
            h2t x0 = *(const h2t*)(hr0 + 2 * p2);
            h2t x1 = *(const h2t*)(hr0 + 512 + 2 * p2);
            #pragma unroll
            for (int c = 0; c < 8; ++c) {
              h2t wv = *(const h2t*)(wbase + (size_t)c * C + 1024 + 2 * p2);
              a[c][0] = fdot2f(wv, x0, a[c][0]);
              a[c][1] = fdot2f(wv, x1, a[c][1]);
            }
          }
        } else {
          #pragma unroll
          for (int it = 0; it < 4; ++it) {
            int p2 = lane + it * 64;
            h2t x0 = *(const h2t*)(hr0 + 2 * p2);
            h2t x1 = *(const h2t*)(hr0 + 512 + 2 * p2);
            #pragma unroll
            for (int c = 0; c < 8; ++c) {
              h2t wv = *(const h2t*)(WL + oR + (size_t)c * e + 2 * p2);
              a[c][0] = fdot2f(wv, x0, a[c][0]);
              a[c][1] = fdot2f(wv, x1, a[c][1]);
            }
          }
        }
        #pragma unroll
        for (int c = 0; c < 8; ++c) { comb[c][0] += i3v[0] * a[c][0]; comb[c][1] += i3v[1] * a[c][1]; }
      }
    }

    // ---- Phase A: poll OWN raw-h broadcast; stats folded into decode ----
    if (pollOwn) {
      const u64* s1 = HBown + (size_t)parR * 512;
      const u32 want = (u32)n;
      u64 v1[2];
      for (;;) {
        v1[0] = gldu64(s1 + tid); v1[1] = gldu64(s1 + 256 + tid);
        if (((u32)(v1[0] >> 32) == want) & ((u32)(v1[1] >> 32) == want)) break;
        __builtin_amdgcn_s_sleep(2);
      }
      float sb0 = 0.f, sb1 = 0.f, qb0 = 0.f, qb1 = 0.f;
      #pragma unroll
      for (int i = 0; i < 2; ++i) {
        int W = i * 256 + tid;
        int glp = W >> 3, q = W & 7, cpp = q >> 1, b = q & 1;
        u32 pay = (u32)v1[i];
        ((u32*)(hr16 + (parR * 2 + b) * 512))[glp * 4 + cpp] = pay;
        __half2 hh; __builtin_memcpy(&hh, &pay, 4);
        float2 fv = __half22float2(hh);
        float sv = fv.x + fv.y, qv = fv.x * fv.x + fv.y * fv.y;
        if (b == 0) { sb0 += sv; qb0 += qv; } else { sb1 += sv; qb1 += qv; }
      }
      #pragma unroll
      for (int off = 32; off; off >>= 1) {
        sb0 += __shfl_xor(sb0, off); qb0 += __shfl_xor(qb0, off);
        sb1 += __shfl_xor(sb1, off); qb1 += __shfl_xor(qb1, off);
      }
      if (lane == 0) { stw[w * 4] = sb0; stw[w * 4 + 1] = sb1; stw[w * 4 + 2] = qb0; stw[w * 4 + 3] = qb1; }
    }
    __syncthreads();

    // ---- finalize own stats ----
    float m1[2] = {0.f, 0.f}, i1v[2] = {0.f, 0.f};
    if (pollOwn) {
      float S0 = stw[0] + stw[4] + stw[8] + stw[12];
      float S1 = stw[1] + stw[5] + stw[9] + stw[13];
      float Q0 = stw[2] + stw[6] + stw[10] + stw[14];
      float Q1 = stw[3] + stw[7] + stw[11] + stw[15];
      m1[0] = S0 * (1.f / 512.f); i1v[0] = rsqrtf(Q0 * (1.f / 512.f) - m1[0] * m1[0] + 1e-5f);
      m1[1] = S1 * (1.f / 512.f); i1v[1] = rsqrtf(Q1 * (1.f / 512.f) - m1[1] * m1[1] + 1e-5f);
    }

    // ---- histN (l1): normalized h(t-1) ----
    if (l == 1 && pollOwn && tid < 16) {
      int c = tid >> 1, b = tid & 1, j = gl * 8 + c;
      float rv = __half2float(hr16[(parR * 2 + b) * 512 + j]);
      gstf(histN + ((size_t)((bp * 2 + b) * Tn + (t - 1))) * Hn + j, (rv - m1[b]) * i1v[b]);
    }

    // ---- post-poll matvec: sec1 only + CB store ----
    if (prod) {
      const __half* h1pl[2] = { hr16 + (parR * 2) * 512, hr16 + (parR * 2 + 1) * 512 };
      if (w < 3) {
        const __half* wbase = (w < 2) ? (WL + (size_t)(w * 8) * C) : (WL + oG1);
        float a[8][2];
        #pragma unroll
        for (int c = 0; c < 8; ++c) { a[c][0] = 0.f; a[c][1] = 0.f; }
        #pragma unroll
        for (int it = 0; it < 4; ++it) {
          int p2 = lane + it * 64;
          h2t x0 = *(const h2t*)(h1pl[0] + 2 * p2);
          h2t x1 = *(const h2t*)(h1pl[1] + 2 * p2);
          #pragma unroll
          for (int c = 0; c < 8; ++c) {
            h2t wv = *(const h2t*)(wbase + (size_t)c * C + 2 * p2);
            a[c][0] = fdot2f(wv, x0, a[c][0]);
            a[c][1] = fdot2f(wv, x1, a[c][1]);
          }
        }
        #pragma unroll
        for (int c = 0; c < 8; ++c) { comb[c][0] += i1v[0] * a[c][0]; comb[c][1] += i1v[1] * a[c][1]; }
      }

      #pragma unroll
      for (int off = 32; off; off >>= 1)
        #pragma unroll
        for (int c = 0; c < 8; ++c) {
          comb[c][0] += __shfl_xor(comb[c][0], off);
          comb[c][1] += __shfl_xor(comb[c][1], off);
        }
      float v0s = 0.f, v1s = 0.f;
      #pragma unroll
      for (int c = 0; c < 8; ++c)
        if (lane == c) { v0s = comb[c][0]; v1s = comb[c][1]; }

      const u64 tagw = ((u64)(u32)(n + 1)) << 32;
      u64* CBw = CBown + (size_t)(n & 1) * 1152 + gl * 18;
      if (w < 2) {
        if (lane < 8) {
          int cg = w * 8 + lane;
          float k0 = i1v[0] * m1[0] * Ss[cg] + ipv[0] * mp[0] * Ss[16 + cg];
          float k1 = i1v[1] * m1[1] * Ss[cg] + ipv[1] * mp[1] * Ss[16 + cg];
          if (l) { k0 += i3v[0] * m3[0] * Ss[32 + cg]; k1 += i3v[1] * m3[1] * Ss[32 + cg]; }
          float bb = bc1L[cg];
          float c0 = fmaxf(v0s - k0 + bb, 0.f), c1 = fmaxf(v1s - k1 + bb, 0.f);
          u32 pay = (u32)f2h(c0) | ((u32)f2h(c1) << 16);
          gstu64(CBw + cg, tagw | pay);
        }
      } else if (w == 2) {
        if (lane < 8) {
          float k0 = i1v[0] * m1[0] * Ss[48 + lane] + ipv[0] * mp[0] * Ss[56 + lane];
          float k1 = i1v[1] * m1[1] * Ss[48 + lane] + ipv[1] * mp[1] * Ss[56 + lane];
          if (l) { k0 += i3v[0] * m3[0] * Ss[64 + lane]; k1 += i3v[1] * m3[1] * Ss[64 + lane]; }
          float bgv = bg1L[lane], wgv = wg2L[lane];
          float t0 = tanhf(v0s - k0 + bgv) * wgv;
          float t1 = tanhf(v1s - k1 + bgv) * wgv;
          #pragma unroll
          for (int off = 1; off < 8; off <<= 1) { t0 += __shfl_xor(t0, off); t1 += __shfl_xor(t1, off); }
          if (lane == 0) {
            u32 b0, b1; __builtin_memcpy(&b0, &t0, 4); __builtin_memcpy(&b1, &t1, 4);
            gstu64(CBw + 16, tagw | b0);
            gstu64(CBw + 17, tagw | b1);
          }
        }
      } else {
        if (lane < 8) {
          float k0 = l ? i3v[0] * m3[0] * Ss[72 + lane] : 0.f;
          float k1 = l ? i3v[1] * m3[1] * Ss[72 + lane] : 0.f;
          rloc[lane * 2]     = v0s - k0 + brL[lane];
          rloc[lane * 2 + 1] = v1s - k1 + brL[lane];
        }
      }
    }

    // ---- Phase B: poll cand1-broadcast + l0 backpressure ----
    if (prod) {
      const u64* CBL = CBown + (size_t)(n & 1) * 1152;
      const u32 want = (u32)(n + 1);
      const bool needF = (l == 0) && (tid < 64);
      const u32* fptr = flagA + (bp * 64 + tid) * 16;
      u64 cv[5];
      const bool last = (tid < 128);
      for (;;) {
        bool ok = true;
        #pragma unroll
        for (int i = 0; i < 4; ++i) cv[i] = gldu64(CBL + i * 256 + tid);
        if (last) cv[4] = gldu64(CBL + 1024 + tid);
        #pragma unroll
        for (int i = 0; i < 4; ++i) ok &= ((u32)(cv[i] >> 32) == want);
        if (last) ok &= ((u32)(cv[4] >> 32) == want);
        if (needF) ok &= (gldu32(fptr) >= (u32)n);
        if (ok) break;
        __builtin_amdgcn_s_sleep(2);
      }
      u16* xc16 = (u16*)xcand;
      #pragma unroll
      for (int i = 0; i < 5; ++i) {
        if (i == 4 && !last) break;
        int idx = i * 256 + tid;
        int p = (int)(((u32)idx * 3641u) >> 16);
        int w2 = idx - p * 18;
        u32 pay = (u32)cv[i];
        if (w2 < 16) {
          int j = p * 16 + w2;
          xc16[j]        = (u16)(pay & 0xffffu);
          xc16[1024 + j] = (u16)(pay >> 16);
        } else {
          float f; __builtin_memcpy(&f, &pay, 4);
          gp[p * 2 + (w2 - 16)] = f;
        }
      }
    }
    __syncthreads();

    // ---- gate (redundant/wave) + matvec2 + finalize + HB store ----
    if (prod) {
      float gs0 = gp[lane * 2], gs1 = gp[lane * 2 + 1];
      #pragma unroll
      for (int off = 32; off; off >>= 1) { gs0 += __shfl_xor(gs0, off); gs1 += __shfl_xor(gs1, off); }
      float gate[2];
      gate[0] = 1.f / (1.f + expf(-(gs0 + bg2L[0])));
      gate[1] = 1.f / (1.f + expf(-(gs1 + bg2L[0])));

      float a2[2][2];
      a2[0][0] = a2[0][1] = a2[1][0] = a2[1][1] = 0.f;
      const __half* wb2 = WL + oC2 + (w * 2) * 1024;
      #pragma unroll
      for (int it = 0; it < 8; ++it) {
        int p2 = lane + it * 64;
        h2t xv0 = *(const h2t*)(xcand + 2 * p2);
        h2t xv1 = *(const h2t*)(xcand + 1024 + 2 * p2);
        #pragma unroll
        for (int cc = 0; cc < 2; ++cc) {
          h2t wv = *(const h2t*)(wb2 + cc * 1024 + 2 * p2);
          a2[cc][0] = fdot2f(wv, xv0, a2[cc][0]);
          a2[cc][1] = fdot2f(wv, xv1, a2[cc][1]);
        }
      }
      #pragma unroll
      for (int off = 32; off; off >>= 1)
        #pragma unroll
        for (int cc = 0; cc < 2; ++cc) {
          a2[cc][0] += __shfl_xor(a2[cc][0], off);
          a2[cc][1] += __shfl_xor(a2[cc][1], off);
        }
      float sel = 0.f;
      #pragma unroll
      for (int cc = 0; cc < 2; ++cc)
        #pragma unroll
        for (int b = 0; b < 2; ++b)
          if (lane == cc * 2 + b) sel = a2[cc][b];
      int cc = (lane >> 1) & 1, b = lane & 1, cl = w * 2 + cc;
      float rv = __half2float(hr16[(parR * 2 + b) * 512 + gl * 8 + cl]);
      float h1n = (rv - m1[b]) * i1v[b];
      float hv = h1n + gate[b] * (sel + bc2L[cl]) + 0.1f * rloc[cl * 2 + b];
      float hv0 = __shfl(hv, 0), hv1 = __shfl(hv, 1);
      float hv2 = __shfl(hv, 2), hv3 = __shfl(hv, 3);
      if (lane < 2) {
        u32 pay = (lane == 0) ? ((u32)f2h(hv0) | ((u32)f2h(hv2) << 16))
                              : ((u32)f2h(hv1) | ((u32)f2h(hv3) << 16));
        u64* HBw = HBown + (size_t)(n & 1) * 512 + gl * 8;
        gstu64(HBw + w * 2 + lane, (((u64)(u32)(n + 1)) << 32) | pay);
      }
      if (l == 1 && gl == 0 && w == 0 && lane == 0) {
        gstf(gates_out + (bp * 2) * Tn + t, gate[0]);
        gstf(gates_out + (bp * 2 + 1) * Tn + t, gate[1]);
      }
    }

    if (pollOwn) { mp[0] = m1[0]; mp[1] = m1[1]; ipv[0] = i1v[0]; ipv[1] = i1v[1]; }
  }
}

// ---------------- attention scores ----------------
__global__ __launch_bounds__(256) void scores_kernel(
    const float* __restrict__ histN,
    const float* __restrict__ wa1, const float* __restrict__ ba1,
    const float* __restrict__ wa2, const float* __restrict__ ba2,
    float* __restrict__ scores)
{
  __shared__ float xs[8][512];
  __shared__ float wacc[4][8];
  const int tid = threadIdx.x, bid = blockIdx.x;

  for (int idx = tid; idx < 4096; idx += 256)
    xs[idx >> 9][idx & 511] = histN[(size_t)(bid * 8) * Hn + idx];
  __syncthreads();

  float pr[8] = {0.f,0.f,0.f,0.f,0.f,0.f,0.f,0.f};
  #pragma unroll
  for (int cc = 0; cc < 2; ++cc) {
    int c = tid + cc * 256;
    float a[8] = {0.f,0.f,0.f,0.f,0.f,0.f,0.f,0.f};
    for (int k = 0; k < 512; ++k) {
      float wv = wa1[(size_t)k * 512 + c];
      #pragma unroll
      for (int r = 0; r < 8; ++r) a[r] = fmaf(xs[r][k], wv, a[r]);
    }
    float b1 = ba1[c], w2 = wa2[c];
    #pragma unroll
    for (int r = 0; r < 8; ++r) pr[r] += tanhf(a[r] + b1) * w2;
  }
  int lane = tid & 63, wq = tid >> 6;
  #pragma unroll
  for (int off = 32; off; off >>= 1)
    #pragma unroll
    for (int r = 0; r < 8; ++r) pr[r] += __shfl_xor(pr[r], off);
  if (lane == 0) {
    #pragma unroll
    for (int r = 0; r < 8; ++r) wacc[wq][r] = pr[r];
  }
  __syncthreads();
  if (tid < 8)
    scores[bid * 8 + tid] = wacc[0][tid] + wacc[1][tid] + wacc[2][tid] + wacc[3][tid] + ba2[0];
}

// ---------------- prefix-softmax tiled scan -> attended (bf16) ----------------
__global__ __launch_bounds__(256) void cumsum_scan_kernel(
    const float* __restrict__ scores, const float* __restrict__ histN,
    u16* __restrict__ att)
{
  __shared__ float ee[512], sa[512], sb[512], red[256];
  __shared__ float tile[64][64];
  const int tid = threadIdx.x;
  const int b = blockIdx.y, j0 = blockIdx.x * 64;

  float s0 = scores[b * Tn + tid], s1 = scores[b * Tn + tid + 256];
  red[tid] = fmaxf(s0, s1);
  __syncthreads();
  for (int s = 128; s; s >>= 1) { if (tid < s) red[tid] = fmaxf(red[tid], red[tid + s]); __syncthreads(); }
  float m = red[0];
  ee[tid] = expf(s0 - m); ee[tid + 256] = expf(s1 - m);
  sa[tid] = ee[tid]; sa[tid + 256] = ee[tid + 256];
  __syncthreads();
  float* A = sa; float* D = sb;
  for (int off = 1; off < 512; off <<= 1) {
    for (int t2 = tid; t2 < 512; t2 += 256) { float v = A[t2]; if (t2 >= off) v += A[t2 - off]; D[t2] = v; }
    __syncthreads();
    float* tmp = A; A = D; D = tmp;
  }
  float* R = D;
  for (int t2 = tid; t2 < 512; t2 += 256) R[t2] = 1.f / A[t2];
  __syncthreads();

  float ax = 0.f;
  for (int tt = 0; tt < 8; ++tt) {
    #pragma unroll
    for (int k = 0; k < 16; ++k) {
      int idx = tid + k * 256;
      int r = idx >> 6, c = idx & 63;
      tile[r][c] = histN[(size_t)(b * Tn + tt * 64 + r) * Hn + j0 + c];
    }
    __syncthreads();
    if (tid < 64) {
      for (int r = 0; r < 64; ++r) {
        int t = tt * 64 + r;
        float x = tile[r][tid];
        ax = fmaf(ee[t], x, ax);
        att[((size_t)(b * Tn + t)) * Hn + j0 + tid] = f2bf(x + ax * R[t]);
      }
    }
    __syncthreads();
  }
}

// ---------------- final GEMM ----------------
typedef short bf16x8_t __attribute__((ext_vector_type(8)));
typedef float f32x4_t  __attribute__((ext_vector_type(4)));

__global__ __launch_bounds__(256) void gemm_kernel(
    const u16* __restrict__ Aw, const u16* __restrict__ Bw,
    const float* __restrict__ bh, float* __restrict__ out)
{
  __shared__ u16 Alds[128 * 64];
  __shared__ u16 Blds[64 * 128];
  const int tid = threadIdx.x;
  const int n0 = blockIdx.x * 128, m0 = blockIdx.y * 128;
  const int w = tid >> 6, lane = tid & 63;
  const int wm = (w & 1) * 64, wn = (w >> 1) * 64;

  f32x4_t acc[4][4];
  #pragma unroll
  for (int i = 0; i < 4; ++i)
    #pragma unroll
    for (int j = 0; j < 4; ++j) acc[i][j] = (f32x4_t){0.f, 0.f, 0.f, 0.f};

  for (int kt = 0; kt < 8; ++kt) {
    const int k0 = kt * 64;
    {
      int row = tid >> 1, kc = (tid & 1) * 32;
      #pragma unroll
      for (int jj = 0; jj < 4; ++jj) {
        uint4 v = *(const uint4*)(Aw + (size_t)(m0 + row) * 512 + k0 + kc + jj * 8);
        int byte = row * 128 + (kc + jj * 8) * 2;
        byte ^= (row & 7) << 4;
        *(uint4*)((char*)Alds + byte) = v;
      }
    }
    {
      #pragma unroll
      for (int q = 0; q < 4; ++q) {
        int r = (tid >> 4) + q * 16, c8 = (tid & 15) * 8;
        uint4 v = *(const uint4*)(Bw + (size_t)(k0 + r) * NPAD + n0 + c8);
        *(uint4*)&Blds[r * 128 + c8] = v;
      }
    }
    __syncthreads();
    #pragma unroll
    for (int kh = 0; kh < 2; ++kh) {
      bf16x8_t af[4];
      #pragma unroll
      for (int i = 0; i < 4; ++i) {
        int row = wm + i * 16 + (lane & 15);
        int byte = row * 128 + kh * 64 + (lane >> 4) * 16;
        byte ^= (row & 7) << 4;
        af[i] = *(const bf16x8_t*)((const char*)Alds + byte);
      }
      const int kb = kh * 32 + (lane >> 4) * 8;
      #pragma unroll
      for (int j = 0; j < 4; ++j) {
        int col = wn + j * 16 + (lane & 15);
        bf16x8_t bf;
        #pragma unroll
        for (int jj = 0; jj < 8; ++jj) bf[jj] = (short)Blds[(kb + jj) * 128 + col];
        #pragma unroll
        for (int i = 0; i < 4; ++i)
          acc[i][j] = __builtin_amdgcn_mfma_f32_16x16x32_bf16(af[i], bf, acc[i][j], 0, 0, 0);
      }
    }
    __syncthreads();
  }
  #pragma unroll
  for (int j = 0; j < 4; ++j) {
    int col = n0 + wn + j * 16 + (lane & 15);
    if (col < Vn) {
      float bias = bh[col];
      #pragma unroll
      for (int i = 0; i < 4; ++i) {
        int rbase = m0 + wm + i * 16 + (lane >> 4) * 4;
        #pragma unroll
        for (int r = 0; r < 4; ++r)
          out[(size_t)(rbase + r) * Vn + col] = acc[i][j][r] + bias;
      }
    }
  }
}

// ---------------- host ----------------
extern "C" void kernel_launch(void* const* d_in, const int* in_sizes, int n_in,
                              void* d_out, int out_size, void* d_ws, size_t ws_size,
                              hipStream_t stream) {
  const int*   ids  = (const int*)d_in[0];
  const float* emb  = (const float*)d_in[1];
  const float* Wc1_0 = (const float*)d_in[2];  const float* bc1_0 = (const float*)d_in[3];
  const float* Wc2_0 = (const float*)d_in[4];  const float* bc2_0 = (const float*)d_in[5];
  const float* Wg1_0 = (const float*)d_in[6];  const float* bg1_0 = (const float*)d_in[7];
  const float* Wg2_0 = (const float*)d_in[8];  const float* bg2_0 = (const float*)d_in[9];
  const float* Wr_0  = (const float*)d_in[10]; const float* br_0  = (const float*)d_in[11];
  const float* Wc1_1 = (const float*)d_in[12]; const float* bc1_1 = (const float*)d_in[13];
  const float* Wc2_1 = (const float*)d_in[14]; const float* bc2_1 = (const float*)d_in[15];
  const float* Wg1_1 = (const float*)d_in[16]; const float* bg1_1 = (const float*)d_in[17];
  const float* Wg2_1 = (const float*)d_in[18]; const float* bg2_1 = (const float*)d_in[19];
  const float* Wr_1  = (const float*)d_in[20]; const float* br_1  = (const float*)d_in[21];
  const float* Wa1 = (const float*)d_in[22]; const float* ba1 = (const float*)d_in[23];
  const float* Wa2 = (const float*)d_in[24]; const float* ba2 = (const float*)d_in[25];
  const float* Wh  = (const float*)d_in[26]; const float* bh  = (const float*)d_in[27];

  float* out = (float*)d_out;
  char*  ws  = (char*)d_ws;

  const size_t OFF_FLAGA = 0;                          // 8192
  const size_t OFF_HB    = 8192;                       // 32768 (4096 u64)
  const size_t OFF_CB    = 40960;                      // 73728 (9216 u64)
  const size_t OFF_WT    = 114688;                     // 11534336
  const size_t OFF_HISTN = OFF_WT + 11534336;
  const size_t OFF_SCO   = OFF_HISTN + 4194304;
  const size_t OFF_ATT   = OFF_SCO + 8192;
  const size_t OFF_WHB   = OFF_ATT + 2097152;

  u32*   flagA  = (u32*)(ws + OFF_FLAGA);
  u64*   HB     = (u64*)(ws + OFF_HB);
  u64*   CB     = (u64*)(ws + OFF_CB);
  __half* wth   = (__half*)(ws + OFF_WT);
  float* histN  = (float*)(ws + OFF_HISTN);
  float* scores = (float*)(ws + OFF_SCO);
  u16*   att    = (u16*)(ws + OFF_ATT);
  u16*   whb    = (u16*)(ws + OFF_WHB);
  float* gates  = out + (size_t)Bn * Tn * Vn;

  __half* wtC1_0h = wth;
  __half* wtG1_0h = wth + 1310720;
  __half* wtC2_0h = wth + 1966080;
  __half* wtR_0h  = wth + 2490368;
  __half* wtC1_1h = wth + 2621440;
  __half* wtG1_1h = wth + 4194304;
  __half* wtC2_1h = wth + 4980736;
  __half* wtR_1h  = wth + 5505024;

  hipMemsetAsync(ws, 0, 114688, stream);   // flagA + HB + CB tags

  transpose_h<<<dim3(32, 40), 256, 0, stream>>>(Wc1_0, wtC1_0h, 1280, 1024);
  transpose_h<<<dim3(16, 40), 256, 0, stream>>>(Wg1_0, wtG1_0h, 1280, 512);
  transpose_h<<<dim3(16, 32), 256, 0, stream>>>(Wc2_0, wtC2_0h, 1024, 512);
  transpose_h<<<dim3(16,  8), 256, 0, stream>>>(Wr_0,  wtR_0h,   256, 512);
  transpose_h<<<dim3(32, 48), 256, 0, stream>>>(Wc1_1, wtC1_1h, 1536, 1024);
  transpose_h<<<dim3(16, 48), 256, 0, stream>>>(Wg1_1, wtG1_1h, 1536, 512);
  transpose_h<<<dim3(16, 32), 256, 0, stream>>>(Wc2_1, wtC2_1h, 1024, 512);
  transpose_h<<<dim3(16, 16), 256, 0, stream>>>(Wr_1,  wtR_1h,   512, 512);

  convwh_kernel<<<dim3(99, 512), 256, 0, stream>>>(Wh, whb);

  (void)hipFuncSetAttribute((const void*)rec_kernel,
                            hipFuncAttributeMaxDynamicSharedMemorySize, REC_LDS);

  rec_kernel<<<dim3(RG), dim3(RNT), REC_LDS, stream>>>(
      ids, emb,
      wtC1_0h, wtG1_0h, wtC2_0h, wtR_0h,
      wtC1_1h, wtG1_1h, wtC2_1h, wtR_1h,
      bc1_0, bg1_0, bc2_0, br_0, Wg2_0, bg2_0,
      bc1_1, bg1_1, bc2_1, br_1, Wg2_1, bg2_1,
      flagA, HB, CB, histN, gates);

  scores_kernel<<<dim3(256), 256, 0, stream>>>(histN, Wa1, ba1, Wa2, ba2, scores);

  cumsum_scan_kernel<<<dim3(8, Bn), 256, 0, stream>>>(scores, histN, att);

  gemm_kernel<<<dim3(393, 16), 256, 0, stream>>>(att, whb, bh, out);
}